// Round 1
// 731.077 us; speedup vs baseline: 1.0361x; 1.0361x over previous
//
#include <hip/hip_runtime.h>
#include <hip/hip_bf16.h>

typedef __hip_bfloat16 bf16;
typedef __attribute__((ext_vector_type(8))) short short8;
typedef __attribute__((ext_vector_type(4))) float f32x4;
typedef __attribute__((ext_vector_type(16))) float f32x16;

__device__ __forceinline__ float b2f(const bf16 v){ return __bfloat162float(v); }
__device__ __forceinline__ float ld(const float* p, long i){ return p[i]; }
__device__ __forceinline__ float ld(const bf16*  p, long i){ return b2f(p[i]); }

__device__ __forceinline__ unsigned f2bf_u(float f){
    union { float f; unsigned u; } a; a.f = f;
    unsigned r = a.u + 0x7FFFu + ((a.u >> 16) & 1u);
    return r >> 16;
}

__device__ __forceinline__ short8 pack8(const float* v){
    // RNE pack via v_cvt_pk_bf16_f32 (compiler emits the packed cvt)
    union { __hip_bfloat162 h[4]; short8 s; } r;
    #pragma unroll
    for (int i=0;i<4;i++)
        r.h[i] = __float22bfloat162_rn(float2{v[2*i], v[2*i+1]});
    return r.s;
}

// ---- converted-params block offsets (floats) within P ----
#define OFF_C1W   0        /* 11616 */
#define OFF_C1B   11616    /* 32   */
#define OFF_RLG   11648    /* 2048 */
#define OFF_RLB   13696
#define OFF_RLM   15744
#define OFF_RLV   17792
#define OFF_RLCW  19840    /* 589824 slots: bf16 WR [net][tap9][half2][lane64][j8] */
#define OFF_RLCB  609664   /* 2048 */
#define OFF_BNG   611712
#define OFF_BNB   611744
#define OFF_BNM   611776
#define OFF_BNV   611808
#define OFF_C2W   611840   /* 32768 */
#define OFF_C2B   644608
#define OFF_C3W   644624   /* 16384 */
#define OFF_C3B   661008
#define OFF_C4W   661024   /* 9216 */
#define OFF_C4B   670240
#define OFF_C5W   670256   /* 6400 */
#define OFF_C5B   676656
#define OFF_F1B   676672   /* 4096 */
#define OFF_F2B   680768   /* 2048 */
#define OFF_F3B   682816   /* 24   */
#define P_TOTAL   682840
#define OFF_WB2   P_TOTAL             /* 32768 bf16 = 16384 f32 slots */
#define OFF_WB3   (P_TOTAL + 16384)   /* 16384 bf16 = 8192 f32 slots  */
#define OFF_WC1   (P_TOTAL + 16384 + 8192)  /* 16896 bf16 = 8448 f32 slots */
#define P_END     (OFF_WC1 + 8448)

#define SZ_RL  589824
#define SZ_WB2 32768
#define SZ_WB3 16384
#define SZ_WC1 16896

// ---------- dtype sniff: flag=1 if inputs are float32, 0 if bf16 ----------
__global__ void k_sniff(const void* __restrict__ x, int* __restrict__ flag)
{
    const bf16* xb = (const bf16*)x;
    const float v = fabsf(b2f(xb[2*threadIdx.x]));
    const int ok = (v >= 1e-6f && v <= 1e6f) ? 1 : 0;
    __shared__ int cnt;
    if (threadIdx.x == 0) cnt = 0;
    __syncthreads();
    atomicAdd(&cnt, ok);
    __syncthreads();
    if (threadIdx.x == 0) *flag = (cnt >= 192) ? 0 : 1;
}

// ---------- convert params to f32 block P + bf16 fragment-layout weight blocks ----------
struct CvtArgs { const void* src[23]; int off[23]; const void* cw; const void* w2; const void* w3; int total; };

__device__ __forceinline__ float getv(const void* p, long i, bool isf){
    return isf ? ((const float*)p)[i] : b2f(((const bf16*)p)[i]);
}

__global__ __launch_bounds__(256) void k_cvt(CvtArgs a, const int* __restrict__ flag,
                                             float* __restrict__ P)
{
    const bool isf = (*flag != 0);
    const int i1 = a.total;            // region WR frags (bf16, in rl_cw slot)
    const int i2 = i1 + SZ_RL;         // WB2
    const int i3 = i2 + SZ_WB2;        // WB3
    const int i4 = i3 + SZ_WB3;        // WC1
    const int i5 = i4 + SZ_WC1;
    for (int idx = blockIdx.x*256 + threadIdx.x; idx < i5; idx += gridDim.x*256){
        if (idx < i1){
            if (idx >= OFF_RLCW && idx < OFF_RLCB) continue;   // slot reused for WR
            int k = 0;
            #pragma unroll
            for (int j = 1; j < 23; j++) if (idx >= a.off[j]) k = j;
            P[idx] = getv(a.src[k], idx - a.off[k], isf);
        } else if (idx < i2){
            // WR[net][tap][half][lane][j]: A-frag (weights, M=co16) for region
            const int d = idx - i1;
            const int net = d / 9216, dn = d % 9216;
            const int tap = dn >> 10, rem = dn & 1023;
            const int half = rem >> 9, lane = (rem >> 3) & 63, j = rem & 7;
            const int co = half*16 + (lane & 15);
            const int ci = ((lane >> 4) << 3) + j;
            const long sidx = (long)((net*32 + co)*32 + ci)*9 + tap;
            ((unsigned short*)(P + OFF_RLCW))[d] = (unsigned short)f2bf_u(getv(a.cw, sidx, isf));
        } else if (idx < i3){
            // WB2[tap][lane][j]: B-frag layout for conv2 (K=32ci)
            const int d = idx - i2;
            const int j = d & 7, lane = (d >> 3) & 63, tap = d >> 9;
            const int n = lane & 15, k = ((lane >> 4) << 3) + j;
            const int ci = k, ky = tap >> 3, kx = tap & 7;
            const long sidx = (long)((n*32 + ci)*8 + ky)*8 + kx;
            ((unsigned short*)(P + OFF_WB2))[d] = (unsigned short)f2bf_u(getv(a.w2, sidx, isf));
        } else if (idx < i4){
            // WB3[pair][lane][j]: B-frag layout for conv3 (K=16ci x 2 taps)
            const int d = idx - i3;
            const int j = d & 7, lane = (d >> 3) & 63, pair = d >> 9;
            const int n = lane & 15, k = ((lane >> 4) << 3) + j;
            const int tsel = k >> 4, ci = k & 15;
            const int ky = pair >> 2, kx = ((pair & 3) << 1) + tsel;
            const long sidx = (long)((n*16 + ci)*8 + ky)*8 + kx;
            ((unsigned short*)(P + OFF_WB3))[d] = (unsigned short)f2bf_u(getv(a.w3, sidx, isf));
        } else {
            // WC1[ky][ch][lane][j]: A-frag (weights, M=co32) for conv1, K=16 = 4kx x 4ci
            const int d = idx - i4;
            const int ky = d / 1536, rem = d % 1536;
            const int ch = rem >> 9, rem2 = rem & 511;
            const int lane = rem2 >> 3, j = rem2 & 7;
            const int co = lane & 31, h5 = lane >> 5;
            const int kx = ch*4 + h5*2 + (j >> 2), ci = j & 3;
            float v = 0.f;
            if (ci < 3 && kx < 11)
                v = getv(a.src[0], (long)((co*3 + ci)*11 + ky)*11 + kx, isf);
            ((unsigned short*)(P + OFF_WC1))[d] = (unsigned short)f2bf_u(v);
        }
    }
}

// ---------------- conv1 via 32x32x16 MFMA: x[32,3,170,170] -> [32,32,160,160] ----------------
// block = (8-row group, 32-col tile, b); wave = 2 row-strips; A=W[co32][k16], B=X[k16][pix32]
__global__ __launch_bounds__(256,3) void k_conv1M(const void* __restrict__ x,
        const int* __restrict__ flag, const float* __restrict__ P, float* __restrict__ out)
{
    __shared__ unsigned short xs[18*44*4];     // [row18][col44][ci4] bf16, 6336 B
    __shared__ unsigned short wsm[SZ_WC1];     // 33792 B
    const int t = threadIdx.x;
    const int y0 = blockIdx.x*8, x0 = blockIdx.y*32, b = blockIdx.z;
    { const uint4* src = (const uint4*)(P + OFF_WC1);
      uint4* dst = (uint4*)wsm;
      for (int e=t; e<2112; e+=256) dst[e] = src[e]; }
    const bool isf = (*flag) != 0;
    for (int e=t; e<792; e+=256){
        const int r = e/44, c = e%44;
        const long base = ((long)(b*3)*170 + (y0+r))*170 + min(x0+c, 169);
        float v0, v1, v2;
        if (isf){
            const float* xf = (const float*)x;
            v0 = xf[base]; v1 = xf[base+28900]; v2 = xf[base+57800];
        } else {
            const bf16* xf = (const bf16*)x;
            v0 = b2f(xf[base]); v1 = b2f(xf[base+28900]); v2 = b2f(xf[base+57800]);
        }
        uint2 u;
        u.x = f2bf_u(v0) | (f2bf_u(v1) << 16);
        u.y = f2bf_u(v2);
        *(uint2*)&xs[(r*44+c)*4] = u;
    }
    __syncthreads();
    const int wave = t>>6, lane = t&63;
    const int n = lane & 31, h5 = lane >> 5;
    const int r0 = wave*2;
    f32x16 acc0 = {0.f}, acc1 = {0.f};
    #pragma unroll
    for (int e=0;e<16;e++){ acc0[e]=0.f; acc1[e]=0.f; }
    #pragma unroll 1
    for (int ky=0; ky<11; ky++){
        #pragma unroll
        for (int ch=0; ch<3; ch++){
            const short8 aw = *(const short8*)&wsm[((ky*3+ch)*64 + lane)*8];
            const int kx0 = ch*4 + h5*2;
            const int a0 = ((r0+ky)*44 + n + kx0)*4;
            const int a1 = ((r0+1+ky)*44 + n + kx0)*4;
            union { uint2 u2[2]; short8 s; } ub0, ub1;
            ub0.u2[0] = *(const uint2*)&xs[a0];
            ub0.u2[1] = *(const uint2*)&xs[a0+4];
            ub1.u2[0] = *(const uint2*)&xs[a1];
            ub1.u2[1] = *(const uint2*)&xs[a1+4];
            acc0 = __builtin_amdgcn_mfma_f32_32x32x16_bf16(aw, ub0.s, acc0, 0,0,0);
            acc1 = __builtin_amdgcn_mfma_f32_32x32x16_bf16(aw, ub1.s, acc1, 0,0,0);
        }
    }
    // D: col = lane&31 = pixel-col, row(co) = (reg&3) + 8*(reg>>2) + 4*h5
    #pragma unroll
    for (int reg=0; reg<16; reg++){
        const int co = (reg&3) + 8*(reg>>2) + 4*h5;
        const float bv = P[OFF_C1B + co];
        float* op = out + ((long)(b*32+co)*160 + (y0+r0))*160 + x0 + n;
        op[0]   = acc0[reg] + bv;
        op[160] = acc1[reg] + bv;
    }
}

// ------- region layer via 16x16x32 MFMA, fused relu+maxpool2+bn with shuffle pooling -------
// block = (patch, batch); A=W[co16][ci32] (2 halves), B=X[ci32][pix16] (4x4 tiles)
__global__ __launch_bounds__(256,2) void k_regionM(const float* __restrict__ in,
        const float* __restrict__ P, float* __restrict__ pooled)
{
    __shared__ unsigned short s_in[484*32];    // [pix 22x22][ci32] bf16, 30976 B
    __shared__ unsigned short wsm[9216];       // [tap9][half2][lane64][j8], 18432 B
    __shared__ float sc[32], sh[32];
    const int t = threadIdx.x;
    const int b = blockIdx.x & 31, kk = blockIdx.x >> 5;
    const int gi = kk >> 3, gj = kk & 7;
    const int net = gj*(gi+1);                 // idx = ii*jj + jj
    const int ibase = (b*32*160 + gi*20)*160 + gj*20;
    if (t < 32){
        const float inv = rsqrtf(P[OFF_RLV+net*32+t]+1e-5f)*P[OFF_RLG+net*32+t];
        sc[t] = inv; sh[t] = P[OFF_RLB+net*32+t] - P[OFF_RLM+net*32+t]*inv;
    }
    { const uint4* src = (const uint4*)((const unsigned short*)(P+OFF_RLCW) + (size_t)net*9216);
      uint4* dst = (uint4*)wsm;
      for (int e=t; e<1152; e+=256) dst[e] = src[e]; }
    __syncthreads();
    // stage BN+ReLU patch, zero halo: item = (pixel, ci-oct) -> one b128 LDS write
    for (int e=t; e<1936; e+=256){
        const int o = e & 3, p = e >> 2;
        const int pr = p/22, pc = p%22;
        unsigned ov[4] = {0u,0u,0u,0u};
        if (pr>0 && pr<21 && pc>0 && pc<21){
            const int base = ibase + (pr-1)*160 + (pc-1);
            #pragma unroll
            for (int q2=0;q2<4;q2++){
                const int ci0 = o*8 + q2*2;
                float v0 = in[base + ci0*25600];
                float v1 = in[base + (ci0+1)*25600];
                v0 = fmaxf(fmaf(v0, sc[ci0],   sh[ci0]),   0.f);
                v1 = fmaxf(fmaf(v1, sc[ci0+1], sh[ci0+1]), 0.f);
                ov[q2] = f2bf_u(v0) | (f2bf_u(v1) << 16);
            }
        }
        *(uint4*)&s_in[p*32 + o*8] = *(const uint4*)ov;
    }
    __syncthreads();
    const int wave = t>>6, lane = t&63;
    const int q = lane>>4, n = lane&15;
    const int dr = n>>2, dc = n&3;
    const int nt = (wave==0) ? 7 : 6;          // 25 tiles over 4 waves
    int trs[7], tcs[7];
    #pragma unroll
    for (int i=0;i<7;i++){ const int tt = 4*i + wave; trs[i] = tt/5; tcs[i] = tt - 5*(tt/5); }
    f32x4 acc[7][2];
    {   float bias_v[2][4];
        #pragma unroll
        for (int h=0;h<2;h++)
            #pragma unroll
            for (int r=0;r<4;r++) bias_v[h][r] = P[OFF_RLCB + net*32 + h*16 + q*4 + r];
        #pragma unroll
        for (int i=0;i<7;i++)
            #pragma unroll
            for (int h=0;h<2;h++)
                acc[i][h] = (f32x4){bias_v[h][0], bias_v[h][1], bias_v[h][2], bias_v[h][3]};
    }
    #pragma unroll 1
    for (int tap=0; tap<9; tap++){
        const int ky = tap/3, kx = tap - 3*(tap/3);
        const short8 a0 = *(const short8*)&wsm[(tap*2+0)*512 + lane*8];
        const short8 a1 = *(const short8*)&wsm[(tap*2+1)*512 + lane*8];
        #pragma unroll
        for (int i=0;i<7;i++){
            if (i < nt){
                const int srow = trs[i]*4 + dr + ky, scol = tcs[i]*4 + dc + kx;
                const short8 bx = *(const short8*)&s_in[(srow*22 + scol)*32 + q*8];
                acc[i][0] = __builtin_amdgcn_mfma_f32_16x16x32_bf16(a0, bx, acc[i][0], 0,0,0);
                acc[i][1] = __builtin_amdgcn_mfma_f32_16x16x32_bf16(a1, bx, acc[i][1], 0,0,0);
            }
        }
    }
    // epilogue: residual + relu + 2x2 shuffle-pool + bn;  D: col=n=pixel, row=co=q*4+reg
    float bnsc[2][4], bnsh[2][4];
    #pragma unroll
    for (int h=0;h<2;h++)
        #pragma unroll
        for (int r=0;r<4;r++){
            const int co = h*16 + q*4 + r;
            const float inv = rsqrtf(P[OFF_BNV+co]+1e-5f)*P[OFF_BNG+co];
            bnsc[h][r] = inv; bnsh[h][r] = P[OFF_BNB+co] - P[OFF_BNM+co]*inv;
        }
    const bool wr = ((n & 5) == 0);            // dc even && dr even
    #pragma unroll
    for (int i=0;i<7;i++){
        if (i < nt){
            const int prow = trs[i]*4 + dr, pcol = tcs[i]*4 + dc;
            #pragma unroll
            for (int h=0;h<2;h++){
                #pragma unroll
                for (int r=0;r<4;r++){
                    const int co = h*16 + q*4 + r;
                    float v = acc[i][h][r] + in[ibase + co*25600 + prow*160 + pcol];
                    v = fmaxf(v, 0.f);
                    v = fmaxf(v, __shfl_xor(v, 1, 64));
                    v = fmaxf(v, __shfl_xor(v, 4, 64));
                    if (wr){
                        pooled[((b*32+co)*80 + gi*10 + trs[i]*2 + (dr>>1))*80
                               + gj*10 + tcs[i]*2 + (dc>>1)] = fmaf(v, bnsc[h][r], bnsh[h][r]);
                    }
                }
            }
        }
    }
}

// ------- conv2/conv3 via MFMA shift-GEMM (validated in R3) -------
template<int CIN, int HIN, int WIN, int HOUT, int WOUT>
__global__ __launch_bounds__(256) void k_convM(const float* __restrict__ in,
        const unsigned short* __restrict__ WB, const float* __restrict__ bias,
        float* __restrict__ out)
{
    constexpr int PP = 23;
    constexpr bool C32 = (CIN == 32);
    __shared__ unsigned short xs[PP*PP*CIN];
    __shared__ unsigned short ws[C32 ? 16*64*8 : 32*64*8];
    const int t = threadIdx.x;
    const int col0 = blockIdx.x*16, row0 = blockIdx.y*16, b = blockIdx.z;
    for (int e = t; e < PP*PP*(CIN/2); e += 256){
        const int ci2 = e % (CIN/2), pix = e / (CIN/2);
        int rr = row0 + pix/PP; if (rr > HIN-1) rr = HIN-1;
        int cc = col0 + pix%PP; if (cc > WIN-1) cc = WIN-1;
        const float* gp = &in[((long)(b*CIN + 2*ci2)*HIN + rr)*WIN + cc];
        const unsigned lo = f2bf_u(gp[0]);
        const unsigned hi = f2bf_u(gp[(long)HIN*WIN]);
        ((unsigned*)xs)[pix*(CIN/2) + ci2] = lo | (hi << 16);
    }
    const int wave = t>>6, lane = t&63;
    const int quad = lane>>4, n16 = lane&15;
    const float bv = bias[n16];
    f32x4 acc[4];
    #pragma unroll
    for (int mt=0;mt<4;mt++) acc[mt] = (f32x4){bv,bv,bv,bv};
    if constexpr (C32){
        for (int ch=0; ch<4; ch++){
            __syncthreads();
            const unsigned* src = (const unsigned*)WB + ch*4096;
            for (int e=t; e<4096; e+=256) ((unsigned*)ws)[e] = src[e];
            __syncthreads();
            #pragma unroll 1
            for (int tap=0; tap<16; tap++){
                const int tg = ch*16+tap, ky = tg>>3, kx = tg&7;
                const short8 bw = *(const short8*)&ws[(tap*64+lane)*8];
                #pragma unroll
                for (int mt=0; mt<4; mt++){
                    const int pr = wave*4+mt+ky, pc = n16+kx;
                    const short8 av = *(const short8*)&xs[(pr*PP+pc)*32 + quad*8];
                    acc[mt] = __builtin_amdgcn_mfma_f32_16x16x32_bf16(av, bw, acc[mt], 0,0,0);
                }
            }
        }
    } else {
        for (int e=t; e<8192; e+=256) ((unsigned*)ws)[e] = ((const unsigned*)WB)[e];
        __syncthreads();
        #pragma unroll 1
        for (int pair=0; pair<32; pair++){
            const int ky = pair>>2, kx0 = (pair&3)*2;
            const short8 bw = *(const short8*)&ws[(pair*64+lane)*8];
            #pragma unroll
            for (int mt=0; mt<4; mt++){
                const int pr = wave*4+mt+ky, pc = n16 + kx0 + (quad>>1);
                const short8 av = *(const short8*)&xs[(pr*PP+pc)*16 + (quad&1)*8];
                acc[mt] = __builtin_amdgcn_mfma_f32_16x16x32_bf16(av, bw, acc[mt], 0,0,0);
            }
        }
    }
    #pragma unroll
    for (int mt=0; mt<4; mt++){
        const int orow = row0 + wave*4 + mt;
        if (orow >= HOUT) continue;
        const int ocol = col0 + quad*4;
        float* op = out + ((long)(b*16 + n16)*HOUT + orow)*WOUT + ocol;
        #pragma unroll
        for (int r=0;r<4;r++){
            if (ocol + r < WOUT) op[r] = fmaxf(acc[mt][r], 0.f);
        }
    }
}

// ---------------- generic direct conv (+relu) for the small conv4/conv5 ----------------
template<int CIN, int COUT, int KS, int STRIDE, int HIN, int WIN, int HOUT, int WOUT, int NG>
__global__ __launch_bounds__(256) void k_convN(const float* __restrict__ in,
        const float* __restrict__ w, const float* __restrict__ bias, float* __restrict__ out)
{
    __shared__ float wl[CIN*KS*KS];
    const int co = blockIdx.y, b = blockIdx.z;
    for (int j=threadIdx.x; j<CIN*KS*KS; j+=blockDim.x) wl[j] = w[co*CIN*KS*KS + j];
    __syncthreads();
    const int i = blockIdx.x*blockDim.x + threadIdx.x;
    if (i >= HOUT*NG) return;
    const int y = i / NG, x0 = (i % NG) * 8;
    float acc[8];
    const float bv = bias[co];
    #pragma unroll
    for (int j=0;j<8;j++) acc[j]=bv;
    constexpr int SPAN = STRIDE*7 + KS;
    for (int ci=0; ci<CIN; ci++){
        #pragma unroll 1
        for (int ky=0; ky<KS; ky++){
            const float* ip = in + ((b*CIN+ci)*HIN + (STRIDE*y+ky))*WIN + STRIDE*x0;
            float v[SPAN];
            #pragma unroll
            for (int j=0;j<SPAN;j++) v[j]=ip[j];
            const float* wr = &wl[(ci*KS+ky)*KS];
            #pragma unroll
            for (int kx=0;kx<KS;kx++){
                const float wv = wr[kx];
                #pragma unroll
                for (int j=0;j<8;j++) acc[j] = fmaf(v[STRIDE*j+kx], wv, acc[j]);
            }
        }
    }
    float* op = out + ((b*COUT+co)*HOUT + y)*WOUT + x0;
    #pragma unroll
    for (int j=0;j<8;j++){
        if (x0 + j < WOUT) op[j] = fmaxf(acc[j], 0.f);
    }
}

// ---------------- FC via MFMA, 2-deep software-pipelined loads ----------------
__global__ void k_binit(float* __restrict__ y, const float* __restrict__ bias, int N)
{
    const int i = blockIdx.x*256 + threadIdx.x;
    if (i < 32*N) y[i] = bias[i % N];
}

template<typename WT>
__device__ __forceinline__ void fcm_loop(const float* __restrict__ xp, const WT* __restrict__ wp,
        int start, int end, int quad, int relu_in, f32x4& acc)
{
    const int nfull = (end - start) >> 5;
    const int end32 = start + (nfull << 5);
    const int qo = quad*8;

    // two named register sets (A/B) — static indexing only (no runtime-indexed arrays)
    f32x4 xA0, xA1, xB0, xB1;
    short8 bwA, bwB;
    f32x4 wA0, wA1, wB0, wB1;   // float-weight path only

    auto loadA = [&](int k0){
        const int ka = k0 + qo;
        xA0 = *(const f32x4*)&xp[ka];
        xA1 = *(const f32x4*)&xp[ka+4];
        if constexpr (__is_same(WT, bf16)){
            bwA = *(const short8*)&wp[ka];
        } else {
            wA0 = *(const f32x4*)&wp[ka];
            wA1 = *(const f32x4*)&wp[ka+4];
        }
    };
    auto loadB = [&](int k0){
        const int ka = k0 + qo;
        xB0 = *(const f32x4*)&xp[ka];
        xB1 = *(const f32x4*)&xp[ka+4];
        if constexpr (__is_same(WT, bf16)){
            bwB = *(const short8*)&wp[ka];
        } else {
            wB0 = *(const f32x4*)&wp[ka];
            wB1 = *(const f32x4*)&wp[ka+4];
        }
    };
    auto compA = [&](){
        float xv[8];
        *(f32x4*)&xv[0] = xA0; *(f32x4*)&xv[4] = xA1;
        if (relu_in){
            #pragma unroll
            for (int j=0;j<8;j++) xv[j] = fmaxf(xv[j], 0.f);
        }
        short8 bw;
        if constexpr (__is_same(WT, bf16)) bw = bwA;
        else { float wv[8]; *(f32x4*)&wv[0]=wA0; *(f32x4*)&wv[4]=wA1; bw = pack8(wv); }
        acc = __builtin_amdgcn_mfma_f32_16x16x32_bf16(pack8(xv), bw, acc, 0,0,0);
    };
    auto compB = [&](){
        float xv[8];
        *(f32x4*)&xv[0] = xB0; *(f32x4*)&xv[4] = xB1;
        if (relu_in){
            #pragma unroll
            for (int j=0;j<8;j++) xv[j] = fmaxf(xv[j], 0.f);
        }
        short8 bw;
        if constexpr (__is_same(WT, bf16)) bw = bwB;
        else { float wv[8]; *(f32x4*)&wv[0]=wB0; *(f32x4*)&wv[4]=wB1; bw = pack8(wv); }
        acc = __builtin_amdgcn_mfma_f32_16x16x32_bf16(pack8(xv), bw, acc, 0,0,0);
    };

    if (nfull > 0){
        loadA(start);               // chunk 0 in flight
        int i = 1;
        for (; i + 2 <= nfull; i += 2){
            loadB(start + (i<<5));          // issue chunk i while chunk i-1 computes
            compA();
            loadA(start + ((i+1)<<5));      // issue chunk i+1 while chunk i computes
            compB();
        }
        if (i < nfull){             // one remaining (i == nfull-1)
            loadB(start + (i<<5));
            compA();
            compB();
        } else {
            compA();
        }
    }
    if (end32 < end){
        const int ka = end32 + qo;
        float xv[8], wv[8];
        #pragma unroll
        for (int j=0;j<8;j++){
            const bool v = (ka + j) < end;
            xv[j] = v ? xp[ka+j] : 0.f;
            wv[j] = v ? (float)ld(wp, ka+j) : 0.f;
            if (relu_in) xv[j] = fmaxf(xv[j], 0.f);
        }
        acc = __builtin_amdgcn_mfma_f32_16x16x32_bf16(pack8(xv), pack8(wv), acc, 0,0,0);
    }
}

__global__ __launch_bounds__(256,4) void k_fcM(const float* __restrict__ x,
        const void* __restrict__ w, const int* __restrict__ flag,
        float* __restrict__ y, int K, int N, int Kc, int relu_in, int Nvalid)
{
    const int t = threadIdx.x;
    const int wave = t>>6, lane = t&63;
    const int quad = lane>>4, n16 = lane&15;
    const int og = wave>>1, bh = wave&1;
    const int o = blockIdx.x*32 + og*16 + n16;
    const int orow = (o < Nvalid) ? o : (Nvalid-1);
    const int xrow = bh*16 + n16;
    const int start = blockIdx.y*Kc;
    const int end = min(K, start + Kc);
    f32x4 acc = {0.f,0.f,0.f,0.f};
    const float* xp = x + (long)xrow*K;
    if (*flag) fcm_loop<float>(xp, (const float*)w + (long)orow*K, start, end, quad, relu_in, acc);
    else       fcm_loop<bf16 >(xp, (const bf16 *)w + (long)orow*K, start, end, quad, relu_in, acc);
    if (o < Nvalid){
        #pragma unroll
        for (int r=0;r<4;r++)
            atomicAdd(&y[(long)(bh*16 + quad*4 + r)*N + o], acc[r]);
    }
}

// ---------------- paired log_softmax over axis 1 of [32,2,12] ----------------
__global__ void k_lsm(const float* __restrict__ in, const int* __restrict__ flag,
                      void* __restrict__ out)
{
    const int i = threadIdx.x;
    if (i >= 384) return;
    const int b = i/12, au = i%12;
    const float a0 = in[b*24+au], a1 = in[b*24+12+au];
    const float m = fmaxf(a0,a1);
    const float lse = m + logf(expf(a0-m)+expf(a1-m));
    const float o0 = a0-lse, o1 = a1-lse;
    if (*flag){
        ((float*)out)[b*24+au]    = o0;
        ((float*)out)[b*24+12+au] = o1;
    } else {
        ((bf16*)out)[b*24+au]    = __float2bfloat16(o0);
        ((bf16*)out)[b*24+12+au] = __float2bfloat16(o1);
    }
}

extern "C" void kernel_launch(void* const* d_in, const int* in_sizes, int n_in,
                              void* d_out, int out_size, void* d_ws, size_t ws_size,
                              hipStream_t stream) {
    (void)in_sizes; (void)n_in; (void)out_size; (void)ws_size;
    const void* x = d_in[0];

    float* A = (float*)d_ws;               // 26,214,400 floats
    float* B = A + 26214400;               //  6,553,600 floats
    float* P = B + 6553600;                //  P_END floats
    int* flag = (int*)(P + P_END);

    CvtArgs a;
    const int src_idx[23] = {1,2,3,4,5,6,7,8,9,10,11,12,13,14,15,16,17,18,19,20,22,24,26};
    const int offs[23] = {OFF_C1W,OFF_C1B,OFF_RLG,OFF_RLB,OFF_RLM,OFF_RLV,OFF_RLCW,OFF_RLCB,
                          OFF_BNG,OFF_BNB,OFF_BNM,OFF_BNV,OFF_C2W,OFF_C2B,OFF_C3W,OFF_C3B,
                          OFF_C4W,OFF_C4B,OFF_C5W,OFF_C5B,OFF_F1B,OFF_F2B,OFF_F3B};
    for (int j=0;j<23;j++){ a.src[j] = d_in[src_idx[j]]; a.off[j] = offs[j]; }
    a.cw = d_in[7]; a.w2 = d_in[13]; a.w3 = d_in[15];
    a.total = P_TOTAL;

    k_sniff<<<1,256,0,stream>>>(x, flag);
    k_cvt<<<(P_TOTAL+SZ_RL+SZ_WB2+SZ_WB3+SZ_WC1+255)/256,256,0,stream>>>(a, flag, P);
    k_conv1M<<<dim3(20,5,32),256,0,stream>>>(x, flag, P, A);
    k_regionM<<<2048,256,0,stream>>>(A, P, B);
    // conv2: [32,32,80,80] -> [32,16,73,73]  (MFMA)
    k_convM<32,80,80,73,73><<<dim3(5,5,32),256,0,stream>>>(B, (const unsigned short*)(P+OFF_WB2), P+OFF_C2B, A);
    // conv3: -> [32,16,66,66]  (MFMA)
    k_convM<16,73,73,66,66><<<dim3(5,5,32),256,0,stream>>>(A, (const unsigned short*)(P+OFF_WB3), P+OFF_C3B, B);
    // conv4: stride 2 -> [32,16,31,31]
    k_convN<16,16,6,2,66,66,31,31,4><<<dim3(1,16,32),128,0,stream>>>(B, P+OFF_C4W, P+OFF_C4B, A);
    // conv5: -> [32,16,27,27]
    k_convN<16,16,5,1,31,31,27,27,4><<<dim3(1,16,32),128,0,stream>>>(A, P+OFF_C5W, P+OFF_C5B, B);
    // fc1: K=11664 -> 4096; x=B, y=A  (8 K-splits, Kc=46*32)
    k_binit<<<(32*4096+255)/256,256,0,stream>>>(A, P+OFF_F1B, 4096);
    k_fcM<<<dim3(128,8),256,0,stream>>>(B, d_in[21], flag, A, 11664, 4096, 1472, 0, 4096);
    // fc2: K=4096 -> 2048; relu-on-load, y=B  (16 K-splits, Kc=8*32)
    k_binit<<<(32*2048+255)/256,256,0,stream>>>(B, P+OFF_F2B, 2048);
    k_fcM<<<dim3(64,16),256,0,stream>>>(A, d_in[23], flag, B, 4096, 2048, 256, 1, 2048);
    // fc3: K=2048 -> 24; relu-on-load, y=A
    k_binit<<<(32*24+255)/256,256,0,stream>>>(A, P+OFF_F3B, 24);
    k_fcM<<<dim3(1,64),256,0,stream>>>(B, d_in[25], flag, A, 2048, 24, 32, 1, 24);
    k_lsm<<<1,384,0,stream>>>(A, flag, d_out);
}

// Round 2
// 720.787 us; speedup vs baseline: 1.0509x; 1.0143x over previous
//
#include <hip/hip_runtime.h>
#include <hip/hip_bf16.h>

typedef __hip_bfloat16 bf16;
typedef __attribute__((ext_vector_type(8))) short short8;
typedef __attribute__((ext_vector_type(4))) float f32x4;
typedef __attribute__((ext_vector_type(16))) float f32x16;

__device__ __forceinline__ float b2f(const bf16 v){ return __bfloat162float(v); }
__device__ __forceinline__ float ld(const float* p, long i){ return p[i]; }
__device__ __forceinline__ float ld(const bf16*  p, long i){ return b2f(p[i]); }

__device__ __forceinline__ unsigned f2bf_u(float f){
    union { float f; unsigned u; } a; a.f = f;
    unsigned r = a.u + 0x7FFFu + ((a.u >> 16) & 1u);
    return r >> 16;
}

__device__ __forceinline__ short8 pack8(const float* v){
    // RNE pack via v_cvt_pk_bf16_f32 (compiler emits the packed cvt)
    union { __hip_bfloat162 h[4]; short8 s; } r;
    #pragma unroll
    for (int i=0;i<4;i++)
        r.h[i] = __float22bfloat162_rn(float2{v[2*i], v[2*i+1]});
    return r.s;
}

// ---- converted-params block offsets (floats) within P ----
#define OFF_C1W   0        /* 11616 */
#define OFF_C1B   11616    /* 32   */
#define OFF_RLG   11648    /* 2048 */
#define OFF_RLB   13696
#define OFF_RLM   15744
#define OFF_RLV   17792
#define OFF_RLCW  19840    /* 589824 slots: bf16 WR [net][tap9][half2][lane64][j8] */
#define OFF_RLCB  609664   /* 2048 */
#define OFF_BNG   611712
#define OFF_BNB   611744
#define OFF_BNM   611776
#define OFF_BNV   611808
#define OFF_C2W   611840   /* 32768 */
#define OFF_C2B   644608
#define OFF_C3W   644624   /* 16384 */
#define OFF_C3B   661008
#define OFF_C4W   661024   /* 9216 */
#define OFF_C4B   670240
#define OFF_C5W   670256   /* 6400 */
#define OFF_C5B   676656
#define OFF_F1B   676672   /* 4096 */
#define OFF_F2B   680768   /* 2048 */
#define OFF_F3B   682816   /* 24   */
#define P_TOTAL   682840
#define OFF_WB2   P_TOTAL             /* 32768 bf16 = 16384 f32 slots */
#define OFF_WB3   (P_TOTAL + 16384)   /* 16384 bf16 = 8192 f32 slots  */
#define OFF_WC1   (P_TOTAL + 16384 + 8192)  /* 16896 bf16 = 8448 f32 slots */
#define P_END     (OFF_WC1 + 8448)

#define SZ_RL  589824
#define SZ_WB2 32768
#define SZ_WB3 16384
#define SZ_WC1 16896

// ---------- dtype sniff: flag=1 if inputs are float32, 0 if bf16 ----------
__global__ void k_sniff(const void* __restrict__ x, int* __restrict__ flag)
{
    const bf16* xb = (const bf16*)x;
    const float v = fabsf(b2f(xb[2*threadIdx.x]));
    const int ok = (v >= 1e-6f && v <= 1e6f) ? 1 : 0;
    __shared__ int cnt;
    if (threadIdx.x == 0) cnt = 0;
    __syncthreads();
    atomicAdd(&cnt, ok);
    __syncthreads();
    if (threadIdx.x == 0) *flag = (cnt >= 192) ? 0 : 1;
}

// ---------- convert params to f32 block P + bf16 fragment-layout weight blocks ----------
struct CvtArgs { const void* src[23]; int off[23]; const void* cw; const void* w2; const void* w3; int total; };

__device__ __forceinline__ float getv(const void* p, long i, bool isf){
    return isf ? ((const float*)p)[i] : b2f(((const bf16*)p)[i]);
}

__global__ __launch_bounds__(256) void k_cvt(CvtArgs a, const int* __restrict__ flag,
                                             float* __restrict__ P)
{
    const bool isf = (*flag != 0);
    const int i1 = a.total;            // region WR frags (bf16, in rl_cw slot)
    const int i2 = i1 + SZ_RL;         // WB2
    const int i3 = i2 + SZ_WB2;        // WB3
    const int i4 = i3 + SZ_WB3;        // WC1
    const int i5 = i4 + SZ_WC1;
    for (int idx = blockIdx.x*256 + threadIdx.x; idx < i5; idx += gridDim.x*256){
        if (idx < i1){
            if (idx >= OFF_RLCW && idx < OFF_RLCB) continue;   // slot reused for WR
            int k = 0;
            #pragma unroll
            for (int j = 1; j < 23; j++) if (idx >= a.off[j]) k = j;
            P[idx] = getv(a.src[k], idx - a.off[k], isf);
        } else if (idx < i2){
            // WR[net][tap][half][lane][j]: A-frag (weights, M=co16) for region
            const int d = idx - i1;
            const int net = d / 9216, dn = d % 9216;
            const int tap = dn >> 10, rem = dn & 1023;
            const int half = rem >> 9, lane = (rem >> 3) & 63, j = rem & 7;
            const int co = half*16 + (lane & 15);
            const int ci = ((lane >> 4) << 3) + j;
            const long sidx = (long)((net*32 + co)*32 + ci)*9 + tap;
            ((unsigned short*)(P + OFF_RLCW))[d] = (unsigned short)f2bf_u(getv(a.cw, sidx, isf));
        } else if (idx < i3){
            // WB2[tap][lane][j]: B-frag layout for conv2 (K=32ci)
            const int d = idx - i2;
            const int j = d & 7, lane = (d >> 3) & 63, tap = d >> 9;
            const int n = lane & 15, k = ((lane >> 4) << 3) + j;
            const int ci = k, ky = tap >> 3, kx = tap & 7;
            const long sidx = (long)((n*32 + ci)*8 + ky)*8 + kx;
            ((unsigned short*)(P + OFF_WB2))[d] = (unsigned short)f2bf_u(getv(a.w2, sidx, isf));
        } else if (idx < i4){
            // WB3[pair][lane][j]: B-frag layout for conv3 (K=16ci x 2 taps)
            const int d = idx - i3;
            const int j = d & 7, lane = (d >> 3) & 63, pair = d >> 9;
            const int n = lane & 15, k = ((lane >> 4) << 3) + j;
            const int tsel = k >> 4, ci = k & 15;
            const int ky = pair >> 2, kx = ((pair & 3) << 1) + tsel;
            const long sidx = (long)((n*16 + ci)*8 + ky)*8 + kx;
            ((unsigned short*)(P + OFF_WB3))[d] = (unsigned short)f2bf_u(getv(a.w3, sidx, isf));
        } else {
            // WC1[ky][ch][lane][j]: A-frag (weights, M=co32) for conv1, K=16 = 4kx x 4ci
            const int d = idx - i4;
            const int ky = d / 1536, rem = d % 1536;
            const int ch = rem >> 9, rem2 = rem & 511;
            const int lane = rem2 >> 3, j = rem2 & 7;
            const int co = lane & 31, h5 = lane >> 5;
            const int kx = ch*4 + h5*2 + (j >> 2), ci = j & 3;
            float v = 0.f;
            if (ci < 3 && kx < 11)
                v = getv(a.src[0], (long)((co*3 + ci)*11 + ky)*11 + kx, isf);
            ((unsigned short*)(P + OFF_WC1))[d] = (unsigned short)f2bf_u(v);
        }
    }
}

// ---------------- conv1 via 32x32x16 MFMA: x[32,3,170,170] -> [32,32,160,160] ----------------
// block = (8-row group, 32-col tile, b); wave = 2 row-strips; A=W[co32][k16], B=X[k16][pix32]
__global__ __launch_bounds__(256,3) void k_conv1M(const void* __restrict__ x,
        const int* __restrict__ flag, const float* __restrict__ P, float* __restrict__ out)
{
    __shared__ unsigned short xs[18*44*4];     // [row18][col44][ci4] bf16, 6336 B
    __shared__ unsigned short wsm[SZ_WC1];     // 33792 B
    const int t = threadIdx.x;
    const int y0 = blockIdx.x*8, x0 = blockIdx.y*32, b = blockIdx.z;
    { const uint4* src = (const uint4*)(P + OFF_WC1);
      uint4* dst = (uint4*)wsm;
      for (int e=t; e<2112; e+=256) dst[e] = src[e]; }
    const bool isf = (*flag) != 0;
    for (int e=t; e<792; e+=256){
        const int r = e/44, c = e%44;
        const long base = ((long)(b*3)*170 + (y0+r))*170 + min(x0+c, 169);
        float v0, v1, v2;
        if (isf){
            const float* xf = (const float*)x;
            v0 = xf[base]; v1 = xf[base+28900]; v2 = xf[base+57800];
        } else {
            const bf16* xf = (const bf16*)x;
            v0 = b2f(xf[base]); v1 = b2f(xf[base+28900]); v2 = b2f(xf[base+57800]);
        }
        uint2 u;
        u.x = f2bf_u(v0) | (f2bf_u(v1) << 16);
        u.y = f2bf_u(v2);
        *(uint2*)&xs[(r*44+c)*4] = u;
    }
    __syncthreads();
    const int wave = t>>6, lane = t&63;
    const int n = lane & 31, h5 = lane >> 5;
    const int r0 = wave*2;
    f32x16 acc0 = {0.f}, acc1 = {0.f};
    #pragma unroll
    for (int e=0;e<16;e++){ acc0[e]=0.f; acc1[e]=0.f; }
    #pragma unroll 1
    for (int ky=0; ky<11; ky++){
        #pragma unroll
        for (int ch=0; ch<3; ch++){
            const short8 aw = *(const short8*)&wsm[((ky*3+ch)*64 + lane)*8];
            const int kx0 = ch*4 + h5*2;
            const int a0 = ((r0+ky)*44 + n + kx0)*4;
            const int a1 = ((r0+1+ky)*44 + n + kx0)*4;
            union { uint2 u2[2]; short8 s; } ub0, ub1;
            ub0.u2[0] = *(const uint2*)&xs[a0];
            ub0.u2[1] = *(const uint2*)&xs[a0+4];
            ub1.u2[0] = *(const uint2*)&xs[a1];
            ub1.u2[1] = *(const uint2*)&xs[a1+4];
            acc0 = __builtin_amdgcn_mfma_f32_32x32x16_bf16(aw, ub0.s, acc0, 0,0,0);
            acc1 = __builtin_amdgcn_mfma_f32_32x32x16_bf16(aw, ub1.s, acc1, 0,0,0);
        }
    }
    // D: col = lane&31 = pixel-col, row(co) = (reg&3) + 8*(reg>>2) + 4*h5
    #pragma unroll
    for (int reg=0; reg<16; reg++){
        const int co = (reg&3) + 8*(reg>>2) + 4*h5;
        const float bv = P[OFF_C1B + co];
        float* op = out + ((long)(b*32+co)*160 + (y0+r0))*160 + x0 + n;
        op[0]   = acc0[reg] + bv;
        op[160] = acc1[reg] + bv;
    }
}

// ------- region layer via 16x16x32 MFMA, fused relu+maxpool2+bn with shuffle pooling -------
// block = (patch, batch); A=W[co16][ci32] (2 halves), B=X[ci32][pix16] (4x4 tiles)
__global__ __launch_bounds__(256,2) void k_regionM(const float* __restrict__ in,
        const float* __restrict__ P, float* __restrict__ pooled)
{
    __shared__ unsigned short s_in[484*32];    // [pix 22x22][ci32] bf16, 30976 B
    __shared__ unsigned short wsm[9216];       // [tap9][half2][lane64][j8], 18432 B
    __shared__ float sc[32], sh[32];
    const int t = threadIdx.x;
    const int b = blockIdx.x & 31, kk = blockIdx.x >> 5;
    const int gi = kk >> 3, gj = kk & 7;
    const int net = gj*(gi+1);                 // idx = ii*jj + jj
    const int ibase = (b*32*160 + gi*20)*160 + gj*20;
    if (t < 32){
        const float inv = rsqrtf(P[OFF_RLV+net*32+t]+1e-5f)*P[OFF_RLG+net*32+t];
        sc[t] = inv; sh[t] = P[OFF_RLB+net*32+t] - P[OFF_RLM+net*32+t]*inv;
    }
    { const uint4* src = (const uint4*)((const unsigned short*)(P+OFF_RLCW) + (size_t)net*9216);
      uint4* dst = (uint4*)wsm;
      for (int e=t; e<1152; e+=256) dst[e] = src[e]; }
    __syncthreads();
    // stage BN+ReLU patch, zero halo: item = (pixel, ci-oct) -> one b128 LDS write
    for (int e=t; e<1936; e+=256){
        const int o = e & 3, p = e >> 2;
        const int pr = p/22, pc = p%22;
        unsigned ov[4] = {0u,0u,0u,0u};
        if (pr>0 && pr<21 && pc>0 && pc<21){
            const int base = ibase + (pr-1)*160 + (pc-1);
            #pragma unroll
            for (int q2=0;q2<4;q2++){
                const int ci0 = o*8 + q2*2;
                float v0 = in[base + ci0*25600];
                float v1 = in[base + (ci0+1)*25600];
                v0 = fmaxf(fmaf(v0, sc[ci0],   sh[ci0]),   0.f);
                v1 = fmaxf(fmaf(v1, sc[ci0+1], sh[ci0+1]), 0.f);
                ov[q2] = f2bf_u(v0) | (f2bf_u(v1) << 16);
            }
        }
        *(uint4*)&s_in[p*32 + o*8] = *(const uint4*)ov;
    }
    __syncthreads();
    const int wave = t>>6, lane = t&63;
    const int q = lane>>4, n = lane&15;
    const int dr = n>>2, dc = n&3;
    const int nt = (wave==0) ? 7 : 6;          // 25 tiles over 4 waves
    int trs[7], tcs[7];
    #pragma unroll
    for (int i=0;i<7;i++){ const int tt = 4*i + wave; trs[i] = tt/5; tcs[i] = tt - 5*(tt/5); }
    f32x4 acc[7][2];
    {   float bias_v[2][4];
        #pragma unroll
        for (int h=0;h<2;h++)
            #pragma unroll
            for (int r=0;r<4;r++) bias_v[h][r] = P[OFF_RLCB + net*32 + h*16 + q*4 + r];
        #pragma unroll
        for (int i=0;i<7;i++)
            #pragma unroll
            for (int h=0;h<2;h++)
                acc[i][h] = (f32x4){bias_v[h][0], bias_v[h][1], bias_v[h][2], bias_v[h][3]};
    }
    #pragma unroll 1
    for (int tap=0; tap<9; tap++){
        const int ky = tap/3, kx = tap - 3*(tap/3);
        const short8 a0 = *(const short8*)&wsm[(tap*2+0)*512 + lane*8];
        const short8 a1 = *(const short8*)&wsm[(tap*2+1)*512 + lane*8];
        #pragma unroll
        for (int i=0;i<7;i++){
            if (i < nt){
                const int srow = trs[i]*4 + dr + ky, scol = tcs[i]*4 + dc + kx;
                const short8 bx = *(const short8*)&s_in[(srow*22 + scol)*32 + q*8];
                acc[i][0] = __builtin_amdgcn_mfma_f32_16x16x32_bf16(a0, bx, acc[i][0], 0,0,0);
                acc[i][1] = __builtin_amdgcn_mfma_f32_16x16x32_bf16(a1, bx, acc[i][1], 0,0,0);
            }
        }
    }
    // epilogue: residual + relu + 2x2 shuffle-pool + bn;  D: col=n=pixel, row=co=q*4+reg
    float bnsc[2][4], bnsh[2][4];
    #pragma unroll
    for (int h=0;h<2;h++)
        #pragma unroll
        for (int r=0;r<4;r++){
            const int co = h*16 + q*4 + r;
            const float inv = rsqrtf(P[OFF_BNV+co]+1e-5f)*P[OFF_BNG+co];
            bnsc[h][r] = inv; bnsh[h][r] = P[OFF_BNB+co] - P[OFF_BNM+co]*inv;
        }
    const bool wr = ((n & 5) == 0);            // dc even && dr even
    #pragma unroll
    for (int i=0;i<7;i++){
        if (i < nt){
            const int prow = trs[i]*4 + dr, pcol = tcs[i]*4 + dc;
            #pragma unroll
            for (int h=0;h<2;h++){
                #pragma unroll
                for (int r=0;r<4;r++){
                    const int co = h*16 + q*4 + r;
                    float v = acc[i][h][r] + in[ibase + co*25600 + prow*160 + pcol];
                    v = fmaxf(v, 0.f);
                    v = fmaxf(v, __shfl_xor(v, 1, 64));
                    v = fmaxf(v, __shfl_xor(v, 4, 64));
                    if (wr){
                        pooled[((b*32+co)*80 + gi*10 + trs[i]*2 + (dr>>1))*80
                               + gj*10 + tcs[i]*2 + (dc>>1)] = fmaf(v, bnsc[h][r], bnsh[h][r]);
                    }
                }
            }
        }
    }
}

// ------- conv2/conv3 via MFMA shift-GEMM (validated in R3) -------
template<int CIN, int HIN, int WIN, int HOUT, int WOUT>
__global__ __launch_bounds__(256) void k_convM(const float* __restrict__ in,
        const unsigned short* __restrict__ WB, const float* __restrict__ bias,
        float* __restrict__ out)
{
    constexpr int PP = 23;
    constexpr bool C32 = (CIN == 32);
    __shared__ unsigned short xs[PP*PP*CIN];
    __shared__ unsigned short ws[C32 ? 16*64*8 : 32*64*8];
    const int t = threadIdx.x;
    const int col0 = blockIdx.x*16, row0 = blockIdx.y*16, b = blockIdx.z;
    for (int e = t; e < PP*PP*(CIN/2); e += 256){
        const int ci2 = e % (CIN/2), pix = e / (CIN/2);
        int rr = row0 + pix/PP; if (rr > HIN-1) rr = HIN-1;
        int cc = col0 + pix%PP; if (cc > WIN-1) cc = WIN-1;
        const float* gp = &in[((long)(b*CIN + 2*ci2)*HIN + rr)*WIN + cc];
        const unsigned lo = f2bf_u(gp[0]);
        const unsigned hi = f2bf_u(gp[(long)HIN*WIN]);
        ((unsigned*)xs)[pix*(CIN/2) + ci2] = lo | (hi << 16);
    }
    const int wave = t>>6, lane = t&63;
    const int quad = lane>>4, n16 = lane&15;
    const float bv = bias[n16];
    f32x4 acc[4];
    #pragma unroll
    for (int mt=0;mt<4;mt++) acc[mt] = (f32x4){bv,bv,bv,bv};
    if constexpr (C32){
        for (int ch=0; ch<4; ch++){
            __syncthreads();
            const unsigned* src = (const unsigned*)WB + ch*4096;
            for (int e=t; e<4096; e+=256) ((unsigned*)ws)[e] = src[e];
            __syncthreads();
            #pragma unroll 1
            for (int tap=0; tap<16; tap++){
                const int tg = ch*16+tap, ky = tg>>3, kx = tg&7;
                const short8 bw = *(const short8*)&ws[(tap*64+lane)*8];
                #pragma unroll
                for (int mt=0; mt<4; mt++){
                    const int pr = wave*4+mt+ky, pc = n16+kx;
                    const short8 av = *(const short8*)&xs[(pr*PP+pc)*32 + quad*8];
                    acc[mt] = __builtin_amdgcn_mfma_f32_16x16x32_bf16(av, bw, acc[mt], 0,0,0);
                }
            }
        }
    } else {
        for (int e=t; e<8192; e+=256) ((unsigned*)ws)[e] = ((const unsigned*)WB)[e];
        __syncthreads();
        #pragma unroll 1
        for (int pair=0; pair<32; pair++){
            const int ky = pair>>2, kx0 = (pair&3)*2;
            const short8 bw = *(const short8*)&ws[(pair*64+lane)*8];
            #pragma unroll
            for (int mt=0; mt<4; mt++){
                const int pr = wave*4+mt+ky, pc = n16 + kx0 + (quad>>1);
                const short8 av = *(const short8*)&xs[(pr*PP+pc)*16 + (quad&1)*8];
                acc[mt] = __builtin_amdgcn_mfma_f32_16x16x32_bf16(av, bw, acc[mt], 0,0,0);
            }
        }
    }
    #pragma unroll
    for (int mt=0; mt<4; mt++){
        const int orow = row0 + wave*4 + mt;
        if (orow >= HOUT) continue;
        const int ocol = col0 + quad*4;
        float* op = out + ((long)(b*16 + n16)*HOUT + orow)*WOUT + ocol;
        #pragma unroll
        for (int r=0;r<4;r++){
            if (ocol + r < WOUT) op[r] = fmaxf(acc[mt][r], 0.f);
        }
    }
}

// ---------------- generic direct conv (+relu) for the small conv4/conv5 ----------------
template<int CIN, int COUT, int KS, int STRIDE, int HIN, int WIN, int HOUT, int WOUT, int NG>
__global__ __launch_bounds__(256) void k_convN(const float* __restrict__ in,
        const float* __restrict__ w, const float* __restrict__ bias, float* __restrict__ out)
{
    __shared__ float wl[CIN*KS*KS];
    const int co = blockIdx.y, b = blockIdx.z;
    for (int j=threadIdx.x; j<CIN*KS*KS; j+=blockDim.x) wl[j] = w[co*CIN*KS*KS + j];
    __syncthreads();
    const int i = blockIdx.x*blockDim.x + threadIdx.x;
    if (i >= HOUT*NG) return;
    const int y = i / NG, x0 = (i % NG) * 8;
    float acc[8];
    const float bv = bias[co];
    #pragma unroll
    for (int j=0;j<8;j++) acc[j]=bv;
    constexpr int SPAN = STRIDE*7 + KS;
    for (int ci=0; ci<CIN; ci++){
        #pragma unroll 1
        for (int ky=0; ky<KS; ky++){
            const float* ip = in + ((b*CIN+ci)*HIN + (STRIDE*y+ky))*WIN + STRIDE*x0;
            float v[SPAN];
            #pragma unroll
            for (int j=0;j<SPAN;j++) v[j]=ip[j];
            const float* wr = &wl[(ci*KS+ky)*KS];
            #pragma unroll
            for (int kx=0;kx<KS;kx++){
                const float wv = wr[kx];
                #pragma unroll
                for (int j=0;j<8;j++) acc[j] = fmaf(v[STRIDE*j+kx], wv, acc[j]);
            }
        }
    }
    float* op = out + ((b*COUT+co)*HOUT + y)*WOUT + x0;
    #pragma unroll
    for (int j=0;j<8;j++){
        if (x0 + j < WOUT) op[j] = fmaxf(acc[j], 0.f);
    }
}

// ---------------- FC via MFMA, pre-packed bf16 x + 3-deep pipelined weight stream ----------------
__global__ void k_binit(float* __restrict__ y, const float* __restrict__ bias, int N)
{
    const int i = blockIdx.x*256 + threadIdx.x;
    if (i < 32*N) y[i] = bias[i % N];
}

// pack f32 activations (optional relu) to bf16, 8 per thread
__global__ __launch_bounds__(256) void k_xpack(const float* __restrict__ in,
        unsigned short* __restrict__ out, int n8, int relu)
{
    const int i = blockIdx.x*256 + threadIdx.x;
    if (i >= n8) return;
    float v[8];
    *(f32x4*)&v[0] = *(const f32x4*)&in[i*8];
    *(f32x4*)&v[4] = *(const f32x4*)&in[i*8+4];
    if (relu){
        #pragma unroll
        for (int j=0;j<8;j++) v[j] = fmaxf(v[j], 0.f);
    }
    *(short8*)&out[i*8] = pack8(v);
}

template<typename WT>
__device__ __forceinline__ void fcm_loop(const unsigned short* __restrict__ xp,
        const WT* __restrict__ wp, int start, int end, int quad, f32x4& acc)
{
    const int nfull = (end - start) >> 5;
    const int end32 = start + (nfull << 5);
    const int qo = quad*8;

    // three named register sets — static indexing only
    short8 xA, xB, xC;
    short8 bwA, bwB, bwC;
    f32x4 wA0, wA1, wB0, wB1, wC0, wC1;   // f32-weight path only

    auto loadA = [&](int k0){
        const int ka = k0 + qo;
        xA = *(const short8*)&xp[ka];
        if constexpr (__is_same(WT, bf16)) bwA = *(const short8*)&wp[ka];
        else { wA0 = *(const f32x4*)&wp[ka]; wA1 = *(const f32x4*)&wp[ka+4]; }
    };
    auto loadB = [&](int k0){
        const int ka = k0 + qo;
        xB = *(const short8*)&xp[ka];
        if constexpr (__is_same(WT, bf16)) bwB = *(const short8*)&wp[ka];
        else { wB0 = *(const f32x4*)&wp[ka]; wB1 = *(const f32x4*)&wp[ka+4]; }
    };
    auto loadC = [&](int k0){
        const int ka = k0 + qo;
        xC = *(const short8*)&xp[ka];
        if constexpr (__is_same(WT, bf16)) bwC = *(const short8*)&wp[ka];
        else { wC0 = *(const f32x4*)&wp[ka]; wC1 = *(const f32x4*)&wp[ka+4]; }
    };
    auto compA = [&](){
        short8 bw;
        if constexpr (__is_same(WT, bf16)) bw = bwA;
        else { float wv[8]; *(f32x4*)&wv[0]=wA0; *(f32x4*)&wv[4]=wA1; bw = pack8(wv); }
        acc = __builtin_amdgcn_mfma_f32_16x16x32_bf16(xA, bw, acc, 0,0,0);
    };
    auto compB = [&](){
        short8 bw;
        if constexpr (__is_same(WT, bf16)) bw = bwB;
        else { float wv[8]; *(f32x4*)&wv[0]=wB0; *(f32x4*)&wv[4]=wB1; bw = pack8(wv); }
        acc = __builtin_amdgcn_mfma_f32_16x16x32_bf16(xB, bw, acc, 0,0,0);
    };
    auto compC = [&](){
        short8 bw;
        if constexpr (__is_same(WT, bf16)) bw = bwC;
        else { float wv[8]; *(f32x4*)&wv[0]=wC0; *(f32x4*)&wv[4]=wC1; bw = pack8(wv); }
        acc = __builtin_amdgcn_mfma_f32_16x16x32_bf16(xC, bw, acc, 0,0,0);
    };

    if (nfull >= 3){
        loadA(start); loadB(start+32); loadC(start+64);
        int j = 0;
        for (; j + 6 <= nfull; j += 3){
            compA(); loadA(start + ((j+3)<<5));
            compB(); loadB(start + ((j+4)<<5));
            compC(); loadC(start + ((j+5)<<5));
        }
        const int rem = nfull - j;   // 3, 4, or 5
        if (rem == 3){ compA(); compB(); compC(); }
        else if (rem == 4){
            compA(); loadA(start + ((j+3)<<5));
            compB(); compC(); compA();
        } else {
            compA(); loadA(start + ((j+3)<<5));
            compB(); loadB(start + ((j+4)<<5));
            compC(); compA(); compB();
        }
    } else if (nfull == 2){
        loadA(start); loadB(start+32); compA(); compB();
    } else if (nfull == 1){
        loadA(start); compA();
    }
    if (end32 < end){
        const int ka = end32 + qo;
        float xv[8], wv[8];
        #pragma unroll
        for (int j=0;j<8;j++){
            const bool v = (ka + j) < end;
            xv[j] = v ? b2f(((const bf16*)xp)[ka+j]) : 0.f;
            wv[j] = v ? (float)ld(wp, ka+j) : 0.f;
        }
        acc = __builtin_amdgcn_mfma_f32_16x16x32_bf16(pack8(xv), pack8(wv), acc, 0,0,0);
    }
}

__global__ __launch_bounds__(256,4) void k_fcM(const unsigned short* __restrict__ x,
        const void* __restrict__ w, const int* __restrict__ flag,
        float* __restrict__ y, int K, int N, int Kc, int Nvalid)
{
    const int t = threadIdx.x;
    const int wave = t>>6, lane = t&63;
    const int quad = lane>>4, n16 = lane&15;
    const int og = wave>>1, bh = wave&1;
    const int o = blockIdx.x*32 + og*16 + n16;
    const int orow = (o < Nvalid) ? o : (Nvalid-1);
    const int xrow = bh*16 + n16;
    const int start = blockIdx.y*Kc;
    const int end = min(K, start + Kc);
    f32x4 acc = {0.f,0.f,0.f,0.f};
    const unsigned short* xp = x + (long)xrow*K;
    if (*flag) fcm_loop<float>(xp, (const float*)w + (long)orow*K, start, end, quad, acc);
    else       fcm_loop<bf16 >(xp, (const bf16 *)w + (long)orow*K, start, end, quad, acc);
    if (o < Nvalid){
        #pragma unroll
        for (int r=0;r<4;r++)
            atomicAdd(&y[(long)(bh*16 + quad*4 + r)*N + o], acc[r]);
    }
}

// ---------------- paired log_softmax over axis 1 of [32,2,12] ----------------
__global__ void k_lsm(const float* __restrict__ in, const int* __restrict__ flag,
                      void* __restrict__ out)
{
    const int i = threadIdx.x;
    if (i >= 384) return;
    const int b = i/12, au = i%12;
    const float a0 = in[b*24+au], a1 = in[b*24+12+au];
    const float m = fmaxf(a0,a1);
    const float lse = m + logf(expf(a0-m)+expf(a1-m));
    const float o0 = a0-lse, o1 = a1-lse;
    if (*flag){
        ((float*)out)[b*24+au]    = o0;
        ((float*)out)[b*24+12+au] = o1;
    } else {
        ((bf16*)out)[b*24+au]    = __float2bfloat16(o0);
        ((bf16*)out)[b*24+12+au] = __float2bfloat16(o1);
    }
}

extern "C" void kernel_launch(void* const* d_in, const int* in_sizes, int n_in,
                              void* d_out, int out_size, void* d_ws, size_t ws_size,
                              hipStream_t stream) {
    (void)in_sizes; (void)n_in; (void)out_size; (void)ws_size;
    const void* x = d_in[0];

    float* A = (float*)d_ws;               // 26,214,400 floats
    float* B = A + 26214400;               //  6,553,600 floats
    float* P = B + 6553600;                //  P_END floats
    int* flag = (int*)(P + P_END);
    unsigned short* Xp = (unsigned short*)(P + P_END + 16);  // 373,248 bf16 max

    CvtArgs a;
    const int src_idx[23] = {1,2,3,4,5,6,7,8,9,10,11,12,13,14,15,16,17,18,19,20,22,24,26};
    const int offs[23] = {OFF_C1W,OFF_C1B,OFF_RLG,OFF_RLB,OFF_RLM,OFF_RLV,OFF_RLCW,OFF_RLCB,
                          OFF_BNG,OFF_BNB,OFF_BNM,OFF_BNV,OFF_C2W,OFF_C2B,OFF_C3W,OFF_C3B,
                          OFF_C4W,OFF_C4B,OFF_C5W,OFF_C5B,OFF_F1B,OFF_F2B,OFF_F3B};
    for (int j=0;j<23;j++){ a.src[j] = d_in[src_idx[j]]; a.off[j] = offs[j]; }
    a.cw = d_in[7]; a.w2 = d_in[13]; a.w3 = d_in[15];
    a.total = P_TOTAL;

    k_sniff<<<1,256,0,stream>>>(x, flag);
    k_cvt<<<(P_TOTAL+SZ_RL+SZ_WB2+SZ_WB3+SZ_WC1+255)/256,256,0,stream>>>(a, flag, P);
    k_conv1M<<<dim3(20,5,32),256,0,stream>>>(x, flag, P, A);
    k_regionM<<<2048,256,0,stream>>>(A, P, B);
    // conv2: [32,32,80,80] -> [32,16,73,73]  (MFMA)
    k_convM<32,80,80,73,73><<<dim3(5,5,32),256,0,stream>>>(B, (const unsigned short*)(P+OFF_WB2), P+OFF_C2B, A);
    // conv3: -> [32,16,66,66]  (MFMA)
    k_convM<16,73,73,66,66><<<dim3(5,5,32),256,0,stream>>>(A, (const unsigned short*)(P+OFF_WB3), P+OFF_C3B, B);
    // conv4: stride 2 -> [32,16,31,31]
    k_convN<16,16,6,2,66,66,31,31,4><<<dim3(1,16,32),128,0,stream>>>(B, P+OFF_C4W, P+OFF_C4B, A);
    // conv5: -> [32,16,27,27]
    k_convN<16,16,5,1,31,31,27,27,4><<<dim3(1,16,32),128,0,stream>>>(A, P+OFF_C5W, P+OFF_C5B, B);
    // fc1: K=11664 -> 4096; x = bf16(conv5 out), y=A  (16 K-splits, Kc=23*32)
    k_xpack<<<(46656+255)/256,256,0,stream>>>(B, Xp, 46656, 0);
    k_binit<<<(32*4096+255)/256,256,0,stream>>>(A, P+OFF_F1B, 4096);
    k_fcM<<<dim3(128,16),256,0,stream>>>(Xp, d_in[21], flag, A, 11664, 4096, 736, 4096);
    // fc2: K=4096 -> 2048; relu folded into pack, y=B  (16 K-splits, Kc=8*32)
    k_xpack<<<(16384+255)/256,256,0,stream>>>(A, Xp, 16384, 1);
    k_binit<<<(32*2048+255)/256,256,0,stream>>>(B, P+OFF_F2B, 2048);
    k_fcM<<<dim3(64,16),256,0,stream>>>(Xp, d_in[23], flag, B, 4096, 2048, 256, 2048);
    // fc3: K=2048 -> 24; relu folded into pack, y=A
    k_xpack<<<(8192+255)/256,256,0,stream>>>(B, Xp, 8192, 1);
    k_binit<<<(32*24+255)/256,256,0,stream>>>(A, P+OFF_F3B, 24);
    k_fcM<<<dim3(1,64),256,0,stream>>>(Xp, d_in[25], flag, A, 2048, 24, 32, 24);
    k_lsm<<<1,384,0,stream>>>(A, flag, d_out);
}

// Round 3
// 716.289 us; speedup vs baseline: 1.0575x; 1.0063x over previous
//
#include <hip/hip_runtime.h>
#include <hip/hip_bf16.h>

typedef __hip_bfloat16 bf16;
typedef __attribute__((ext_vector_type(8))) short short8;
typedef __attribute__((ext_vector_type(4))) float f32x4;
typedef __attribute__((ext_vector_type(16))) float f32x16;

__device__ __forceinline__ float b2f(const bf16 v){ return __bfloat162float(v); }
__device__ __forceinline__ float ld(const float* p, long i){ return p[i]; }
__device__ __forceinline__ float ld(const bf16*  p, long i){ return b2f(p[i]); }

__device__ __forceinline__ unsigned f2bf_u(float f){
    union { float f; unsigned u; } a; a.f = f;
    unsigned r = a.u + 0x7FFFu + ((a.u >> 16) & 1u);
    return r >> 16;
}

__device__ __forceinline__ short8 pack8(const float* v){
    // RNE pack via v_cvt_pk_bf16_f32 (compiler emits the packed cvt)
    union { __hip_bfloat162 h[4]; short8 s; } r;
    #pragma unroll
    for (int i=0;i<4;i++)
        r.h[i] = __float22bfloat162_rn(float2{v[2*i], v[2*i+1]});
    return r.s;
}

#define GLD_LDS16(g, l) __builtin_amdgcn_global_load_lds( \
    (const __attribute__((address_space(1))) void*)(g), \
    (__attribute__((address_space(3))) void*)(l), 16, 0, 0)

// ---- converted-params block offsets (floats) within P ----
#define OFF_C1W   0        /* 11616 */
#define OFF_C1B   11616    /* 32   */
#define OFF_RLG   11648    /* 2048 */
#define OFF_RLB   13696
#define OFF_RLM   15744
#define OFF_RLV   17792
#define OFF_RLCW  19840    /* 589824 slots: bf16 WR [net][tap9][half2][lane64][j8] */
#define OFF_RLCB  609664   /* 2048 */
#define OFF_BNG   611712
#define OFF_BNB   611744
#define OFF_BNM   611776
#define OFF_BNV   611808
#define OFF_C2W   611840   /* 32768 */
#define OFF_C2B   644608
#define OFF_C3W   644624   /* 16384 */
#define OFF_C3B   661008
#define OFF_C4W   661024   /* 9216 */
#define OFF_C4B   670240
#define OFF_C5W   670256   /* 6400 */
#define OFF_C5B   676656
#define OFF_F1B   676672   /* 4096 */
#define OFF_F2B   680768   /* 2048 */
#define OFF_F3B   682816   /* 24   */
#define P_TOTAL   682840
#define OFF_WB2   P_TOTAL             /* 32768 bf16 = 16384 f32 slots */
#define OFF_WB3   (P_TOTAL + 16384)   /* 16384 bf16 = 8192 f32 slots  */
#define OFF_WC1   (P_TOTAL + 16384 + 8192)  /* 16896 bf16 = 8448 f32 slots */
#define P_END     (OFF_WC1 + 8448)

#define SZ_RL  589824
#define SZ_WB2 32768
#define SZ_WB3 16384
#define SZ_WC1 16896

// ---------- dtype sniff: flag=1 if inputs are float32, 0 if bf16 ----------
__global__ void k_sniff(const void* __restrict__ x, int* __restrict__ flag)
{
    const bf16* xb = (const bf16*)x;
    const float v = fabsf(b2f(xb[2*threadIdx.x]));
    const int ok = (v >= 1e-6f && v <= 1e6f) ? 1 : 0;
    __shared__ int cnt;
    if (threadIdx.x == 0) cnt = 0;
    __syncthreads();
    atomicAdd(&cnt, ok);
    __syncthreads();
    if (threadIdx.x == 0) *flag = (cnt >= 192) ? 0 : 1;
}

// ---------- convert params to f32 block P + bf16 fragment-layout weight blocks ----------
struct CvtArgs { const void* src[23]; int off[23]; const void* cw; const void* w2; const void* w3; int total; };

__device__ __forceinline__ float getv(const void* p, long i, bool isf){
    return isf ? ((const float*)p)[i] : b2f(((const bf16*)p)[i]);
}

__global__ __launch_bounds__(256) void k_cvt(CvtArgs a, const int* __restrict__ flag,
                                             float* __restrict__ P)
{
    const bool isf = (*flag != 0);
    const int i1 = a.total;            // region WR frags (bf16, in rl_cw slot)
    const int i2 = i1 + SZ_RL;         // WB2
    const int i3 = i2 + SZ_WB2;        // WB3
    const int i4 = i3 + SZ_WB3;        // WC1
    const int i5 = i4 + SZ_WC1;
    for (int idx = blockIdx.x*256 + threadIdx.x; idx < i5; idx += gridDim.x*256){
        if (idx < i1){
            if (idx >= OFF_RLCW && idx < OFF_RLCB) continue;   // slot reused for WR
            int k = 0;
            #pragma unroll
            for (int j = 1; j < 23; j++) if (idx >= a.off[j]) k = j;
            P[idx] = getv(a.src[k], idx - a.off[k], isf);
        } else if (idx < i2){
            // WR[net][tap][half][lane][j]: A-frag (weights, M=co16) for region
            const int d = idx - i1;
            const int net = d / 9216, dn = d % 9216;
            const int tap = dn >> 10, rem = dn & 1023;
            const int half = rem >> 9, lane = (rem >> 3) & 63, j = rem & 7;
            const int co = half*16 + (lane & 15);
            const int ci = ((lane >> 4) << 3) + j;
            const long sidx = (long)((net*32 + co)*32 + ci)*9 + tap;
            ((unsigned short*)(P + OFF_RLCW))[d] = (unsigned short)f2bf_u(getv(a.cw, sidx, isf));
        } else if (idx < i3){
            // WB2[tap][lane][j]: B-frag layout for conv2 (K=32ci)
            const int d = idx - i2;
            const int j = d & 7, lane = (d >> 3) & 63, tap = d >> 9;
            const int n = lane & 15, k = ((lane >> 4) << 3) + j;
            const int ci = k, ky = tap >> 3, kx = tap & 7;
            const long sidx = (long)((n*32 + ci)*8 + ky)*8 + kx;
            ((unsigned short*)(P + OFF_WB2))[d] = (unsigned short)f2bf_u(getv(a.w2, sidx, isf));
        } else if (idx < i4){
            // WB3[pair][lane][j]: B-frag layout for conv3 (K=16ci x 2 taps)
            const int d = idx - i3;
            const int j = d & 7, lane = (d >> 3) & 63, pair = d >> 9;
            const int n = lane & 15, k = ((lane >> 4) << 3) + j;
            const int tsel = k >> 4, ci = k & 15;
            const int ky = pair >> 2, kx = ((pair & 3) << 1) + tsel;
            const long sidx = (long)((n*16 + ci)*8 + ky)*8 + kx;
            ((unsigned short*)(P + OFF_WB3))[d] = (unsigned short)f2bf_u(getv(a.w3, sidx, isf));
        } else {
            // WC1[ky][ch][lane][j]: A-frag (weights, M=co32) for conv1, K=16 = 4kx x 4ci
            const int d = idx - i4;
            const int ky = d / 1536, rem = d % 1536;
            const int ch = rem >> 9, rem2 = rem & 511;
            const int lane = rem2 >> 3, j = rem2 & 7;
            const int co = lane & 31, h5 = lane >> 5;
            const int kx = ch*4 + h5*2 + (j >> 2), ci = j & 3;
            float v = 0.f;
            if (ci < 3 && kx < 11)
                v = getv(a.src[0], (long)((co*3 + ci)*11 + ky)*11 + kx, isf);
            ((unsigned short*)(P + OFF_WC1))[d] = (unsigned short)f2bf_u(v);
        }
    }
}

// ---------------- conv1 via 32x32x16 MFMA: x[32,3,170,170] -> [32,32,160,160] ----------------
// block = (8-row group, 32-col tile, b); wave = 2 row-strips; A=W[co32][k16], B=X[k16][pix32]
__global__ __launch_bounds__(256,3) void k_conv1M(const void* __restrict__ x,
        const int* __restrict__ flag, const float* __restrict__ P, float* __restrict__ out)
{
    __shared__ unsigned short xs[18*44*4];     // [row18][col44][ci4] bf16, 6336 B
    __shared__ unsigned short wsm[SZ_WC1];     // 33792 B
    const int t = threadIdx.x;
    const int y0 = blockIdx.x*8, x0 = blockIdx.y*32, b = blockIdx.z;
    { const uint4* src = (const uint4*)(P + OFF_WC1);
      uint4* dst = (uint4*)wsm;
      for (int e=t; e<2112; e+=256) dst[e] = src[e]; }
    const bool isf = (*flag) != 0;
    for (int e=t; e<792; e+=256){
        const int r = e/44, c = e%44;
        const long base = ((long)(b*3)*170 + (y0+r))*170 + min(x0+c, 169);
        float v0, v1, v2;
        if (isf){
            const float* xf = (const float*)x;
            v0 = xf[base]; v1 = xf[base+28900]; v2 = xf[base+57800];
        } else {
            const bf16* xf = (const bf16*)x;
            v0 = b2f(xf[base]); v1 = b2f(xf[base+28900]); v2 = b2f(xf[base+57800]);
        }
        uint2 u;
        u.x = f2bf_u(v0) | (f2bf_u(v1) << 16);
        u.y = f2bf_u(v2);
        *(uint2*)&xs[(r*44+c)*4] = u;
    }
    __syncthreads();
    const int wave = t>>6, lane = t&63;
    const int n = lane & 31, h5 = lane >> 5;
    const int r0 = wave*2;
    f32x16 acc0 = {0.f}, acc1 = {0.f};
    #pragma unroll
    for (int e=0;e<16;e++){ acc0[e]=0.f; acc1[e]=0.f; }
    #pragma unroll 1
    for (int ky=0; ky<11; ky++){
        #pragma unroll
        for (int ch=0; ch<3; ch++){
            const short8 aw = *(const short8*)&wsm[((ky*3+ch)*64 + lane)*8];
            const int kx0 = ch*4 + h5*2;
            const int a0 = ((r0+ky)*44 + n + kx0)*4;
            const int a1 = ((r0+1+ky)*44 + n + kx0)*4;
            union { uint2 u2[2]; short8 s; } ub0, ub1;
            ub0.u2[0] = *(const uint2*)&xs[a0];
            ub0.u2[1] = *(const uint2*)&xs[a0+4];
            ub1.u2[0] = *(const uint2*)&xs[a1];
            ub1.u2[1] = *(const uint2*)&xs[a1+4];
            acc0 = __builtin_amdgcn_mfma_f32_32x32x16_bf16(aw, ub0.s, acc0, 0,0,0);
            acc1 = __builtin_amdgcn_mfma_f32_32x32x16_bf16(aw, ub1.s, acc1, 0,0,0);
        }
    }
    // D: col = lane&31 = pixel-col, row(co) = (reg&3) + 8*(reg>>2) + 4*h5
    #pragma unroll
    for (int reg=0; reg<16; reg++){
        const int co = (reg&3) + 8*(reg>>2) + 4*h5;
        const float bv = P[OFF_C1B + co];
        float* op = out + ((long)(b*32+co)*160 + (y0+r0))*160 + x0 + n;
        op[0]   = acc0[reg] + bv;
        op[160] = acc1[reg] + bv;
    }
}

// ------- region layer via 16x16x32 MFMA, fused relu+maxpool2+bn with shuffle pooling -------
// block = (patch, batch); A=W[co16][ci32] (2 halves), B=X[ci32][pix16] (4x4 tiles)
__global__ __launch_bounds__(256,2) void k_regionM(const float* __restrict__ in,
        const float* __restrict__ P, float* __restrict__ pooled)
{
    __shared__ unsigned short s_in[484*32];    // [pix 22x22][ci32] bf16, 30976 B
    __shared__ unsigned short wsm[9216];       // [tap9][half2][lane64][j8], 18432 B
    __shared__ float sc[32], sh[32];
    const int t = threadIdx.x;
    const int b = blockIdx.x & 31, kk = blockIdx.x >> 5;
    const int gi = kk >> 3, gj = kk & 7;
    const int net = gj*(gi+1);                 // idx = ii*jj + jj
    const int ibase = (b*32*160 + gi*20)*160 + gj*20;
    if (t < 32){
        const float inv = rsqrtf(P[OFF_RLV+net*32+t]+1e-5f)*P[OFF_RLG+net*32+t];
        sc[t] = inv; sh[t] = P[OFF_RLB+net*32+t] - P[OFF_RLM+net*32+t]*inv;
    }
    { const uint4* src = (const uint4*)((const unsigned short*)(P+OFF_RLCW) + (size_t)net*9216);
      uint4* dst = (uint4*)wsm;
      for (int e=t; e<1152; e+=256) dst[e] = src[e]; }
    __syncthreads();
    // stage BN+ReLU patch, zero halo: item = (pixel, ci-oct) -> one b128 LDS write
    for (int e=t; e<1936; e+=256){
        const int o = e & 3, p = e >> 2;
        const int pr = p/22, pc = p%22;
        unsigned ov[4] = {0u,0u,0u,0u};
        if (pr>0 && pr<21 && pc>0 && pc<21){
            const int base = ibase + (pr-1)*160 + (pc-1);
            #pragma unroll
            for (int q2=0;q2<4;q2++){
                const int ci0 = o*8 + q2*2;
                float v0 = in[base + ci0*25600];
                float v1 = in[base + (ci0+1)*25600];
                v0 = fmaxf(fmaf(v0, sc[ci0],   sh[ci0]),   0.f);
                v1 = fmaxf(fmaf(v1, sc[ci0+1], sh[ci0+1]), 0.f);
                ov[q2] = f2bf_u(v0) | (f2bf_u(v1) << 16);
            }
        }
        *(uint4*)&s_in[p*32 + o*8] = *(const uint4*)ov;
    }
    __syncthreads();
    const int wave = t>>6, lane = t&63;
    const int q = lane>>4, n = lane&15;
    const int dr = n>>2, dc = n&3;
    const int nt = (wave==0) ? 7 : 6;          // 25 tiles over 4 waves
    int trs[7], tcs[7];
    #pragma unroll
    for (int i=0;i<7;i++){ const int tt = 4*i + wave; trs[i] = tt/5; tcs[i] = tt - 5*(tt/5); }
    f32x4 acc[7][2];
    {   float bias_v[2][4];
        #pragma unroll
        for (int h=0;h<2;h++)
            #pragma unroll
            for (int r=0;r<4;r++) bias_v[h][r] = P[OFF_RLCB + net*32 + h*16 + q*4 + r];
        #pragma unroll
        for (int i=0;i<7;i++)
            #pragma unroll
            for (int h=0;h<2;h++)
                acc[i][h] = (f32x4){bias_v[h][0], bias_v[h][1], bias_v[h][2], bias_v[h][3]};
    }
    #pragma unroll 1
    for (int tap=0; tap<9; tap++){
        const int ky = tap/3, kx = tap - 3*(tap/3);
        const short8 a0 = *(const short8*)&wsm[(tap*2+0)*512 + lane*8];
        const short8 a1 = *(const short8*)&wsm[(tap*2+1)*512 + lane*8];
        #pragma unroll
        for (int i=0;i<7;i++){
            if (i < nt){
                const int srow = trs[i]*4 + dr + ky, scol = tcs[i]*4 + dc + kx;
                const short8 bx = *(const short8*)&s_in[(srow*22 + scol)*32 + q*8];
                acc[i][0] = __builtin_amdgcn_mfma_f32_16x16x32_bf16(a0, bx, acc[i][0], 0,0,0);
                acc[i][1] = __builtin_amdgcn_mfma_f32_16x16x32_bf16(a1, bx, acc[i][1], 0,0,0);
            }
        }
    }
    // epilogue: residual + relu + 2x2 shuffle-pool + bn;  D: col=n=pixel, row=co=q*4+reg
    float bnsc[2][4], bnsh[2][4];
    #pragma unroll
    for (int h=0;h<2;h++)
        #pragma unroll
        for (int r=0;r<4;r++){
            const int co = h*16 + q*4 + r;
            const float inv = rsqrtf(P[OFF_BNV+co]+1e-5f)*P[OFF_BNG+co];
            bnsc[h][r] = inv; bnsh[h][r] = P[OFF_BNB+co] - P[OFF_BNM+co]*inv;
        }
    const bool wr = ((n & 5) == 0);            // dc even && dr even
    #pragma unroll
    for (int i=0;i<7;i++){
        if (i < nt){
            const int prow = trs[i]*4 + dr, pcol = tcs[i]*4 + dc;
            #pragma unroll
            for (int h=0;h<2;h++){
                #pragma unroll
                for (int r=0;r<4;r++){
                    const int co = h*16 + q*4 + r;
                    float v = acc[i][h][r] + in[ibase + co*25600 + prow*160 + pcol];
                    v = fmaxf(v, 0.f);
                    v = fmaxf(v, __shfl_xor(v, 1, 64));
                    v = fmaxf(v, __shfl_xor(v, 4, 64));
                    if (wr){
                        pooled[((b*32+co)*80 + gi*10 + trs[i]*2 + (dr>>1))*80
                               + gj*10 + tcs[i]*2 + (dc>>1)] = fmaf(v, bnsc[h][r], bnsh[h][r]);
                    }
                }
            }
        }
    }
}

// ------- conv2/conv3 via MFMA shift-GEMM (validated in R3) -------
template<int CIN, int HIN, int WIN, int HOUT, int WOUT>
__global__ __launch_bounds__(256) void k_convM(const float* __restrict__ in,
        const unsigned short* __restrict__ WB, const float* __restrict__ bias,
        float* __restrict__ out)
{
    constexpr int PP = 23;
    constexpr bool C32 = (CIN == 32);
    __shared__ unsigned short xs[PP*PP*CIN];
    __shared__ unsigned short ws[C32 ? 16*64*8 : 32*64*8];
    const int t = threadIdx.x;
    const int col0 = blockIdx.x*16, row0 = blockIdx.y*16, b = blockIdx.z;
    for (int e = t; e < PP*PP*(CIN/2); e += 256){
        const int ci2 = e % (CIN/2), pix = e / (CIN/2);
        int rr = row0 + pix/PP; if (rr > HIN-1) rr = HIN-1;
        int cc = col0 + pix%PP; if (cc > WIN-1) cc = WIN-1;
        const float* gp = &in[((long)(b*CIN + 2*ci2)*HIN + rr)*WIN + cc];
        const unsigned lo = f2bf_u(gp[0]);
        const unsigned hi = f2bf_u(gp[(long)HIN*WIN]);
        ((unsigned*)xs)[pix*(CIN/2) + ci2] = lo | (hi << 16);
    }
    const int wave = t>>6, lane = t&63;
    const int quad = lane>>4, n16 = lane&15;
    const float bv = bias[n16];
    f32x4 acc[4];
    #pragma unroll
    for (int mt=0;mt<4;mt++) acc[mt] = (f32x4){bv,bv,bv,bv};
    if constexpr (C32){
        for (int ch=0; ch<4; ch++){
            __syncthreads();
            const unsigned* src = (const unsigned*)WB + ch*4096;
            for (int e=t; e<4096; e+=256) ((unsigned*)ws)[e] = src[e];
            __syncthreads();
            #pragma unroll 1
            for (int tap=0; tap<16; tap++){
                const int tg = ch*16+tap, ky = tg>>3, kx = tg&7;
                const short8 bw = *(const short8*)&ws[(tap*64+lane)*8];
                #pragma unroll
                for (int mt=0; mt<4; mt++){
                    const int pr = wave*4+mt+ky, pc = n16+kx;
                    const short8 av = *(const short8*)&xs[(pr*PP+pc)*32 + quad*8];
                    acc[mt] = __builtin_amdgcn_mfma_f32_16x16x32_bf16(av, bw, acc[mt], 0,0,0);
                }
            }
        }
    } else {
        for (int e=t; e<8192; e+=256) ((unsigned*)ws)[e] = ((const unsigned*)WB)[e];
        __syncthreads();
        #pragma unroll 1
        for (int pair=0; pair<32; pair++){
            const int ky = pair>>2, kx0 = (pair&3)*2;
            const short8 bw = *(const short8*)&ws[(pair*64+lane)*8];
            #pragma unroll
            for (int mt=0; mt<4; mt++){
                const int pr = wave*4+mt+ky, pc = n16 + kx0 + (quad>>1);
                const short8 av = *(const short8*)&xs[(pr*PP+pc)*16 + (quad&1)*8];
                acc[mt] = __builtin_amdgcn_mfma_f32_16x16x32_bf16(av, bw, acc[mt], 0,0,0);
            }
        }
    }
    #pragma unroll
    for (int mt=0; mt<4; mt++){
        const int orow = row0 + wave*4 + mt;
        if (orow >= HOUT) continue;
        const int ocol = col0 + quad*4;
        float* op = out + ((long)(b*16 + n16)*HOUT + orow)*WOUT + ocol;
        #pragma unroll
        for (int r=0;r<4;r++){
            if (ocol + r < WOUT) op[r] = fmaxf(acc[mt][r], 0.f);
        }
    }
}

// ---------------- generic direct conv (+relu) for the small conv4/conv5 ----------------
template<int CIN, int COUT, int KS, int STRIDE, int HIN, int WIN, int HOUT, int WOUT, int NG>
__global__ __launch_bounds__(256) void k_convN(const float* __restrict__ in,
        const float* __restrict__ w, const float* __restrict__ bias, float* __restrict__ out)
{
    __shared__ float wl[CIN*KS*KS];
    const int co = blockIdx.y, b = blockIdx.z;
    for (int j=threadIdx.x; j<CIN*KS*KS; j+=blockDim.x) wl[j] = w[co*CIN*KS*KS + j];
    __syncthreads();
    const int i = blockIdx.x*blockDim.x + threadIdx.x;
    if (i >= HOUT*NG) return;
    const int y = i / NG, x0 = (i % NG) * 8;
    float acc[8];
    const float bv = bias[co];
    #pragma unroll
    for (int j=0;j<8;j++) acc[j]=bv;
    constexpr int SPAN = STRIDE*7 + KS;
    for (int ci=0; ci<CIN; ci++){
        #pragma unroll 1
        for (int ky=0; ky<KS; ky++){
            const float* ip = in + ((b*CIN+ci)*HIN + (STRIDE*y+ky))*WIN + STRIDE*x0;
            float v[SPAN];
            #pragma unroll
            for (int j=0;j<SPAN;j++) v[j]=ip[j];
            const float* wr = &wl[(ci*KS+ky)*KS];
            #pragma unroll
            for (int kx=0;kx<KS;kx++){
                const float wv = wr[kx];
                #pragma unroll
                for (int j=0;j<8;j++) acc[j] = fmaf(v[STRIDE*j+kx], wv, acc[j]);
            }
        }
    }
    float* op = out + ((b*COUT+co)*HOUT + y)*WOUT + x0;
    #pragma unroll
    for (int j=0;j<8;j++){
        if (x0 + j < WOUT) op[j] = fmaxf(acc[j], 0.f);
    }
}

// ---------------- FC helpers ----------------
__global__ void k_binit(float* __restrict__ y, const float* __restrict__ bias, int N)
{
    const int i = blockIdx.x*256 + threadIdx.x;
    if (i < 32*N) y[i] = bias[i % N];
}

// pack f32 activations (optional relu) to bf16, 8 per thread, zero-pad K to Kdst
__global__ __launch_bounds__(256) void k_xpack(const float* __restrict__ in,
        unsigned short* __restrict__ out, int rows, int Ksrc, int Kdst, int relu)
{
    const int per = Kdst >> 3;
    const int i = blockIdx.x*256 + threadIdx.x;
    if (i >= rows*per) return;
    const int row = i / per, k = (i - row*per)*8;
    float v[8];
    if (k + 8 <= Ksrc){
        *(f32x4*)&v[0] = *(const f32x4*)&in[(long)row*Ksrc + k];
        *(f32x4*)&v[4] = *(const f32x4*)&in[(long)row*Ksrc + k + 4];
    } else {
        #pragma unroll
        for (int j=0;j<8;j++) v[j] = (k + j < Ksrc) ? in[(long)row*Ksrc + k + j] : 0.f;
    }
    if (relu){
        #pragma unroll
        for (int j=0;j<8;j++) v[j] = fmaxf(v[j], 0.f);
    }
    *(short8*)&out[(long)row*Kdst + k] = pack8(v);
}

// ---------------- fc1/fc2: LDS-staged GEMM via global_load_lds (m97 structure) ----------------
// Block: 32 N-rows, 256 threads (4 waves: og=N-half, bh=M-half). K-step BK=128 floats.
// LDS W-tile [32 rows][128 K], double-buffered. Source-side XOR swizzle (T21):
// LDS linear, global chunk c_src = c ^ (row&7), same XOR on ds_read.
template<typename WT>
__device__ __forceinline__ void fcl_body(const unsigned short* __restrict__ x,
        const WT* __restrict__ w, float* __restrict__ y,
        int Kw, int Khat, int N, int Kc, int Nvalid, unsigned char* lbuf)
{
    constexpr bool WF = __is_same(WT, float);
    const int t = threadIdx.x;
    const int wave = t>>6, lane = t&63;
    const int quad = lane>>4, n16 = lane&15;
    const int og = wave>>1, bh = wave&1;
    const int bx = blockIdx.x;
    const int start = blockIdx.y*Kc;
    int steps = 0;
    {   const int rem = Kw - start;
        const int sa = Kc >> 7;
        if (rem > 0){ steps = (rem + 127) >> 7; if (steps > sa) steps = sa; }
    }
    f32x4 acc = {0.f,0.f,0.f,0.f};
    const unsigned short* xp = x + (long)(bh*16 + n16)*Khat;
    const int row = og*16 + n16;

    auto stage = [&](int s, int bsel){
        const int k0 = start + (s<<7);
        const bool swz = (k0 + 128 <= Kw);
        unsigned char* base = lbuf + bsel*16384;
        if constexpr (WF){
            const int r0 = wave*8;
            #pragma unroll
            for (int c=0;c<4;c++){
                const int rr = r0 + 2*c + (lane>>5);
                const int cs = swz ? ((lane&31) ^ (rr&7)) : (lane&31);
                long koff = (long)k0 + cs*4;
                const float* ga = w + (long)(bx*32 + rr)*Kw + koff;
                if (!swz && (koff + 4 > Kw)) ga = w + (long)(bx*32 + rr)*Kw;  // x=0 there
                GLD_LDS16(ga, base + (r0 + 2*c)*512);
            }
        } else {
            const int r0 = wave*8;
            #pragma unroll
            for (int c=0;c<2;c++){
                const int rr = r0 + 4*c + (lane>>4);
                const int cs = swz ? ((lane&15) ^ (rr&7)) : (lane&15);
                long koff = (long)k0 + cs*8;
                const WT* ga = w + (long)(bx*32 + rr)*Kw + koff;
                if (!swz && (koff + 8 > Kw)) ga = w + (long)(bx*32 + rr)*Kw;
                GLD_LDS16(ga, base + (r0 + 4*c)*256);
            }
        }
    };
    auto consume = [&](int s, int bsel){
        const int k0 = start + (s<<7);
        const bool swz = (k0 + 128 <= Kw);
        const unsigned char* base = lbuf + bsel*16384;
        #pragma unroll
        for (int kk=0; kk<4; kk++){
            const int ka = k0 + kk*32 + quad*8;
            const short8 x8 = *(const short8*)&xp[ka];
            short8 bw;
            if constexpr (WF){
                const int c0 = kk*8 + quad*2;
                const int p0 = swz ? (c0 ^ (row&7)) : c0;
                const int p1 = swz ? ((c0+1) ^ (row&7)) : (c0+1);
                float wv[8];
                *(f32x4*)&wv[0] = *(const f32x4*)&base[row*512 + p0*16];
                *(f32x4*)&wv[4] = *(const f32x4*)&base[row*512 + p1*16];
                bw = pack8(wv);
            } else {
                const int c0 = kk*4 + quad;
                const int p0 = swz ? (c0 ^ (row&7)) : c0;
                bw = *(const short8*)&base[row*256 + p0*16];
            }
            acc = __builtin_amdgcn_mfma_f32_16x16x32_bf16(x8, bw, acc, 0,0,0);
        }
    };

    if (steps > 0){
        stage(0, 0);
        __syncthreads();
        for (int s=0; s<steps; s++){
            if (s+1 < steps) stage(s+1, (s+1)&1);
            consume(s, s&1);
            __syncthreads();
        }
    }
    const int o = bx*32 + og*16 + n16;
    if (o < Nvalid){
        #pragma unroll
        for (int r=0;r<4;r++)
            atomicAdd(&y[(long)(bh*16 + quad*4 + r)*N + o], acc[r]);
    }
}

__global__ __launch_bounds__(256) void k_fcL(const unsigned short* __restrict__ x,
        const void* __restrict__ w, const int* __restrict__ flag,
        float* __restrict__ y, int Kw, int Khat, int N, int Kc, int Nvalid)
{
    __shared__ unsigned char lbuf[2*16384];
    if (*flag) fcl_body<float>(x, (const float*)w, y, Kw, Khat, N, Kc, Nvalid, lbuf);
    else       fcl_body<bf16 >(x, (const bf16 *)w, y, Kw, Khat, N, Kc, Nvalid, lbuf);
}

// ---------------- fc3 (tiny): register-pipelined MFMA ----------------
template<typename WT>
__device__ __forceinline__ void fcm_loop(const unsigned short* __restrict__ xp,
        const WT* __restrict__ wp, int start, int end, int quad, f32x4& acc)
{
    const int nfull = (end - start) >> 5;
    const int end32 = start + (nfull << 5);
    const int qo = quad*8;

    short8 xA, xB, xC;
    short8 bwA, bwB, bwC;
    f32x4 wA0, wA1, wB0, wB1, wC0, wC1;

    auto loadA = [&](int k0){
        const int ka = k0 + qo;
        xA = *(const short8*)&xp[ka];
        if constexpr (__is_same(WT, bf16)) bwA = *(const short8*)&wp[ka];
        else { wA0 = *(const f32x4*)&wp[ka]; wA1 = *(const f32x4*)&wp[ka+4]; }
    };
    auto loadB = [&](int k0){
        const int ka = k0 + qo;
        xB = *(const short8*)&xp[ka];
        if constexpr (__is_same(WT, bf16)) bwB = *(const short8*)&wp[ka];
        else { wB0 = *(const f32x4*)&wp[ka]; wB1 = *(const f32x4*)&wp[ka+4]; }
    };
    auto loadC = [&](int k0){
        const int ka = k0 + qo;
        xC = *(const short8*)&xp[ka];
        if constexpr (__is_same(WT, bf16)) bwC = *(const short8*)&wp[ka];
        else { wC0 = *(const f32x4*)&wp[ka]; wC1 = *(const f32x4*)&wp[ka+4]; }
    };
    auto compA = [&](){
        short8 bw;
        if constexpr (__is_same(WT, bf16)) bw = bwA;
        else { float wv[8]; *(f32x4*)&wv[0]=wA0; *(f32x4*)&wv[4]=wA1; bw = pack8(wv); }
        acc = __builtin_amdgcn_mfma_f32_16x16x32_bf16(xA, bw, acc, 0,0,0);
    };
    auto compB = [&](){
        short8 bw;
        if constexpr (__is_same(WT, bf16)) bw = bwB;
        else { float wv[8]; *(f32x4*)&wv[0]=wB0; *(f32x4*)&wv[4]=wB1; bw = pack8(wv); }
        acc = __builtin_amdgcn_mfma_f32_16x16x32_bf16(xB, bw, acc, 0,0,0);
    };
    auto compC = [&](){
        short8 bw;
        if constexpr (__is_same(WT, bf16)) bw = bwC;
        else { float wv[8]; *(f32x4*)&wv[0]=wC0; *(f32x4*)&wv[4]=wC1; bw = pack8(wv); }
        acc = __builtin_amdgcn_mfma_f32_16x16x32_bf16(xC, bw, acc, 0,0,0);
    };

    if (nfull >= 3){
        loadA(start); loadB(start+32); loadC(start+64);
        int j = 0;
        for (; j + 6 <= nfull; j += 3){
            compA(); loadA(start + ((j+3)<<5));
            compB(); loadB(start + ((j+4)<<5));
            compC(); loadC(start + ((j+5)<<5));
        }
        const int rem = nfull - j;
        if (rem == 3){ compA(); compB(); compC(); }
        else if (rem == 4){
            compA(); loadA(start + ((j+3)<<5));
            compB(); compC(); compA();
        } else {
            compA(); loadA(start + ((j+3)<<5));
            compB(); loadB(start + ((j+4)<<5));
            compC(); compA(); compB();
        }
    } else if (nfull == 2){
        loadA(start); loadB(start+32); compA(); compB();
    } else if (nfull == 1){
        loadA(start); compA();
    }
    if (end32 < end){
        const int ka = end32 + qo;
        float xv[8], wv[8];
        #pragma unroll
        for (int j=0;j<8;j++){
            const bool v = (ka + j) < end;
            xv[j] = v ? b2f(((const bf16*)xp)[ka+j]) : 0.f;
            wv[j] = v ? (float)ld(wp, ka+j) : 0.f;
        }
        acc = __builtin_amdgcn_mfma_f32_16x16x32_bf16(pack8(xv), pack8(wv), acc, 0,0,0);
    }
}

__global__ __launch_bounds__(256,4) void k_fcM(const unsigned short* __restrict__ x,
        const void* __restrict__ w, const int* __restrict__ flag,
        float* __restrict__ y, int K, int N, int Kc, int Nvalid)
{
    const int t = threadIdx.x;
    const int wave = t>>6, lane = t&63;
    const int quad = lane>>4, n16 = lane&15;
    const int og = wave>>1, bh = wave&1;
    const int o = blockIdx.x*32 + og*16 + n16;
    const int orow = (o < Nvalid) ? o : (Nvalid-1);
    const int xrow = bh*16 + n16;
    const int start = blockIdx.y*Kc;
    const int end = min(K, start + Kc);
    f32x4 acc = {0.f,0.f,0.f,0.f};
    const unsigned short* xp = x + (long)xrow*K;
    if (*flag) fcm_loop<float>(xp, (const float*)w + (long)orow*K, start, end, quad, acc);
    else       fcm_loop<bf16 >(xp, (const bf16 *)w + (long)orow*K, start, end, quad, acc);
    if (o < Nvalid){
        #pragma unroll
        for (int r=0;r<4;r++)
            atomicAdd(&y[(long)(bh*16 + quad*4 + r)*N + o], acc[r]);
    }
}

// ---------------- paired log_softmax over axis 1 of [32,2,12] ----------------
__global__ void k_lsm(const float* __restrict__ in, const int* __restrict__ flag,
                      void* __restrict__ out)
{
    const int i = threadIdx.x;
    if (i >= 384) return;
    const int b = i/12, au = i%12;
    const float a0 = in[b*24+au], a1 = in[b*24+12+au];
    const float m = fmaxf(a0,a1);
    const float lse = m + logf(expf(a0-m)+expf(a1-m));
    const float o0 = a0-lse, o1 = a1-lse;
    if (*flag){
        ((float*)out)[b*24+au]    = o0;
        ((float*)out)[b*24+12+au] = o1;
    } else {
        ((bf16*)out)[b*24+au]    = __float2bfloat16(o0);
        ((bf16*)out)[b*24+12+au] = __float2bfloat16(o1);
    }
}

extern "C" void kernel_launch(void* const* d_in, const int* in_sizes, int n_in,
                              void* d_out, int out_size, void* d_ws, size_t ws_size,
                              hipStream_t stream) {
    (void)in_sizes; (void)n_in; (void)out_size; (void)ws_size;
    const void* x = d_in[0];

    float* A = (float*)d_ws;               // 26,214,400 floats
    float* B = A + 26214400;               //  6,553,600 floats
    float* P = B + 6553600;                //  P_END floats
    int* flag = (int*)(P + P_END);
    unsigned short* Xp = (unsigned short*)(P + P_END + 16);  // up to 393,216 bf16

    CvtArgs a;
    const int src_idx[23] = {1,2,3,4,5,6,7,8,9,10,11,12,13,14,15,16,17,18,19,20,22,24,26};
    const int offs[23] = {OFF_C1W,OFF_C1B,OFF_RLG,OFF_RLB,OFF_RLM,OFF_RLV,OFF_RLCW,OFF_RLCB,
                          OFF_BNG,OFF_BNB,OFF_BNM,OFF_BNV,OFF_C2W,OFF_C2B,OFF_C3W,OFF_C3B,
                          OFF_C4W,OFF_C4B,OFF_C5W,OFF_C5B,OFF_F1B,OFF_F2B,OFF_F3B};
    for (int j=0;j<23;j++){ a.src[j] = d_in[src_idx[j]]; a.off[j] = offs[j]; }
    a.cw = d_in[7]; a.w2 = d_in[13]; a.w3 = d_in[15];
    a.total = P_TOTAL;

    k_sniff<<<1,256,0,stream>>>(x, flag);
    k_cvt<<<(P_TOTAL+SZ_RL+SZ_WB2+SZ_WB3+SZ_WC1+255)/256,256,0,stream>>>(a, flag, P);
    k_conv1M<<<dim3(20,5,32),256,0,stream>>>(x, flag, P, A);
    k_regionM<<<2048,256,0,stream>>>(A, P, B);
    // conv2: [32,32,80,80] -> [32,16,73,73]  (MFMA)
    k_convM<32,80,80,73,73><<<dim3(5,5,32),256,0,stream>>>(B, (const unsigned short*)(P+OFF_WB2), P+OFF_C2B, A);
    // conv3: -> [32,16,66,66]  (MFMA)
    k_convM<16,73,73,66,66><<<dim3(5,5,32),256,0,stream>>>(A, (const unsigned short*)(P+OFF_WB3), P+OFF_C3B, B);
    // conv4: stride 2 -> [32,16,31,31]
    k_convN<16,16,6,2,66,66,31,31,4><<<dim3(1,16,32),128,0,stream>>>(B, P+OFF_C4W, P+OFF_C4B, A);
    // conv5: -> [32,16,27,27]
    k_convN<16,16,5,1,31,31,27,27,4><<<dim3(1,16,32),128,0,stream>>>(A, P+OFF_C5W, P+OFF_C5B, B);
    // fc1: K=11664 (pad 12288) -> 4096; x = bf16(conv5 out), y=A; 16 K-splits, BK=128, dbuf LDS
    k_xpack<<<(32*(12288/8)+255)/256,256,0,stream>>>(B, Xp, 32, 11664, 12288, 0);
    k_binit<<<(32*4096+255)/256,256,0,stream>>>(A, P+OFF_F1B, 4096);
    k_fcL<<<dim3(128,16),256,0,stream>>>(Xp, d_in[21], flag, A, 11664, 12288, 4096, 768, 4096);
    // fc2: K=4096 -> 2048; relu folded into pack, y=B; 16 K-splits
    k_xpack<<<(32*(4096/8)+255)/256,256,0,stream>>>(A, Xp, 32, 4096, 4096, 1);
    k_binit<<<(32*2048+255)/256,256,0,stream>>>(B, P+OFF_F2B, 2048);
    k_fcL<<<dim3(64,16),256,0,stream>>>(Xp, d_in[23], flag, B, 4096, 4096, 2048, 256, 2048);
    // fc3: K=2048 -> 24; relu folded into pack, y=A
    k_xpack<<<(32*(2048/8)+255)/256,256,0,stream>>>(B, Xp, 32, 2048, 2048, 1);
    k_binit<<<(32*24+255)/256,256,0,stream>>>(A, P+OFF_F3B, 24);
    k_fcM<<<dim3(1,64),256,0,stream>>>(Xp, d_in[25], flag, A, 2048, 24, 32, 24);
    k_lsm<<<1,384,0,stream>>>(A, flag, d_out);
}

// Round 4
// 586.552 us; speedup vs baseline: 1.2914x; 1.2212x over previous
//
#include <hip/hip_runtime.h>
#include <hip/hip_bf16.h>

typedef __hip_bfloat16 bf16;
typedef __attribute__((ext_vector_type(8))) short short8;
typedef __attribute__((ext_vector_type(4))) float f32x4;
typedef __attribute__((ext_vector_type(16))) float f32x16;

__device__ __forceinline__ float b2f(const bf16 v){ return __bfloat162float(v); }
__device__ __forceinline__ float ld(const float* p, long i){ return p[i]; }
__device__ __forceinline__ float ld(const bf16*  p, long i){ return b2f(p[i]); }

__device__ __forceinline__ unsigned f2bf_u(float f){
    union { float f; unsigned u; } a; a.f = f;
    unsigned r = a.u + 0x7FFFu + ((a.u >> 16) & 1u);
    return r >> 16;
}

__device__ __forceinline__ short8 pack8(const float* v){
    union { __hip_bfloat162 h[4]; short8 s; } r;
    #pragma unroll
    for (int i=0;i<4;i++)
        r.h[i] = __float22bfloat162_rn(float2{v[2*i], v[2*i+1]});
    return r.s;
}

#define GLD_LDS16(g, l) __builtin_amdgcn_global_load_lds( \
    (const __attribute__((address_space(1))) void*)(g), \
    (__attribute__((address_space(3))) void*)(l), 16, 0, 0)

// ---- converted-params block offsets (floats) within P ----
#define OFF_C1W   0        /* 11616 */
#define OFF_C1B   11616    /* 32   */
#define OFF_RLG   11648    /* 2048 */
#define OFF_RLB   13696
#define OFF_RLM   15744
#define OFF_RLV   17792
#define OFF_RLCW  19840    /* 589824 slots: bf16 WR [net][tap9][half2][lane64][j8] */
#define OFF_RLCB  609664   /* 2048 */
#define OFF_BNG   611712
#define OFF_BNB   611744
#define OFF_BNM   611776
#define OFF_BNV   611808
#define OFF_C2W   611840   /* 32768 */
#define OFF_C2B   644608
#define OFF_C3W   644624   /* 16384 */
#define OFF_C3B   661008
#define OFF_C4W   661024   /* 9216 */
#define OFF_C4B   670240
#define OFF_C5W   670256   /* 6400 */
#define OFF_C5B   676656
#define OFF_F1B   676672   /* 4096 */
#define OFF_F2B   680768   /* 2048 */
#define OFF_F3B   682816   /* 24   */
#define P_TOTAL   682840
#define OFF_WB2   P_TOTAL             /* 32768 bf16 = 16384 f32 slots */
#define OFF_WB3   (P_TOTAL + 16384)   /* 16384 bf16 = 8192 f32 slots  */
#define OFF_WC1   (P_TOTAL + 16384 + 8192)  /* 16896 bf16 = 8448 f32 slots */
#define P_END     (OFF_WC1 + 8448)

#define SZ_RL  589824
#define SZ_WB2 32768
#define SZ_WB3 16384
#define SZ_WC1 16896

// ---------- dtype sniff: flag=1 if inputs are float32, 0 if bf16 ----------
__global__ void k_sniff(const void* __restrict__ x, int* __restrict__ flag)
{
    const bf16* xb = (const bf16*)x;
    const float v = fabsf(b2f(xb[2*threadIdx.x]));
    const int ok = (v >= 1e-6f && v <= 1e6f) ? 1 : 0;
    __shared__ int cnt;
    if (threadIdx.x == 0) cnt = 0;
    __syncthreads();
    atomicAdd(&cnt, ok);
    __syncthreads();
    if (threadIdx.x == 0) *flag = (cnt >= 192) ? 0 : 1;
}

// ---------- convert params to f32 block P + bf16 fragment-layout weight blocks ----------
struct CvtArgs { const void* src[23]; int off[23]; const void* cw; const void* w2; const void* w3; int total; };

__device__ __forceinline__ float getv(const void* p, long i, bool isf){
    return isf ? ((const float*)p)[i] : b2f(((const bf16*)p)[i]);
}

__global__ __launch_bounds__(256) void k_cvt(CvtArgs a, const int* __restrict__ flag,
                                             float* __restrict__ P)
{
    const bool isf = (*flag != 0);
    const int i1 = a.total;            // region WR frags (bf16, in rl_cw slot)
    const int i2 = i1 + SZ_RL;         // WB2
    const int i3 = i2 + SZ_WB2;        // WB3
    const int i4 = i3 + SZ_WB3;        // WC1
    const int i5 = i4 + SZ_WC1;
    for (int idx = blockIdx.x*256 + threadIdx.x; idx < i5; idx += gridDim.x*256){
        if (idx < i1){
            if (idx >= OFF_RLCW && idx < OFF_RLCB) continue;   // slot reused for WR
            int k = 0;
            #pragma unroll
            for (int j = 1; j < 23; j++) if (idx >= a.off[j]) k = j;
            P[idx] = getv(a.src[k], idx - a.off[k], isf);
        } else if (idx < i2){
            // WR[net][tap][half][lane][j]: A-frag (weights, M=co16) for region
            const int d = idx - i1;
            const int net = d / 9216, dn = d % 9216;
            const int tap = dn >> 10, rem = dn & 1023;
            const int half = rem >> 9, lane = (rem >> 3) & 63, j = rem & 7;
            const int co = half*16 + (lane & 15);
            const int ci = ((lane >> 4) << 3) + j;
            const long sidx = (long)((net*32 + co)*32 + ci)*9 + tap;
            ((unsigned short*)(P + OFF_RLCW))[d] = (unsigned short)f2bf_u(getv(a.cw, sidx, isf));
        } else if (idx < i3){
            // WB2[tap][lane][j]: B-frag layout for conv2 (K=32ci)
            const int d = idx - i2;
            const int j = d & 7, lane = (d >> 3) & 63, tap = d >> 9;
            const int n = lane & 15, k = ((lane >> 4) << 3) + j;
            const int ci = k, ky = tap >> 3, kx = tap & 7;
            const long sidx = (long)((n*32 + ci)*8 + ky)*8 + kx;
            ((unsigned short*)(P + OFF_WB2))[d] = (unsigned short)f2bf_u(getv(a.w2, sidx, isf));
        } else if (idx < i4){
            // WB3[pair][lane][j]: B-frag layout for conv3 (K=16ci x 2 taps)
            const int d = idx - i3;
            const int j = d & 7, lane = (d >> 3) & 63, pair = d >> 9;
            const int n = lane & 15, k = ((lane >> 4) << 3) + j;
            const int tsel = k >> 4, ci = k & 15;
            const int ky = pair >> 2, kx = ((pair & 3) << 1) + tsel;
            const long sidx = (long)((n*16 + ci)*8 + ky)*8 + kx;
            ((unsigned short*)(P + OFF_WB3))[d] = (unsigned short)f2bf_u(getv(a.w3, sidx, isf));
        } else {
            // WC1[ky][ch][lane][j]: A-frag (weights, M=co32) for conv1, K=16 = 4kx x 4ci
            const int d = idx - i4;
            const int ky = d / 1536, rem = d % 1536;
            const int ch = rem >> 9, rem2 = rem & 511;
            const int lane = rem2 >> 3, j = rem2 & 7;
            const int co = lane & 31, h5 = lane >> 5;
            const int kx = ch*4 + h5*2 + (j >> 2), ci = j & 3;
            float v = 0.f;
            if (ci < 3 && kx < 11)
                v = getv(a.src[0], (long)((co*3 + ci)*11 + ky)*11 + kx, isf);
            ((unsigned short*)(P + OFF_WC1))[d] = (unsigned short)f2bf_u(v);
        }
    }
}

// ---------------- conv1 via 32x32x16 MFMA: x[32,3,170,170] -> NHWC [32,160,160,32] ----------------
__global__ __launch_bounds__(256,3) void k_conv1M(const void* __restrict__ x,
        const int* __restrict__ flag, const float* __restrict__ P, float* __restrict__ out)
{
    __shared__ unsigned short xs[18*44*4];     // [row18][col44][ci4] bf16, 6336 B
    __shared__ unsigned short wsm[SZ_WC1];     // 33792 B
    const int t = threadIdx.x;
    const int y0 = blockIdx.x*8, x0 = blockIdx.y*32, b = blockIdx.z;
    { const uint4* src = (const uint4*)(P + OFF_WC1);
      uint4* dst = (uint4*)wsm;
      for (int e=t; e<2112; e+=256) dst[e] = src[e]; }
    const bool isf = (*flag) != 0;
    for (int e=t; e<792; e+=256){
        const int r = e/44, c = e%44;
        const long base = ((long)(b*3)*170 + (y0+r))*170 + min(x0+c, 169);
        float v0, v1, v2;
        if (isf){
            const float* xf = (const float*)x;
            v0 = xf[base]; v1 = xf[base+28900]; v2 = xf[base+57800];
        } else {
            const bf16* xf = (const bf16*)x;
            v0 = b2f(xf[base]); v1 = b2f(xf[base+28900]); v2 = b2f(xf[base+57800]);
        }
        uint2 u;
        u.x = f2bf_u(v0) | (f2bf_u(v1) << 16);
        u.y = f2bf_u(v2);
        *(uint2*)&xs[(r*44+c)*4] = u;
    }
    __syncthreads();
    const int wave = t>>6, lane = t&63;
    const int n = lane & 31, h5 = lane >> 5;
    const int r0 = wave*2;
    f32x16 acc0 = {0.f}, acc1 = {0.f};
    #pragma unroll
    for (int e=0;e<16;e++){ acc0[e]=0.f; acc1[e]=0.f; }
    #pragma unroll 1
    for (int ky=0; ky<11; ky++){
        #pragma unroll
        for (int ch=0; ch<3; ch++){
            const short8 aw = *(const short8*)&wsm[((ky*3+ch)*64 + lane)*8];
            const int kx0 = ch*4 + h5*2;
            const int a0 = ((r0+ky)*44 + n + kx0)*4;
            const int a1 = ((r0+1+ky)*44 + n + kx0)*4;
            union { uint2 u2[2]; short8 s; } ub0, ub1;
            ub0.u2[0] = *(const uint2*)&xs[a0];
            ub0.u2[1] = *(const uint2*)&xs[a0+4];
            ub1.u2[0] = *(const uint2*)&xs[a1];
            ub1.u2[1] = *(const uint2*)&xs[a1+4];
            acc0 = __builtin_amdgcn_mfma_f32_32x32x16_bf16(aw, ub0.s, acc0, 0,0,0);
            acc1 = __builtin_amdgcn_mfma_f32_32x32x16_bf16(aw, ub1.s, acc1, 0,0,0);
        }
    }
    // D: col = lane&31 = pixel-col, row(co) = (reg&3) + 8*(reg>>2) + 4*h5
    // NHWC store: 4 consecutive co per reg-group of 4
    float* opb = out + ((long)b*25600 + (long)(y0+r0)*160 + x0 + n)*32;
    #pragma unroll
    for (int g=0; g<4; g++){
        const int co0 = 8*g + 4*h5;
        const f32x4 bv = *(const f32x4*)&P[OFF_C1B + co0];
        f32x4 s0, s1;
        #pragma unroll
        for (int r=0;r<4;r++){ s0[r] = acc0[4*g+r] + bv[r]; s1[r] = acc1[4*g+r] + bv[r]; }
        *(f32x4*)(opb + co0) = s0;
        *(f32x4*)(opb + 160*32 + co0) = s1;
    }
}

// ------- region layer via 16x16x32 MFMA; NHWC in [32,160,160,32], NHWC pooled [32,80,80,32] -------
__global__ __launch_bounds__(256,2) void k_regionM(const float* __restrict__ in,
        const float* __restrict__ P, float* __restrict__ pooled)
{
    __shared__ unsigned short s_in[484*32];    // [pix 22x22][ci32] bf16, 30976 B
    __shared__ unsigned short wsm[9216];       // [tap9][half2][lane64][j8], 18432 B
    __shared__ float sc[32], sh[32];
    const int t = threadIdx.x;
    const int b = blockIdx.x & 31, kk = blockIdx.x >> 5;
    const int gi = kk >> 3, gj = kk & 7;
    const int net = gj*(gi+1);                 // idx = ii*jj + jj
    const long pbase = ((long)b*25600 + (long)(gi*20)*160 + gj*20)*32;
    if (t < 32){
        const float inv = rsqrtf(P[OFF_RLV+net*32+t]+1e-5f)*P[OFF_RLG+net*32+t];
        sc[t] = inv; sh[t] = P[OFF_RLB+net*32+t] - P[OFF_RLM+net*32+t]*inv;
    }
    { const uint4* src = (const uint4*)((const unsigned short*)(P+OFF_RLCW) + (size_t)net*9216);
      uint4* dst = (uint4*)wsm;
      for (int e=t; e<1152; e+=256) dst[e] = src[e]; }
    __syncthreads();
    // stage BN+ReLU patch, zero halo: contiguous NHWC 8-ch reads
    for (int e=t; e<1936; e+=256){
        const int o = e & 3, p = e >> 2;
        const int pr = p/22, pc = p%22;
        short8 pk = {0,0,0,0,0,0,0,0};
        if (pr>0 && pr<21 && pc>0 && pc<21){
            const long a = pbase + ((long)(pr-1)*160 + (pc-1))*32 + o*8;
            float v[8];
            *(f32x4*)&v[0] = *(const f32x4*)&in[a];
            *(f32x4*)&v[4] = *(const f32x4*)&in[a+4];
            #pragma unroll
            for (int j=0;j<8;j++){
                const int ci = o*8 + j;
                v[j] = fmaxf(fmaf(v[j], sc[ci], sh[ci]), 0.f);
            }
            pk = pack8(v);
        }
        *(short8*)&s_in[p*32 + o*8] = pk;
    }
    __syncthreads();
    const int wave = t>>6, lane = t&63;
    const int q = lane>>4, n = lane&15;
    const int dr = n>>2, dc = n&3;
    const int nt = (wave==0) ? 7 : 6;          // 25 tiles over 4 waves
    int trs[7], tcs[7];
    #pragma unroll
    for (int i=0;i<7;i++){ const int tt = 4*i + wave; trs[i] = tt/5; tcs[i] = tt - 5*(tt/5); }
    f32x4 acc[7][2];
    {   float bias_v[2][4];
        #pragma unroll
        for (int h=0;h<2;h++)
            #pragma unroll
            for (int r=0;r<4;r++) bias_v[h][r] = P[OFF_RLCB + net*32 + h*16 + q*4 + r];
        #pragma unroll
        for (int i=0;i<7;i++)
            #pragma unroll
            for (int h=0;h<2;h++)
                acc[i][h] = (f32x4){bias_v[h][0], bias_v[h][1], bias_v[h][2], bias_v[h][3]};
    }
    #pragma unroll 1
    for (int tap=0; tap<9; tap++){
        const int ky = tap/3, kx = tap - 3*(tap/3);
        const short8 a0 = *(const short8*)&wsm[(tap*2+0)*512 + lane*8];
        const short8 a1 = *(const short8*)&wsm[(tap*2+1)*512 + lane*8];
        #pragma unroll
        for (int i=0;i<7;i++){
            if (i < nt){
                const int srow = trs[i]*4 + dr + ky, scol = tcs[i]*4 + dc + kx;
                const short8 bx = *(const short8*)&s_in[(srow*22 + scol)*32 + q*8];
                acc[i][0] = __builtin_amdgcn_mfma_f32_16x16x32_bf16(a0, bx, acc[i][0], 0,0,0);
                acc[i][1] = __builtin_amdgcn_mfma_f32_16x16x32_bf16(a1, bx, acc[i][1], 0,0,0);
            }
        }
    }
    // epilogue: residual + relu + 2x2 shuffle-pool + bn; contiguous f32x4 residual + pooled stores
    float bnsc[2][4], bnsh[2][4];
    #pragma unroll
    for (int h=0;h<2;h++)
        #pragma unroll
        for (int r=0;r<4;r++){
            const int co = h*16 + q*4 + r;
            const float inv = rsqrtf(P[OFF_BNV+co]+1e-5f)*P[OFF_BNG+co];
            bnsc[h][r] = inv; bnsh[h][r] = P[OFF_BNB+co] - P[OFF_BNM+co]*inv;
        }
    const bool wr = ((n & 5) == 0);            // dc even && dr even
    #pragma unroll
    for (int i=0;i<7;i++){
        if (i < nt){
            const int prow = trs[i]*4 + dr, pcol = tcs[i]*4 + dc;
            const long ra = pbase + ((long)prow*160 + pcol)*32;
            const long pa0 = ((long)b*6400 + (long)(gi*10 + trs[i]*2 + (dr>>1))*80
                              + gj*10 + tcs[i]*2 + (dc>>1))*32;
            #pragma unroll
            for (int h=0;h<2;h++){
                const f32x4 res = *(const f32x4*)&in[ra + h*16 + q*4];
                f32x4 pv;
                #pragma unroll
                for (int r=0;r<4;r++){
                    float v = acc[i][h][r] + res[r];
                    v = fmaxf(v, 0.f);
                    v = fmaxf(v, __shfl_xor(v, 1, 64));
                    v = fmaxf(v, __shfl_xor(v, 4, 64));
                    pv[r] = fmaf(v, bnsc[h][r], bnsh[h][r]);
                }
                if (wr) *(f32x4*)&pooled[pa0 + h*16 + q*4] = pv;
            }
        }
    }
}

// ------- conv2/conv3 via MFMA shift-GEMM; NHWC input, selectable output layout -------
template<int CIN, int HIN, int WIN, int HOUT, int WOUT, bool NHWC_OUT>
__global__ __launch_bounds__(256) void k_convM(const float* __restrict__ in,
        const unsigned short* __restrict__ WB, const float* __restrict__ bias,
        float* __restrict__ out)
{
    constexpr int PP = 23;
    constexpr bool C32 = (CIN == 32);
    __shared__ unsigned short xs[PP*PP*CIN];
    __shared__ unsigned short ws[C32 ? 16*64*8 : 32*64*8];
    const int t = threadIdx.x;
    const int col0 = blockIdx.x*16, row0 = blockIdx.y*16, b = blockIdx.z;
    for (int e = t; e < PP*PP*(CIN/8); e += 256){
        const int o = e % (CIN/8), pix = e / (CIN/8);
        int rr = row0 + pix/PP; if (rr > HIN-1) rr = HIN-1;
        int cc = col0 + pix%PP; if (cc > WIN-1) cc = WIN-1;
        const float* gp = &in[((long)b*HIN*WIN + (long)rr*WIN + cc)*CIN + o*8];
        float v[8];
        *(f32x4*)&v[0] = *(const f32x4*)gp;
        *(f32x4*)&v[4] = *(const f32x4*)(gp+4);
        *(short8*)&xs[pix*CIN + o*8] = pack8(v);
    }
    const int wave = t>>6, lane = t&63;
    const int quad = lane>>4, n16 = lane&15;
    const float bv = bias[n16];
    f32x4 acc[4];
    #pragma unroll
    for (int mt=0;mt<4;mt++) acc[mt] = (f32x4){bv,bv,bv,bv};
    if constexpr (C32){
        for (int ch=0; ch<4; ch++){
            __syncthreads();
            const unsigned* src = (const unsigned*)WB + ch*4096;
            for (int e=t; e<4096; e+=256) ((unsigned*)ws)[e] = src[e];
            __syncthreads();
            #pragma unroll 1
            for (int tap=0; tap<16; tap++){
                const int tg = ch*16+tap, ky = tg>>3, kx = tg&7;
                const short8 bw = *(const short8*)&ws[(tap*64+lane)*8];
                #pragma unroll
                for (int mt=0; mt<4; mt++){
                    const int pr = wave*4+mt+ky, pc = n16+kx;
                    const short8 av = *(const short8*)&xs[(pr*PP+pc)*32 + quad*8];
                    acc[mt] = __builtin_amdgcn_mfma_f32_16x16x32_bf16(av, bw, acc[mt], 0,0,0);
                }
            }
        }
    } else {
        for (int e=t; e<8192; e+=256) ((unsigned*)ws)[e] = ((const unsigned*)WB)[e];
        __syncthreads();
        #pragma unroll 1
        for (int pair=0; pair<32; pair++){
            const int ky = pair>>2, kx0 = (pair&3)*2;
            const short8 bw = *(const short8*)&ws[(pair*64+lane)*8];
            #pragma unroll
            for (int mt=0; mt<4; mt++){
                const int pr = wave*4+mt+ky, pc = n16 + kx0 + (quad>>1);
                const short8 av = *(const short8*)&xs[(pr*PP+pc)*16 + (quad&1)*8];
                acc[mt] = __builtin_amdgcn_mfma_f32_16x16x32_bf16(av, bw, acc[mt], 0,0,0);
            }
        }
    }
    #pragma unroll
    for (int mt=0; mt<4; mt++){
        const int orow = row0 + wave*4 + mt;
        if (orow >= HOUT) continue;
        const int ocol = col0 + quad*4;
        #pragma unroll
        for (int r=0;r<4;r++){
            if (ocol + r < WOUT){
                if constexpr (NHWC_OUT)
                    out[((long)b*HOUT*WOUT + (long)orow*WOUT + ocol + r)*16 + n16] = fmaxf(acc[mt][r], 0.f);
                else
                    out[((long)(b*16 + n16)*HOUT + orow)*WOUT + ocol + r] = fmaxf(acc[mt][r], 0.f);
            }
        }
    }
}

// ---------------- direct conv (+relu) for conv4/conv5, OW outputs/thread ----------------
template<int CIN, int COUT, int KS, int STRIDE, int HIN, int WIN, int HOUT, int WOUT,
         int NG, int OW, bool BF16OUT, int ROWPAD>
__global__ __launch_bounds__(256,2) void k_convN(const float* __restrict__ in,
        const float* __restrict__ w, const float* __restrict__ bias, void* __restrict__ outv)
{
    __shared__ float wl[CIN*KS*KS];
    const int co = blockIdx.y, b = blockIdx.z;
    for (int j=threadIdx.x; j<CIN*KS*KS; j+=blockDim.x) wl[j] = w[co*CIN*KS*KS + j];
    __syncthreads();
    const int i = blockIdx.x*blockDim.x + threadIdx.x;
    if (i >= HOUT*NG) return;
    const int y = i / NG, x0 = (i % NG) * OW;
    float acc[OW];
    const float bv = bias[co];
    #pragma unroll
    for (int j=0;j<OW;j++) acc[j]=bv;
    constexpr int SPAN = STRIDE*(OW-1) + KS;
    for (int ci=0; ci<CIN; ci++){
        #pragma unroll
        for (int ky=0; ky<KS; ky++){
            const float* ip = in + ((long)(b*CIN+ci)*HIN + (STRIDE*y+ky))*WIN + STRIDE*x0;
            float v[SPAN];
            #pragma unroll
            for (int j=0;j<SPAN;j++) v[j]=ip[j];
            const float* wr = &wl[(ci*KS+ky)*KS];
            #pragma unroll
            for (int kx=0;kx<KS;kx++){
                const float wv = wr[kx];
                #pragma unroll
                for (int j=0;j<OW;j++) acc[j] = fmaf(v[STRIDE*j+kx], wv, acc[j]);
            }
        }
    }
    if constexpr (BF16OUT){
        unsigned short* op = (unsigned short*)outv + (long)b*ROWPAD + (co*HOUT + y)*WOUT + x0;
        #pragma unroll
        for (int j=0;j<OW;j++)
            if (x0 + j < WOUT) op[j] = (unsigned short)f2bf_u(fmaxf(acc[j], 0.f));
    } else {
        float* op = (float*)outv + ((long)(b*COUT+co)*HOUT + y)*WOUT + x0;
        #pragma unroll
        for (int j=0;j<OW;j++)
            if (x0 + j < WOUT) op[j] = fmaxf(acc[j], 0.f);
    }
}

// ---------------- FC helpers ----------------
__global__ void k_binit(float* __restrict__ y, const float* __restrict__ bias, int N)
{
    const int i = blockIdx.x*256 + threadIdx.x;
    if (i < 32*N) y[i] = bias[i % N];
}

// fc1 prep: bias-init y AND zero the Xp K-pad region [11664,12288) per row
__global__ void k_fc1prep(float* __restrict__ y, const float* __restrict__ bias,
                          unsigned short* __restrict__ xp)
{
    const int i = blockIdx.x*256 + threadIdx.x;
    if (i < 32*4096) y[i] = bias[i & 4095];
    if (i < 19968){
        const int r = i / 624;
        xp[(long)r*12288 + 11664 + (i - r*624)] = 0;
    }
}

// pack f32 activations (optional relu) to bf16, 8 per thread, zero-pad K to Kdst
__global__ __launch_bounds__(256) void k_xpack(const float* __restrict__ in,
        unsigned short* __restrict__ out, int rows, int Ksrc, int Kdst, int relu)
{
    const int per = Kdst >> 3;
    const int i = blockIdx.x*256 + threadIdx.x;
    if (i >= rows*per) return;
    const int row = i / per, k = (i - row*per)*8;
    float v[8];
    if (k + 8 <= Ksrc){
        *(f32x4*)&v[0] = *(const f32x4*)&in[(long)row*Ksrc + k];
        *(f32x4*)&v[4] = *(const f32x4*)&in[(long)row*Ksrc + k + 4];
    } else {
        #pragma unroll
        for (int j=0;j<8;j++) v[j] = (k + j < Ksrc) ? in[(long)row*Ksrc + k + j] : 0.f;
    }
    if (relu){
        #pragma unroll
        for (int j=0;j<8;j++) v[j] = fmaxf(v[j], 0.f);
    }
    *(short8*)&out[(long)row*Kdst + k] = pack8(v);
}

// ---------------- fc1/fc2: LDS-staged GEMM via global_load_lds ----------------
template<typename WT>
__device__ __forceinline__ void fcl_body(const unsigned short* __restrict__ x,
        const WT* __restrict__ w, float* __restrict__ y,
        int Kw, int Khat, int N, int Kc, int Nvalid, unsigned char* lbuf)
{
    constexpr bool WF = __is_same(WT, float);
    const int t = threadIdx.x;
    const int wave = t>>6, lane = t&63;
    const int quad = lane>>4, n16 = lane&15;
    const int og = wave>>1, bh = wave&1;
    const int bx = blockIdx.x;
    const int start = blockIdx.y*Kc;
    int steps = 0;
    {   const int rem = Kw - start;
        const int sa = Kc >> 7;
        if (rem > 0){ steps = (rem + 127) >> 7; if (steps > sa) steps = sa; }
    }
    f32x4 acc = {0.f,0.f,0.f,0.f};
    const unsigned short* xp = x + (long)(bh*16 + n16)*Khat;
    const int row = og*16 + n16;

    auto stage = [&](int s, int bsel){
        const int k0 = start + (s<<7);
        const bool swz = (k0 + 128 <= Kw);
        unsigned char* base = lbuf + bsel*16384;
        if constexpr (WF){
            const int r0 = wave*8;
            #pragma unroll
            for (int c=0;c<4;c++){
                const int rr = r0 + 2*c + (lane>>5);
                const int cs = swz ? ((lane&31) ^ (rr&7)) : (lane&31);
                long koff = (long)k0 + cs*4;
                const float* ga = w + (long)(bx*32 + rr)*Kw + koff;
                if (!swz && (koff + 4 > Kw)) ga = w + (long)(bx*32 + rr)*Kw;  // x=0 there
                GLD_LDS16(ga, base + (r0 + 2*c)*512);
            }
        } else {
            const int r0 = wave*8;
            #pragma unroll
            for (int c=0;c<2;c++){
                const int rr = r0 + 4*c + (lane>>4);
                const int cs = swz ? ((lane&15) ^ (rr&7)) : (lane&15);
                long koff = (long)k0 + cs*8;
                const WT* ga = w + (long)(bx*32 + rr)*Kw + koff;
                if (!swz && (koff + 8 > Kw)) ga = w + (long)(bx*32 + rr)*Kw;
                GLD_LDS16(ga, base + (r0 + 4*c)*256);
            }
        }
    };
    auto consume = [&](int s, int bsel){
        const int k0 = start + (s<<7);
        const bool swz = (k0 + 128 <= Kw);
        const unsigned char* base = lbuf + bsel*16384;
        #pragma unroll
        for (int kk=0; kk<4; kk++){
            const int ka = k0 + kk*32 + quad*8;
            const short8 x8 = *(const short8*)&xp[ka];
            short8 bw;
            if constexpr (WF){
                const int c0 = kk*8 + quad*2;
                const int p0 = swz ? (c0 ^ (row&7)) : c0;
                const int p1 = swz ? ((c0+1) ^ (row&7)) : (c0+1);
                float wv[8];
                *(f32x4*)&wv[0] = *(const f32x4*)&base[row*512 + p0*16];
                *(f32x4*)&wv[4] = *(const f32x4*)&base[row*512 + p1*16];
                bw = pack8(wv);
            } else {
                const int c0 = kk*4 + quad;
                const int p0 = swz ? (c0 ^ (row&7)) : c0;
                bw = *(const short8*)&base[row*256 + p0*16];
            }
            acc = __builtin_amdgcn_mfma_f32_16x16x32_bf16(x8, bw, acc, 0,0,0);
        }
    };

    if (steps > 0){
        stage(0, 0);
        __syncthreads();
        for (int s=0; s<steps; s++){
            if (s+1 < steps) stage(s+1, (s+1)&1);
            consume(s, s&1);
            __syncthreads();
        }
    }
    const int o = bx*32 + og*16 + n16;
    if (o < Nvalid){
        #pragma unroll
        for (int r=0;r<4;r++)
            atomicAdd(&y[(long)(bh*16 + quad*4 + r)*N + o], acc[r]);
    }
}

__global__ __launch_bounds__(256) void k_fcL(const unsigned short* __restrict__ x,
        const void* __restrict__ w, const int* __restrict__ flag,
        float* __restrict__ y, int Kw, int Khat, int N, int Kc, int Nvalid)
{
    __shared__ unsigned char lbuf[2*16384];
    if (*flag) fcl_body<float>(x, (const float*)w, y, Kw, Khat, N, Kc, Nvalid, lbuf);
    else       fcl_body<bf16 >(x, (const bf16 *)w, y, Kw, Khat, N, Kc, Nvalid, lbuf);
}

// ---------------- fc3 (tiny): register-pipelined MFMA ----------------
template<typename WT>
__device__ __forceinline__ void fcm_loop(const unsigned short* __restrict__ xp,
        const WT* __restrict__ wp, int start, int end, int quad, f32x4& acc)
{
    const int nfull = (end - start) >> 5;
    const int end32 = start + (nfull << 5);
    const int qo = quad*8;

    short8 xA, xB, xC;
    short8 bwA, bwB, bwC;
    f32x4 wA0, wA1, wB0, wB1, wC0, wC1;

    auto loadA = [&](int k0){
        const int ka = k0 + qo;
        xA = *(const short8*)&xp[ka];
        if constexpr (__is_same(WT, bf16)) bwA = *(const short8*)&wp[ka];
        else { wA0 = *(const f32x4*)&wp[ka]; wA1 = *(const f32x4*)&wp[ka+4]; }
    };
    auto loadB = [&](int k0){
        const int ka = k0 + qo;
        xB = *(const short8*)&xp[ka];
        if constexpr (__is_same(WT, bf16)) bwB = *(const short8*)&wp[ka];
        else { wB0 = *(const f32x4*)&wp[ka]; wB1 = *(const f32x4*)&wp[ka+4]; }
    };
    auto loadC = [&](int k0){
        const int ka = k0 + qo;
        xC = *(const short8*)&xp[ka];
        if constexpr (__is_same(WT, bf16)) bwC = *(const short8*)&wp[ka];
        else { wC0 = *(const f32x4*)&wp[ka]; wC1 = *(const f32x4*)&wp[ka+4]; }
    };
    auto compA = [&](){
        short8 bw;
        if constexpr (__is_same(WT, bf16)) bw = bwA;
        else { float wv[8]; *(f32x4*)&wv[0]=wA0; *(f32x4*)&wv[4]=wA1; bw = pack8(wv); }
        acc = __builtin_amdgcn_mfma_f32_16x16x32_bf16(xA, bw, acc, 0,0,0);
    };
    auto compB = [&](){
        short8 bw;
        if constexpr (__is_same(WT, bf16)) bw = bwB;
        else { float wv[8]; *(f32x4*)&wv[0]=wB0; *(f32x4*)&wv[4]=wB1; bw = pack8(wv); }
        acc = __builtin_amdgcn_mfma_f32_16x16x32_bf16(xB, bw, acc, 0,0,0);
    };
    auto compC = [&](){
        short8 bw;
        if constexpr (__is_same(WT, bf16)) bw = bwC;
        else { float wv[8]; *(f32x4*)&wv[0]=wC0; *(f32x4*)&wv[4]=wC1; bw = pack8(wv); }
        acc = __builtin_amdgcn_mfma_f32_16x16x32_bf16(xC, bw, acc, 0,0,0);
    };

    if (nfull >= 3){
        loadA(start); loadB(start+32); loadC(start+64);
        int j = 0;
        for (; j + 6 <= nfull; j += 3){
            compA(); loadA(start + ((j+3)<<5));
            compB(); loadB(start + ((j+4)<<5));
            compC(); loadC(start + ((j+5)<<5));
        }
        const int rem = nfull - j;
        if (rem == 3){ compA(); compB(); compC(); }
        else if (rem == 4){
            compA(); loadA(start + ((j+3)<<5));
            compB(); compC(); compA();
        } else {
            compA(); loadA(start + ((j+3)<<5));
            compB(); loadB(start + ((j+4)<<5));
            compC(); compA(); compB();
        }
    } else if (nfull == 2){
        loadA(start); loadB(start+32); compA(); compB();
    } else if (nfull == 1){
        loadA(start); compA();
    }
    if (end32 < end){
        const int ka = end32 + qo;
        float xv[8], wv[8];
        #pragma unroll
        for (int j=0;j<8;j++){
            const bool v = (ka + j) < end;
            xv[j] = v ? b2f(((const bf16*)xp)[ka+j]) : 0.f;
            wv[j] = v ? (float)ld(wp, ka+j) : 0.f;
        }
        acc = __builtin_amdgcn_mfma_f32_16x16x32_bf16(pack8(xv), pack8(wv), acc, 0,0,0);
    }
}

__global__ __launch_bounds__(256,4) void k_fcM(const unsigned short* __restrict__ x,
        const void* __restrict__ w, const int* __restrict__ flag,
        float* __restrict__ y, int K, int N, int Kc, int Nvalid)
{
    const int t = threadIdx.x;
    const int wave = t>>6, lane = t&63;
    const int quad = lane>>4, n16 = lane&15;
    const int og = wave>>1, bh = wave&1;
    const int o = blockIdx.x*32 + og*16 + n16;
    const int orow = (o < Nvalid) ? o : (Nvalid-1);
    const int xrow = bh*16 + n16;
    const int start = blockIdx.y*Kc;
    const int end = min(K, start + Kc);
    f32x4 acc = {0.f,0.f,0.f,0.f};
    const unsigned short* xp = x + (long)xrow*K;
    if (*flag) fcm_loop<float>(xp, (const float*)w + (long)orow*K, start, end, quad, acc);
    else       fcm_loop<bf16 >(xp, (const bf16 *)w + (long)orow*K, start, end, quad, acc);
    if (o < Nvalid){
        #pragma unroll
        for (int r=0;r<4;r++)
            atomicAdd(&y[(long)(bh*16 + quad*4 + r)*N + o], acc[r]);
    }
}

// ---------------- paired log_softmax over axis 1 of [32,2,12] ----------------
__global__ void k_lsm(const float* __restrict__ in, const int* __restrict__ flag,
                      void* __restrict__ out)
{
    const int i = threadIdx.x;
    if (i >= 384) return;
    const int b = i/12, au = i%12;
    const float a0 = in[b*24+au], a1 = in[b*24+12+au];
    const float m = fmaxf(a0,a1);
    const float lse = m + logf(expf(a0-m)+expf(a1-m));
    const float o0 = a0-lse, o1 = a1-lse;
    if (*flag){
        ((float*)out)[b*24+au]    = o0;
        ((float*)out)[b*24+12+au] = o1;
    } else {
        ((bf16*)out)[b*24+au]    = __float2bfloat16(o0);
        ((bf16*)out)[b*24+12+au] = __float2bfloat16(o1);
    }
}

extern "C" void kernel_launch(void* const* d_in, const int* in_sizes, int n_in,
                              void* d_out, int out_size, void* d_ws, size_t ws_size,
                              hipStream_t stream) {
    (void)in_sizes; (void)n_in; (void)out_size; (void)ws_size;
    const void* x = d_in[0];

    float* A = (float*)d_ws;               // 26,214,400 floats
    float* B = A + 26214400;               //  6,553,600 floats
    float* P = B + 6553600;                //  P_END floats
    int* flag = (int*)(P + P_END);
    unsigned short* Xp = (unsigned short*)(P + P_END + 16);  // up to 393,216 bf16

    CvtArgs a;
    const int src_idx[23] = {1,2,3,4,5,6,7,8,9,10,11,12,13,14,15,16,17,18,19,20,22,24,26};
    const int offs[23] = {OFF_C1W,OFF_C1B,OFF_RLG,OFF_RLB,OFF_RLM,OFF_RLV,OFF_RLCW,OFF_RLCB,
                          OFF_BNG,OFF_BNB,OFF_BNM,OFF_BNV,OFF_C2W,OFF_C2B,OFF_C3W,OFF_C3B,
                          OFF_C4W,OFF_C4B,OFF_C5W,OFF_C5B,OFF_F1B,OFF_F2B,OFF_F3B};
    for (int j=0;j<23;j++){ a.src[j] = d_in[src_idx[j]]; a.off[j] = offs[j]; }
    a.cw = d_in[7]; a.w2 = d_in[13]; a.w3 = d_in[15];
    a.total = P_TOTAL;

    k_sniff<<<1,256,0,stream>>>(x, flag);
    k_cvt<<<(P_TOTAL+SZ_RL+SZ_WB2+SZ_WB3+SZ_WC1+255)/256,256,0,stream>>>(a, flag, P);
    // conv1 -> A as NHWC [32,160,160,32]
    k_conv1M<<<dim3(20,5,32),256,0,stream>>>(x, flag, P, A);
    // region -> B as NHWC pooled [32,80,80,32]
    k_regionM<<<2048,256,0,stream>>>(A, P, B);
    // conv2: NHWC in -> NHWC out A [32,73,73,16]
    k_convM<32,80,80,73,73,true><<<dim3(5,5,32),256,0,stream>>>(B, (const unsigned short*)(P+OFF_WB2), P+OFF_C2B, A);
    // conv3: NHWC in -> NCHW out B [32,16,66,66]
    k_convM<16,73,73,66,66,false><<<dim3(5,5,32),256,0,stream>>>(A, (const unsigned short*)(P+OFF_WB3), P+OFF_C3B, B);
    // conv4: stride 2 -> A [32,16,31,31] (NCHW), 4 outputs/thread
    k_convN<16,16,6,2,66,66,31,31,8,4,false,0><<<dim3(1,16,32),256,0,stream>>>(B, P+OFF_C4W, P+OFF_C4B, A);
    // conv5: -> bf16 Xp rows [32][12288] directly (k = co*729 + y*27 + x)
    k_convN<16,16,5,1,31,31,27,27,7,4,true,12288><<<dim3(1,16,32),256,0,stream>>>(A, P+OFF_C5W, P+OFF_C5B, Xp);
    // fc1: K=11664 (pad 12288) -> 4096; y=A; bias-init + Xp pad-zero fused
    k_fc1prep<<<512,256,0,stream>>>(A, P+OFF_F1B, Xp);
    k_fcL<<<dim3(128,16),256,0,stream>>>(Xp, d_in[21], flag, A, 11664, 12288, 4096, 768, 4096);
    // fc2: K=4096 -> 2048; relu folded into pack, y=B
    k_xpack<<<(32*(4096/8)+255)/256,256,0,stream>>>(A, Xp, 32, 4096, 4096, 1);
    k_binit<<<(32*2048+255)/256,256,0,stream>>>(B, P+OFF_F2B, 2048);
    k_fcL<<<dim3(64,16),256,0,stream>>>(Xp, d_in[23], flag, B, 4096, 4096, 2048, 256, 2048);
    // fc3: K=2048 -> 24; relu folded into pack, y=A
    k_xpack<<<(32*(2048/8)+255)/256,256,0,stream>>>(B, Xp, 32, 2048, 2048, 1);
    k_binit<<<(32*24+255)/256,256,0,stream>>>(A, P+OFF_F3B, 24);
    k_fcM<<<dim3(1,64),256,0,stream>>>(Xp, d_in[25], flag, A, 2048, 24, 32, 24);
    k_lsm<<<1,384,0,stream>>>(A, flag, d_out);
}

// Round 5
// 584.004 us; speedup vs baseline: 1.2970x; 1.0044x over previous
//
#include <hip/hip_runtime.h>
#include <hip/hip_bf16.h>

typedef __hip_bfloat16 bf16;
typedef __attribute__((ext_vector_type(8))) short short8;
typedef __attribute__((ext_vector_type(4))) float f32x4;
typedef __attribute__((ext_vector_type(16))) float f32x16;

__device__ __forceinline__ float b2f(const bf16 v){ return __bfloat162float(v); }
__device__ __forceinline__ float ld(const float* p, long i){ return p[i]; }
__device__ __forceinline__ float ld(const bf16*  p, long i){ return b2f(p[i]); }

__device__ __forceinline__ unsigned f2bf_u(float f){
    union { float f; unsigned u; } a; a.f = f;
    unsigned r = a.u + 0x7FFFu + ((a.u >> 16) & 1u);
    return r >> 16;
}

__device__ __forceinline__ short8 pack8(const float* v){
    union { __hip_bfloat162 h[4]; short8 s; } r;
    #pragma unroll
    for (int i=0;i<4;i++)
        r.h[i] = __float22bfloat162_rn(float2{v[2*i], v[2*i+1]});
    return r.s;
}

__device__ __forceinline__ uint2 pack4(const float* v){
    union { __hip_bfloat162 h[2]; uint2 u; } r;
    r.h[0] = __float22bfloat162_rn(float2{v[0], v[1]});
    r.h[1] = __float22bfloat162_rn(float2{v[2], v[3]});
    return r.u;
}

__device__ __forceinline__ void unp8(uint4 u, float* v){
    union { unsigned x; float f; } a;
    a.x = u.x<<16; v[0]=a.f; a.x = u.x&0xffff0000u; v[1]=a.f;
    a.x = u.y<<16; v[2]=a.f; a.x = u.y&0xffff0000u; v[3]=a.f;
    a.x = u.z<<16; v[4]=a.f; a.x = u.z&0xffff0000u; v[5]=a.f;
    a.x = u.w<<16; v[6]=a.f; a.x = u.w&0xffff0000u; v[7]=a.f;
}

__device__ __forceinline__ void unp4(uint2 u, float* v){
    union { unsigned x; float f; } a;
    a.x = u.x<<16; v[0]=a.f; a.x = u.x&0xffff0000u; v[1]=a.f;
    a.x = u.y<<16; v[2]=a.f; a.x = u.y&0xffff0000u; v[3]=a.f;
}

#define GLD_LDS16(g, l) __builtin_amdgcn_global_load_lds( \
    (const __attribute__((address_space(1))) void*)(g), \
    (__attribute__((address_space(3))) void*)(l), 16, 0, 0)

// ---- converted-params block offsets (floats) within P ----
#define OFF_C1W   0        /* 11616 */
#define OFF_C1B   11616    /* 32   */
#define OFF_RLG   11648    /* 2048 */
#define OFF_RLB   13696
#define OFF_RLM   15744
#define OFF_RLV   17792
#define OFF_RLCW  19840    /* 589824 slots: bf16 WR [net][tap9][half2][lane64][j8] */
#define OFF_RLCB  609664   /* 2048 */
#define OFF_BNG   611712
#define OFF_BNB   611744
#define OFF_BNM   611776
#define OFF_BNV   611808
#define OFF_C2W   611840   /* 32768 */
#define OFF_C2B   644608
#define OFF_C3W   644624   /* 16384 */
#define OFF_C3B   661008
#define OFF_C4W   661024   /* 9216 */
#define OFF_C4B   670240
#define OFF_C5W   670256   /* 6400 */
#define OFF_C5B   676656
#define OFF_F1B   676672   /* 4096 */
#define OFF_F2B   680768   /* 2048 */
#define OFF_F3B   682816   /* 24   */
#define P_TOTAL   682840
#define OFF_WB2   P_TOTAL             /* 32768 bf16 = 16384 f32 slots */
#define OFF_WB3   (P_TOTAL + 16384)   /* 16384 bf16 = 8192 f32 slots  */
#define OFF_WC1   (P_TOTAL + 16384 + 8192)  /* 16896 bf16 = 8448 f32 slots */
#define P_END     (OFF_WC1 + 8448)

#define SZ_RL  589824
#define SZ_WB2 32768
#define SZ_WB3 16384
#define SZ_WC1 16896

// ---------- dtype sniff: flag=1 if inputs are float32, 0 if bf16 ----------
__global__ void k_sniff(const void* __restrict__ x, int* __restrict__ flag)
{
    const bf16* xb = (const bf16*)x;
    const float v = fabsf(b2f(xb[2*threadIdx.x]));
    const int ok = (v >= 1e-6f && v <= 1e6f) ? 1 : 0;
    __shared__ int cnt;
    if (threadIdx.x == 0) cnt = 0;
    __syncthreads();
    atomicAdd(&cnt, ok);
    __syncthreads();
    if (threadIdx.x == 0) *flag = (cnt >= 192) ? 0 : 1;
}

// ---------- convert params to f32 block P + bf16 fragment-layout weight blocks ----------
struct CvtArgs { const void* src[23]; int off[23]; const void* cw; const void* w2; const void* w3; int total; };

__device__ __forceinline__ float getv(const void* p, long i, bool isf){
    return isf ? ((const float*)p)[i] : b2f(((const bf16*)p)[i]);
}

__global__ __launch_bounds__(256) void k_cvt(CvtArgs a, const int* __restrict__ flag,
                                             float* __restrict__ P)
{
    const bool isf = (*flag != 0);
    const int i1 = a.total;            // region WR frags (bf16, in rl_cw slot)
    const int i2 = i1 + SZ_RL;         // WB2
    const int i3 = i2 + SZ_WB2;        // WB3
    const int i4 = i3 + SZ_WB3;        // WC1
    const int i5 = i4 + SZ_WC1;
    for (int idx = blockIdx.x*256 + threadIdx.x; idx < i5; idx += gridDim.x*256){
        if (idx < i1){
            if (idx >= OFF_RLCW && idx < OFF_RLCB) continue;   // slot reused for WR
            int k = 0;
            #pragma unroll
            for (int j = 1; j < 23; j++) if (idx >= a.off[j]) k = j;
            P[idx] = getv(a.src[k], idx - a.off[k], isf);
        } else if (idx < i2){
            // WR[net][tap][half][lane][j]: A-frag (weights, M=co16) for region
            const int d = idx - i1;
            const int net = d / 9216, dn = d % 9216;
            const int tap = dn >> 10, rem = dn & 1023;
            const int half = rem >> 9, lane = (rem >> 3) & 63, j = rem & 7;
            const int co = half*16 + (lane & 15);
            const int ci = ((lane >> 4) << 3) + j;
            const long sidx = (long)((net*32 + co)*32 + ci)*9 + tap;
            ((unsigned short*)(P + OFF_RLCW))[d] = (unsigned short)f2bf_u(getv(a.cw, sidx, isf));
        } else if (idx < i3){
            // WB2[tap][lane][j]: B-frag layout for conv2 (K=32ci)
            const int d = idx - i2;
            const int j = d & 7, lane = (d >> 3) & 63, tap = d >> 9;
            const int n = lane & 15, k = ((lane >> 4) << 3) + j;
            const int ci = k, ky = tap >> 3, kx = tap & 7;
            const long sidx = (long)((n*32 + ci)*8 + ky)*8 + kx;
            ((unsigned short*)(P + OFF_WB2))[d] = (unsigned short)f2bf_u(getv(a.w2, sidx, isf));
        } else if (idx < i4){
            // WB3[pair][lane][j]: B-frag layout for conv3 (K=16ci x 2 taps)
            const int d = idx - i3;
            const int j = d & 7, lane = (d >> 3) & 63, pair = d >> 9;
            const int n = lane & 15, k = ((lane >> 4) << 3) + j;
            const int tsel = k >> 4, ci = k & 15;
            const int ky = pair >> 2, kx = ((pair & 3) << 1) + tsel;
            const long sidx = (long)((n*16 + ci)*8 + ky)*8 + kx;
            ((unsigned short*)(P + OFF_WB3))[d] = (unsigned short)f2bf_u(getv(a.w3, sidx, isf));
        } else {
            // WC1[ky][ch][lane][j]: A-frag (weights, M=co32) for conv1, K=16 = 4kx x 4ci
            const int d = idx - i4;
            const int ky = d / 1536, rem = d % 1536;
            const int ch = rem >> 9, rem2 = rem & 511;
            const int lane = rem2 >> 3, j = rem2 & 7;
            const int co = lane & 31, h5 = lane >> 5;
            const int kx = ch*4 + h5*2 + (j >> 2), ci = j & 3;
            float v = 0.f;
            if (ci < 3 && kx < 11)
                v = getv(a.src[0], (long)((co*3 + ci)*11 + ky)*11 + kx, isf);
            ((unsigned short*)(P + OFF_WC1))[d] = (unsigned short)f2bf_u(v);
        }
    }
}

// ---------------- conv1 via 32x32x16 MFMA: x[32,3,170,170] -> bf16 NHWC [32,160,160,32] ----------------
__global__ __launch_bounds__(256,3) void k_conv1M(const void* __restrict__ x,
        const int* __restrict__ flag, const float* __restrict__ P, unsigned short* __restrict__ out)
{
    __shared__ unsigned short xs[18*44*4];     // [row18][col44][ci4] bf16, 6336 B
    __shared__ unsigned short wsm[SZ_WC1];     // 33792 B
    const int t = threadIdx.x;
    const int y0 = blockIdx.x*8, x0 = blockIdx.y*32, b = blockIdx.z;
    { const uint4* src = (const uint4*)(P + OFF_WC1);
      uint4* dst = (uint4*)wsm;
      for (int e=t; e<2112; e+=256) dst[e] = src[e]; }
    const bool isf = (*flag) != 0;
    for (int e=t; e<792; e+=256){
        const int r = e/44, c = e%44;
        const long base = ((long)(b*3)*170 + (y0+r))*170 + min(x0+c, 169);
        float v0, v1, v2;
        if (isf){
            const float* xf = (const float*)x;
            v0 = xf[base]; v1 = xf[base+28900]; v2 = xf[base+57800];
        } else {
            const bf16* xf = (const bf16*)x;
            v0 = b2f(xf[base]); v1 = b2f(xf[base+28900]); v2 = b2f(xf[base+57800]);
        }
        uint2 u;
        u.x = f2bf_u(v0) | (f2bf_u(v1) << 16);
        u.y = f2bf_u(v2);
        *(uint2*)&xs[(r*44+c)*4] = u;
    }
    __syncthreads();
    const int wave = t>>6, lane = t&63;
    const int n = lane & 31, h5 = lane >> 5;
    const int r0 = wave*2;
    f32x16 acc0 = {0.f}, acc1 = {0.f};
    #pragma unroll
    for (int e=0;e<16;e++){ acc0[e]=0.f; acc1[e]=0.f; }
    #pragma unroll 1
    for (int ky=0; ky<11; ky++){
        #pragma unroll
        for (int ch=0; ch<3; ch++){
            const short8 aw = *(const short8*)&wsm[((ky*3+ch)*64 + lane)*8];
            const int kx0 = ch*4 + h5*2;
            const int a0 = ((r0+ky)*44 + n + kx0)*4;
            const int a1 = ((r0+1+ky)*44 + n + kx0)*4;
            union { uint2 u2[2]; short8 s; } ub0, ub1;
            ub0.u2[0] = *(const uint2*)&xs[a0];
            ub0.u2[1] = *(const uint2*)&xs[a0+4];
            ub1.u2[0] = *(const uint2*)&xs[a1];
            ub1.u2[1] = *(const uint2*)&xs[a1+4];
            acc0 = __builtin_amdgcn_mfma_f32_32x32x16_bf16(aw, ub0.s, acc0, 0,0,0);
            acc1 = __builtin_amdgcn_mfma_f32_32x32x16_bf16(aw, ub1.s, acc1, 0,0,0);
        }
    }
    // D: col = lane&31 = pixel-col, row(co) = (reg&3) + 8*(reg>>2) + 4*h5
    // bf16 NHWC store: 4 consecutive co per reg-group of 4
    unsigned short* opb = out + ((long)b*25600 + (long)(y0+r0)*160 + x0 + n)*32;
    #pragma unroll
    for (int g=0; g<4; g++){
        const int co0 = 8*g + 4*h5;
        const f32x4 bv = *(const f32x4*)&P[OFF_C1B + co0];
        float s0[4], s1[4];
        #pragma unroll
        for (int r=0;r<4;r++){ s0[r] = acc0[4*g+r] + bv[r]; s1[r] = acc1[4*g+r] + bv[r]; }
        *(uint2*)(opb + co0) = pack4(s0);
        *(uint2*)(opb + 160*32 + co0) = pack4(s1);
    }
}

// ------- region layer via 16x16x32 MFMA; bf16 NHWC in, bf16 NHWC pooled out -------
__global__ __launch_bounds__(256,2) void k_regionM(const unsigned short* __restrict__ in,
        const float* __restrict__ P, unsigned short* __restrict__ pooled)
{
    __shared__ unsigned short s_in[484*32];    // [pix 22x22][ci32] bf16, 30976 B
    __shared__ unsigned short wsm[9216];       // [tap9][half2][lane64][j8], 18432 B
    __shared__ float sc[32], sh[32];
    const int t = threadIdx.x;
    const int b = blockIdx.x & 31, kk = blockIdx.x >> 5;
    const int gi = kk >> 3, gj = kk & 7;
    const int net = gj*(gi+1);                 // idx = ii*jj + jj
    const long pbase = ((long)b*25600 + (long)(gi*20)*160 + gj*20)*32;
    if (t < 32){
        const float inv = rsqrtf(P[OFF_RLV+net*32+t]+1e-5f)*P[OFF_RLG+net*32+t];
        sc[t] = inv; sh[t] = P[OFF_RLB+net*32+t] - P[OFF_RLM+net*32+t]*inv;
    }
    { const uint4* src = (const uint4*)((const unsigned short*)(P+OFF_RLCW) + (size_t)net*9216);
      uint4* dst = (uint4*)wsm;
      for (int e=t; e<1152; e+=256) dst[e] = src[e]; }
    __syncthreads();
    // stage BN+ReLU patch, zero halo: contiguous bf16 NHWC 8-ch reads
    for (int e=t; e<1936; e+=256){
        const int o = e & 3, p = e >> 2;
        const int pr = p/22, pc = p%22;
        short8 pk = {0,0,0,0,0,0,0,0};
        if (pr>0 && pr<21 && pc>0 && pc<21){
            const long a = pbase + ((long)(pr-1)*160 + (pc-1))*32 + o*8;
            const uint4 u = *(const uint4*)&in[a];
            float v[8];
            unp8(u, v);
            #pragma unroll
            for (int j=0;j<8;j++){
                const int ci = o*8 + j;
                v[j] = fmaxf(fmaf(v[j], sc[ci], sh[ci]), 0.f);
            }
            pk = pack8(v);
        }
        *(short8*)&s_in[p*32 + o*8] = pk;
    }
    __syncthreads();
    const int wave = t>>6, lane = t&63;
    const int q = lane>>4, n = lane&15;
    const int dr = n>>2, dc = n&3;
    const int nt = (wave==0) ? 7 : 6;          // 25 tiles over 4 waves
    int trs[7], tcs[7];
    #pragma unroll
    for (int i=0;i<7;i++){ const int tt = 4*i + wave; trs[i] = tt/5; tcs[i] = tt - 5*(tt/5); }
    f32x4 acc[7][2];
    {   float bias_v[2][4];
        #pragma unroll
        for (int h=0;h<2;h++)
            #pragma unroll
            for (int r=0;r<4;r++) bias_v[h][r] = P[OFF_RLCB + net*32 + h*16 + q*4 + r];
        #pragma unroll
        for (int i=0;i<7;i++)
            #pragma unroll
            for (int h=0;h<2;h++)
                acc[i][h] = (f32x4){bias_v[h][0], bias_v[h][1], bias_v[h][2], bias_v[h][3]};
    }
    #pragma unroll 1
    for (int tap=0; tap<9; tap++){
        const int ky = tap/3, kx = tap - 3*(tap/3);
        const short8 a0 = *(const short8*)&wsm[(tap*2+0)*512 + lane*8];
        const short8 a1 = *(const short8*)&wsm[(tap*2+1)*512 + lane*8];
        #pragma unroll
        for (int i=0;i<7;i++){
            if (i < nt){
                const int srow = trs[i]*4 + dr + ky, scol = tcs[i]*4 + dc + kx;
                const short8 bx = *(const short8*)&s_in[(srow*22 + scol)*32 + q*8];
                acc[i][0] = __builtin_amdgcn_mfma_f32_16x16x32_bf16(a0, bx, acc[i][0], 0,0,0);
                acc[i][1] = __builtin_amdgcn_mfma_f32_16x16x32_bf16(a1, bx, acc[i][1], 0,0,0);
            }
        }
    }
    // epilogue: residual + relu + 2x2 shuffle-pool + bn; bf16 residual reads + bf16 pooled stores
    float bnsc[2][4], bnsh[2][4];
    #pragma unroll
    for (int h=0;h<2;h++)
        #pragma unroll
        for (int r=0;r<4;r++){
            const int co = h*16 + q*4 + r;
            const float inv = rsqrtf(P[OFF_BNV+co]+1e-5f)*P[OFF_BNG+co];
            bnsc[h][r] = inv; bnsh[h][r] = P[OFF_BNB+co] - P[OFF_BNM+co]*inv;
        }
    const bool wr = ((n & 5) == 0);            // dc even && dr even
    #pragma unroll
    for (int i=0;i<7;i++){
        if (i < nt){
            const int prow = trs[i]*4 + dr, pcol = tcs[i]*4 + dc;
            const long ra = pbase + ((long)prow*160 + pcol)*32;
            const long pa0 = ((long)b*6400 + (long)(gi*10 + trs[i]*2 + (dr>>1))*80
                              + gj*10 + tcs[i]*2 + (dc>>1))*32;
            #pragma unroll
            for (int h=0;h<2;h++){
                const uint2 ru = *(const uint2*)&in[ra + h*16 + q*4];
                float res[4];
                unp4(ru, res);
                float pv[4];
                #pragma unroll
                for (int r=0;r<4;r++){
                    float v = acc[i][h][r] + res[r];
                    v = fmaxf(v, 0.f);
                    v = fmaxf(v, __shfl_xor(v, 1, 64));
                    v = fmaxf(v, __shfl_xor(v, 4, 64));
                    pv[r] = fmaf(v, bnsc[h][r], bnsh[h][r]);
                }
                if (wr) *(uint2*)&pooled[pa0 + h*16 + q*4] = pack4(pv);
            }
        }
    }
}

// ------- conv2/conv3 via MFMA shift-GEMM; bf16 NHWC input (pure memcpy stage) -------
template<int CIN, int HIN, int WIN, int HOUT, int WOUT, bool NHWC_OUT>
__global__ __launch_bounds__(256) void k_convM(const unsigned short* __restrict__ in,
        const unsigned short* __restrict__ WB, const float* __restrict__ bias,
        void* __restrict__ outv)
{
    constexpr int PP = 23;
    constexpr bool C32 = (CIN == 32);
    __shared__ unsigned short xs[PP*PP*CIN];
    __shared__ unsigned short ws[C32 ? 16*64*8 : 32*64*8];
    const int t = threadIdx.x;
    const int col0 = blockIdx.x*16, row0 = blockIdx.y*16, b = blockIdx.z;
    for (int e = t; e < PP*PP*(CIN/8); e += 256){
        const int o = e % (CIN/8), pix = e / (CIN/8);
        int rr = row0 + pix/PP; if (rr > HIN-1) rr = HIN-1;
        int cc = col0 + pix%PP; if (cc > WIN-1) cc = WIN-1;
        const uint4 v = *(const uint4*)&in[((long)b*HIN*WIN + (long)rr*WIN + cc)*CIN + o*8];
        *(uint4*)&xs[pix*CIN + o*8] = v;
    }
    const int wave = t>>6, lane = t&63;
    const int quad = lane>>4, n16 = lane&15;
    const float bv = bias[n16];
    f32x4 acc[4];
    #pragma unroll
    for (int mt=0;mt<4;mt++) acc[mt] = (f32x4){bv,bv,bv,bv};
    if constexpr (C32){
        for (int ch=0; ch<4; ch++){
            __syncthreads();
            const unsigned* src = (const unsigned*)WB + ch*4096;
            for (int e=t; e<4096; e+=256) ((unsigned*)ws)[e] = src[e];
            __syncthreads();
            #pragma unroll 1
            for (int tap=0; tap<16; tap++){
                const int tg = ch*16+tap, ky = tg>>3, kx = tg&7;
                const short8 bw = *(const short8*)&ws[(tap*64+lane)*8];
                #pragma unroll
                for (int mt=0; mt<4; mt++){
                    const int pr = wave*4+mt+ky, pc = n16+kx;
                    const short8 av = *(const short8*)&xs[(pr*PP+pc)*32 + quad*8];
                    acc[mt] = __builtin_amdgcn_mfma_f32_16x16x32_bf16(av, bw, acc[mt], 0,0,0);
                }
            }
        }
    } else {
        for (int e=t; e<8192; e+=256) ((unsigned*)ws)[e] = ((const unsigned*)WB)[e];
        __syncthreads();
        #pragma unroll 1
        for (int pair=0; pair<32; pair++){
            const int ky = pair>>2, kx0 = (pair&3)*2;
            const short8 bw = *(const short8*)&ws[(pair*64+lane)*8];
            #pragma unroll
            for (int mt=0; mt<4; mt++){
                const int pr = wave*4+mt+ky, pc = n16 + kx0 + (quad>>1);
                const short8 av = *(const short8*)&xs[(pr*PP+pc)*16 + (quad&1)*8];
                acc[mt] = __builtin_amdgcn_mfma_f32_16x16x32_bf16(av, bw, acc[mt], 0,0,0);
            }
        }
    }
    #pragma unroll
    for (int mt=0; mt<4; mt++){
        const int orow = row0 + wave*4 + mt;
        if (orow >= HOUT) continue;
        const int ocol = col0 + quad*4;
        #pragma unroll
        for (int r=0;r<4;r++){
            if (ocol + r < WOUT){
                const float v = fmaxf(acc[mt][r], 0.f);
                if constexpr (NHWC_OUT)
                    ((unsigned short*)outv)[((long)b*HOUT*WOUT + (long)orow*WOUT + ocol + r)*16 + n16]
                        = (unsigned short)f2bf_u(v);
                else
                    ((float*)outv)[((long)(b*16 + n16)*HOUT + orow)*WOUT + ocol + r] = v;
            }
        }
    }
}

// ---------------- direct conv (+relu) for conv4/conv5, OW outputs/thread ----------------
template<int CIN, int COUT, int KS, int STRIDE, int HIN, int WIN, int HOUT, int WOUT,
         int NG, int OW, bool BF16OUT, int ROWPAD>
__global__ __launch_bounds__(256,2) void k_convN(const float* __restrict__ in,
        const float* __restrict__ w, const float* __restrict__ bias, void* __restrict__ outv)
{
    __shared__ float wl[CIN*KS*KS];
    const int co = blockIdx.y, b = blockIdx.z;
    for (int j=threadIdx.x; j<CIN*KS*KS; j+=blockDim.x) wl[j] = w[co*CIN*KS*KS + j];
    __syncthreads();
    const int i = blockIdx.x*blockDim.x + threadIdx.x;
    if (i >= HOUT*NG) return;
    const int y = i / NG, x0 = (i % NG) * OW;
    float acc[OW];
    const float bv = bias[co];
    #pragma unroll
    for (int j=0;j<OW;j++) acc[j]=bv;
    constexpr int SPAN = STRIDE*(OW-1) + KS;
    for (int ci=0; ci<CIN; ci++){
        #pragma unroll
        for (int ky=0; ky<KS; ky++){
            const float* ip = in + ((long)(b*CIN+ci)*HIN + (STRIDE*y+ky))*WIN + STRIDE*x0;
            float v[SPAN];
            #pragma unroll
            for (int j=0;j<SPAN;j++) v[j]=ip[j];
            const float* wr = &wl[(ci*KS+ky)*KS];
            #pragma unroll
            for (int kx=0;kx<KS;kx++){
                const float wv = wr[kx];
                #pragma unroll
                for (int j=0;j<OW;j++) acc[j] = fmaf(v[STRIDE*j+kx], wv, acc[j]);
            }
        }
    }
    if constexpr (BF16OUT){
        unsigned short* op = (unsigned short*)outv + (long)b*ROWPAD + (co*HOUT + y)*WOUT + x0;
        #pragma unroll
        for (int j=0;j<OW;j++)
            if (x0 + j < WOUT) op[j] = (unsigned short)f2bf_u(fmaxf(acc[j], 0.f));
    } else {
        float* op = (float*)outv + ((long)(b*COUT+co)*HOUT + y)*WOUT + x0;
        #pragma unroll
        for (int j=0;j<OW;j++)
            if (x0 + j < WOUT) op[j] = fmaxf(acc[j], 0.f);
    }
}

// ---------------- FC helpers ----------------
__global__ void k_binit(float* __restrict__ y, const float* __restrict__ bias, int N)
{
    const int i = blockIdx.x*256 + threadIdx.x;
    if (i < 32*N) y[i] = bias[i % N];
}

// fc1 prep: bias-init y AND zero the Xp K-pad region [11664,12288) per row
__global__ void k_fc1prep(float* __restrict__ y, const float* __restrict__ bias,
                          unsigned short* __restrict__ xp)
{
    const int i = blockIdx.x*256 + threadIdx.x;
    if (i < 32*4096) y[i] = bias[i & 4095];
    if (i < 19968){
        const int r = i / 624;
        xp[(long)r*12288 + 11664 + (i - r*624)] = 0;
    }
}

// pack f32 activations (optional relu) to bf16, 8 per thread, zero-pad K to Kdst
__global__ __launch_bounds__(256) void k_xpack(const float* __restrict__ in,
        unsigned short* __restrict__ out, int rows, int Ksrc, int Kdst, int relu)
{
    const int per = Kdst >> 3;
    const int i = blockIdx.x*256 + threadIdx.x;
    if (i >= rows*per) return;
    const int row = i / per, k = (i - row*per)*8;
    float v[8];
    if (k + 8 <= Ksrc){
        *(f32x4*)&v[0] = *(const f32x4*)&in[(long)row*Ksrc + k];
        *(f32x4*)&v[4] = *(const f32x4*)&in[(long)row*Ksrc + k + 4];
    } else {
        #pragma unroll
        for (int j=0;j<8;j++) v[j] = (k + j < Ksrc) ? in[(long)row*Ksrc + k + j] : 0.f;
    }
    if (relu){
        #pragma unroll
        for (int j=0;j<8;j++) v[j] = fmaxf(v[j], 0.f);
    }
    *(short8*)&out[(long)row*Kdst + k] = pack8(v);
}

// ---------------- fc1/fc2: LDS-staged GEMM via global_load_lds ----------------
template<typename WT>
__device__ __forceinline__ void fcl_body(const unsigned short* __restrict__ x,
        const WT* __restrict__ w, float* __restrict__ y,
        int Kw, int Khat, int N, int Kc, int Nvalid, unsigned char* lbuf)
{
    constexpr bool WF = __is_same(WT, float);
    const int t = threadIdx.x;
    const int wave = t>>6, lane = t&63;
    const int quad = lane>>4, n16 = lane&15;
    const int og = wave>>1, bh = wave&1;
    const int bx = blockIdx.x;
    const int start = blockIdx.y*Kc;
    int steps = 0;
    {   const int rem = Kw - start;
        const int sa = Kc >> 7;
        if (rem > 0){ steps = (rem + 127) >> 7; if (steps > sa) steps = sa; }
    }
    f32x4 acc = {0.f,0.f,0.f,0.f};
    const unsigned short* xp = x + (long)(bh*16 + n16)*Khat;
    const int row = og*16 + n16;

    auto stage = [&](int s, int bsel){
        const int k0 = start + (s<<7);
        const bool swz = (k0 + 128 <= Kw);
        unsigned char* base = lbuf + bsel*16384;
        if constexpr (WF){
            const int r0 = wave*8;
            #pragma unroll
            for (int c=0;c<4;c++){
                const int rr = r0 + 2*c + (lane>>5);
                const int cs = swz ? ((lane&31) ^ (rr&7)) : (lane&31);
                long koff = (long)k0 + cs*4;
                const float* ga = w + (long)(bx*32 + rr)*Kw + koff;
                if (!swz && (koff + 4 > Kw)) ga = w + (long)(bx*32 + rr)*Kw;  // x=0 there
                GLD_LDS16(ga, base + (r0 + 2*c)*512);
            }
        } else {
            const int r0 = wave*8;
            #pragma unroll
            for (int c=0;c<2;c++){
                const int rr = r0 + 4*c + (lane>>4);
                const int cs = swz ? ((lane&15) ^ (rr&7)) : (lane&15);
                long koff = (long)k0 + cs*8;
                const WT* ga = w + (long)(bx*32 + rr)*Kw + koff;
                if (!swz && (koff + 8 > Kw)) ga = w + (long)(bx*32 + rr)*Kw;
                GLD_LDS16(ga, base + (r0 + 4*c)*256);
            }
        }
    };
    auto consume = [&](int s, int bsel){
        const int k0 = start + (s<<7);
        const bool swz = (k0 + 128 <= Kw);
        const unsigned char* base = lbuf + bsel*16384;
        #pragma unroll
        for (int kk=0; kk<4; kk++){
            const int ka = k0 + kk*32 + quad*8;
            const short8 x8 = *(const short8*)&xp[ka];
            short8 bw;
            if constexpr (WF){
                const int c0 = kk*8 + quad*2;
                const int p0 = swz ? (c0 ^ (row&7)) : c0;
                const int p1 = swz ? ((c0+1) ^ (row&7)) : (c0+1);
                float wv[8];
                *(f32x4*)&wv[0] = *(const f32x4*)&base[row*512 + p0*16];
                *(f32x4*)&wv[4] = *(const f32x4*)&base[row*512 + p1*16];
                bw = pack8(wv);
            } else {
                const int c0 = kk*4 + quad;
                const int p0 = swz ? (c0 ^ (row&7)) : c0;
                bw = *(const short8*)&base[row*256 + p0*16];
            }
            acc = __builtin_amdgcn_mfma_f32_16x16x32_bf16(x8, bw, acc, 0,0,0);
        }
    };

    if (steps > 0){
        stage(0, 0);
        __syncthreads();
        for (int s=0; s<steps; s++){
            if (s+1 < steps) stage(s+1, (s+1)&1);
            consume(s, s&1);
            __syncthreads();
        }
    }
    const int o = bx*32 + og*16 + n16;
    if (o < Nvalid){
        #pragma unroll
        for (int r=0;r<4;r++)
            atomicAdd(&y[(long)(bh*16 + quad*4 + r)*N + o], acc[r]);
    }
}

__global__ __launch_bounds__(256) void k_fcL(const unsigned short* __restrict__ x,
        const void* __restrict__ w, const int* __restrict__ flag,
        float* __restrict__ y, int Kw, int Khat, int N, int Kc, int Nvalid)
{
    __shared__ unsigned char lbuf[2*16384];
    if (*flag) fcl_body<float>(x, (const float*)w, y, Kw, Khat, N, Kc, Nvalid, lbuf);
    else       fcl_body<bf16 >(x, (const bf16 *)w, y, Kw, Khat, N, Kc, Nvalid, lbuf);
}

// ---------------- fc3 (tiny): register-pipelined MFMA ----------------
template<typename WT>
__device__ __forceinline__ void fcm_loop(const unsigned short* __restrict__ xp,
        const WT* __restrict__ wp, int start, int end, int quad, f32x4& acc)
{
    const int nfull = (end - start) >> 5;
    const int end32 = start + (nfull << 5);
    const int qo = quad*8;

    short8 xA, xB, xC;
    short8 bwA, bwB, bwC;
    f32x4 wA0, wA1, wB0, wB1, wC0, wC1;

    auto loadA = [&](int k0){
        const int ka = k0 + qo;
        xA = *(const short8*)&xp[ka];
        if constexpr (__is_same(WT, bf16)) bwA = *(const short8*)&wp[ka];
        else { wA0 = *(const f32x4*)&wp[ka]; wA1 = *(const f32x4*)&wp[ka+4]; }
    };
    auto loadB = [&](int k0){
        const int ka = k0 + qo;
        xB = *(const short8*)&xp[ka];
        if constexpr (__is_same(WT, bf16)) bwB = *(const short8*)&wp[ka];
        else { wB0 = *(const f32x4*)&wp[ka]; wB1 = *(const f32x4*)&wp[ka+4]; }
    };
    auto loadC = [&](int k0){
        const int ka = k0 + qo;
        xC = *(const short8*)&xp[ka];
        if constexpr (__is_same(WT, bf16)) bwC = *(const short8*)&wp[ka];
        else { wC0 = *(const f32x4*)&wp[ka]; wC1 = *(const f32x4*)&wp[ka+4]; }
    };
    auto compA = [&](){
        short8 bw;
        if constexpr (__is_same(WT, bf16)) bw = bwA;
        else { float wv[8]; *(f32x4*)&wv[0]=wA0; *(f32x4*)&wv[4]=wA1; bw = pack8(wv); }
        acc = __builtin_amdgcn_mfma_f32_16x16x32_bf16(xA, bw, acc, 0,0,0);
    };
    auto compB = [&](){
        short8 bw;
        if constexpr (__is_same(WT, bf16)) bw = bwB;
        else { float wv[8]; *(f32x4*)&wv[0]=wB0; *(f32x4*)&wv[4]=wB1; bw = pack8(wv); }
        acc = __builtin_amdgcn_mfma_f32_16x16x32_bf16(xB, bw, acc, 0,0,0);
    };
    auto compC = [&](){
        short8 bw;
        if constexpr (__is_same(WT, bf16)) bw = bwC;
        else { float wv[8]; *(f32x4*)&wv[0]=wC0; *(f32x4*)&wv[4]=wC1; bw = pack8(wv); }
        acc = __builtin_amdgcn_mfma_f32_16x16x32_bf16(xC, bw, acc, 0,0,0);
    };

    if (nfull >= 3){
        loadA(start); loadB(start+32); loadC(start+64);
        int j = 0;
        for (; j + 6 <= nfull; j += 3){
            compA(); loadA(start + ((j+3)<<5));
            compB(); loadB(start + ((j+4)<<5));
            compC(); loadC(start + ((j+5)<<5));
        }
        const int rem = nfull - j;
        if (rem == 3){ compA(); compB(); compC(); }
        else if (rem == 4){
            compA(); loadA(start + ((j+3)<<5));
            compB(); compC(); compA();
        } else {
            compA(); loadA(start + ((j+3)<<5));
            compB(); loadB(start + ((j+4)<<5));
            compC(); compA(); compB();
        }
    } else if (nfull == 2){
        loadA(start); loadB(start+32); compA(); compB();
    } else if (nfull == 1){
        loadA(start); compA();
    }
    if (end32 < end){
        const int ka = end32 + qo;
        float xv[8], wv[8];
        #pragma unroll
        for (int j=0;j<8;j++){
            const bool v = (ka + j) < end;
            xv[j] = v ? b2f(((const bf16*)xp)[ka+j]) : 0.f;
            wv[j] = v ? (float)ld(wp, ka+j) : 0.f;
        }
        acc = __builtin_amdgcn_mfma_f32_16x16x32_bf16(pack8(xv), pack8(wv), acc, 0,0,0);
    }
}

__global__ __launch_bounds__(256,4) void k_fcM(const unsigned short* __restrict__ x,
        const void* __restrict__ w, const int* __restrict__ flag,
        float* __restrict__ y, int K, int N, int Kc, int Nvalid)
{
    const int t = threadIdx.x;
    const int wave = t>>6, lane = t&63;
    const int quad = lane>>4, n16 = lane&15;
    const int og = wave>>1, bh = wave&1;
    const int o = blockIdx.x*32 + og*16 + n16;
    const int orow = (o < Nvalid) ? o : (Nvalid-1);
    const int xrow = bh*16 + n16;
    const int start = blockIdx.y*Kc;
    const int end = min(K, start + Kc);
    f32x4 acc = {0.f,0.f,0.f,0.f};
    const unsigned short* xp = x + (long)xrow*K;
    if (*flag) fcm_loop<float>(xp, (const float*)w + (long)orow*K, start, end, quad, acc);
    else       fcm_loop<bf16 >(xp, (const bf16 *)w + (long)orow*K, start, end, quad, acc);
    if (o < Nvalid){
        #pragma unroll
        for (int r=0;r<4;r++)
            atomicAdd(&y[(long)(bh*16 + quad*4 + r)*N + o], acc[r]);
    }
}

// ---------------- paired log_softmax over axis 1 of [32,2,12] ----------------
__global__ void k_lsm(const float* __restrict__ in, const int* __restrict__ flag,
                      void* __restrict__ out)
{
    const int i = threadIdx.x;
    if (i >= 384) return;
    const int b = i/12, au = i%12;
    const float a0 = in[b*24+au], a1 = in[b*24+12+au];
    const float m = fmaxf(a0,a1);
    const float lse = m + logf(expf(a0-m)+expf(a1-m));
    const float o0 = a0-lse, o1 = a1-lse;
    if (*flag){
        ((float*)out)[b*24+au]    = o0;
        ((float*)out)[b*24+12+au] = o1;
    } else {
        ((bf16*)out)[b*24+au]    = __float2bfloat16(o0);
        ((bf16*)out)[b*24+12+au] = __float2bfloat16(o1);
    }
}

extern "C" void kernel_launch(void* const* d_in, const int* in_sizes, int n_in,
                              void* d_out, int out_size, void* d_ws, size_t ws_size,
                              hipStream_t stream) {
    (void)in_sizes; (void)n_in; (void)out_size; (void)ws_size;
    const void* x = d_in[0];

    float* A = (float*)d_ws;               // 26,214,400 floats
    float* B = A + 26214400;               //  6,553,600 floats
    float* P = B + 6553600;                //  P_END floats
    int* flag = (int*)(P + P_END);
    unsigned short* Xp = (unsigned short*)(P + P_END + 16);  // up to 393,216 bf16
    unsigned short* Abf = (unsigned short*)A;
    unsigned short* Bbf = (unsigned short*)B;

    CvtArgs a;
    const int src_idx[23] = {1,2,3,4,5,6,7,8,9,10,11,12,13,14,15,16,17,18,19,20,22,24,26};
    const int offs[23] = {OFF_C1W,OFF_C1B,OFF_RLG,OFF_RLB,OFF_RLM,OFF_RLV,OFF_RLCW,OFF_RLCB,
                          OFF_BNG,OFF_BNB,OFF_BNM,OFF_BNV,OFF_C2W,OFF_C2B,OFF_C3W,OFF_C3B,
                          OFF_C4W,OFF_C4B,OFF_C5W,OFF_C5B,OFF_F1B,OFF_F2B,OFF_F3B};
    for (int j=0;j<23;j++){ a.src[j] = d_in[src_idx[j]]; a.off[j] = offs[j]; }
    a.cw = d_in[7]; a.w2 = d_in[13]; a.w3 = d_in[15];
    a.total = P_TOTAL;

    k_sniff<<<1,256,0,stream>>>(x, flag);
    k_cvt<<<(P_TOTAL+SZ_RL+SZ_WB2+SZ_WB3+SZ_WC1+255)/256,256,0,stream>>>(a, flag, P);
    // conv1 -> Abf as bf16 NHWC [32,160,160,32]
    k_conv1M<<<dim3(20,5,32),256,0,stream>>>(x, flag, P, Abf);
    // region -> Bbf as bf16 NHWC pooled [32,80,80,32]
    k_regionM<<<2048,256,0,stream>>>(Abf, P, Bbf);
    // conv2: bf16 NHWC in -> bf16 NHWC out Abf [32,73,73,16]
    k_convM<32,80,80,73,73,true><<<dim3(5,5,32),256,0,stream>>>(Bbf, (const unsigned short*)(P+OFF_WB2), P+OFF_C2B, (void*)Abf);
    // conv3: bf16 NHWC in -> NCHW f32 out B [32,16,66,66]
    k_convM<16,73,73,66,66,false><<<dim3(5,5,32),256,0,stream>>>(Abf, (const unsigned short*)(P+OFF_WB3), P+OFF_C3B, (void*)B);
    // conv4: stride 2 -> A [32,16,31,31] (NCHW f32), 4 outputs/thread
    k_convN<16,16,6,2,66,66,31,31,8,4,false,0><<<dim3(1,16,32),256,0,stream>>>(B, P+OFF_C4W, P+OFF_C4B, A);
    // conv5: -> bf16 Xp rows [32][12288] directly (k = co*729 + y*27 + x)
    k_convN<16,16,5,1,31,31,27,27,7,4,true,12288><<<dim3(1,16,32),256,0,stream>>>(A, P+OFF_C5W, P+OFF_C5B, Xp);
    // fc1: K=11664 (pad 12288) -> 4096; y=A; bias-init + Xp pad-zero fused
    k_fc1prep<<<512,256,0,stream>>>(A, P+OFF_F1B, Xp);
    k_fcL<<<dim3(128,16),256,0,stream>>>(Xp, d_in[21], flag, A, 11664, 12288, 4096, 768, 4096);
    // fc2: K=4096 -> 2048; relu folded into pack, y=B
    k_xpack<<<(32*(4096/8)+255)/256,256,0,stream>>>(A, Xp, 32, 4096, 4096, 1);
    k_binit<<<(32*2048+255)/256,256,0,stream>>>(B, P+OFF_F2B, 2048);
    k_fcL<<<dim3(64,16),256,0,stream>>>(Xp, d_in[23], flag, B, 4096, 4096, 2048, 256, 2048);
    // fc3: K=2048 -> 24; relu folded into pack, y=A
    k_xpack<<<(32*(2048/8)+255)/256,256,0,stream>>>(B, Xp, 32, 2048, 2048, 1);
    k_binit<<<(32*24+255)/256,256,0,stream>>>(A, P+OFF_F3B, 24);
    k_fcM<<<dim3(1,64),256,0,stream>>>(Xp, d_in[25], flag, A, 2048, 24, 32, 24);
    k_lsm<<<1,384,0,stream>>>(A, flag, d_out);
}

// Round 6
// 569.733 us; speedup vs baseline: 1.3295x; 1.0250x over previous
//
#include <hip/hip_runtime.h>
#include <hip/hip_bf16.h>

typedef __hip_bfloat16 bf16;
typedef __attribute__((ext_vector_type(8))) short short8;
typedef __attribute__((ext_vector_type(4))) float f32x4;
typedef __attribute__((ext_vector_type(16))) float f32x16;

__device__ __forceinline__ float b2f(const bf16 v){ return __bfloat162float(v); }
__device__ __forceinline__ float ld(const float* p, long i){ return p[i]; }
__device__ __forceinline__ float ld(const bf16*  p, long i){ return b2f(p[i]); }

__device__ __forceinline__ unsigned f2bf_u(float f){
    union { float f; unsigned u; } a; a.f = f;
    unsigned r = a.u + 0x7FFFu + ((a.u >> 16) & 1u);
    return r >> 16;
}

__device__ __forceinline__ short8 pack8(const float* v){
    union { __hip_bfloat162 h[4]; short8 s; } r;
    #pragma unroll
    for (int i=0;i<4;i++)
        r.h[i] = __float22bfloat162_rn(float2{v[2*i], v[2*i+1]});
    return r.s;
}

__device__ __forceinline__ uint2 pack4(const float* v){
    union { __hip_bfloat162 h[2]; uint2 u; } r;
    r.h[0] = __float22bfloat162_rn(float2{v[0], v[1]});
    r.h[1] = __float22bfloat162_rn(float2{v[2], v[3]});
    return r.u;
}

__device__ __forceinline__ void unp8(uint4 u, float* v){
    union { unsigned x; float f; } a;
    a.x = u.x<<16; v[0]=a.f; a.x = u.x&0xffff0000u; v[1]=a.f;
    a.x = u.y<<16; v[2]=a.f; a.x = u.y&0xffff0000u; v[3]=a.f;
    a.x = u.z<<16; v[4]=a.f; a.x = u.z&0xffff0000u; v[5]=a.f;
    a.x = u.w<<16; v[6]=a.f; a.x = u.w&0xffff0000u; v[7]=a.f;
}

__device__ __forceinline__ void unp4(uint2 u, float* v){
    union { unsigned x; float f; } a;
    a.x = u.x<<16; v[0]=a.f; a.x = u.x&0xffff0000u; v[1]=a.f;
    a.x = u.y<<16; v[2]=a.f; a.x = u.y&0xffff0000u; v[3]=a.f;
}

#define GLD_LDS16(g, l) __builtin_amdgcn_global_load_lds( \
    (const __attribute__((address_space(1))) void*)(g), \
    (__attribute__((address_space(3))) void*)(l), 16, 0, 0)

// ---- converted-params block offsets (floats) within P ----
#define OFF_C1W   0        /* 11616 */
#define OFF_C1B   11616    /* 32   */
#define OFF_RLG   11648    /* 2048 */
#define OFF_RLB   13696
#define OFF_RLM   15744
#define OFF_RLV   17792
#define OFF_RLCW  19840    /* 589824 slots: bf16 WR [net][tap9][half2][lane64][j8] */
#define OFF_RLCB  609664   /* 2048 */
#define OFF_BNG   611712
#define OFF_BNB   611744
#define OFF_BNM   611776
#define OFF_BNV   611808
#define OFF_C2W   611840   /* 32768 */
#define OFF_C2B   644608
#define OFF_C3W   644624   /* 16384 */
#define OFF_C3B   661008
#define OFF_C4W   661024   /* 9216 */
#define OFF_C4B   670240
#define OFF_C5W   670256   /* 6400 */
#define OFF_C5B   676656
#define OFF_F1B   676672   /* 4096 */
#define OFF_F2B   680768   /* 2048 */
#define OFF_F3B   682816   /* 24   */
#define P_TOTAL   682840
#define OFF_WB2   P_TOTAL             /* 32768 bf16 = 16384 f32 slots */
#define OFF_WB3   (P_TOTAL + 16384)   /* 16384 bf16 = 8192 f32 slots  */
#define OFF_WC1   (P_TOTAL + 16384 + 8192)  /* 16896 bf16 = 8448 f32 slots */
#define P_END     (OFF_WC1 + 8448)

#define SZ_RL  589824
#define SZ_WB2 32768
#define SZ_WB3 16384
#define SZ_WC1 16896

// ---------- convert params; self-sniff dtype (flag=1 if f32 inputs) ----------
struct CvtArgs { const void* src[23]; int off[23]; const void* cw; const void* w2; const void* w3;
                 const void* x0; int total; };

__device__ __forceinline__ float getv(const void* p, long i, bool isf){
    return isf ? ((const float*)p)[i] : b2f(((const bf16*)p)[i]);
}

__global__ __launch_bounds__(256) void k_cvt(CvtArgs a, int* __restrict__ flag,
                                             float* __restrict__ P)
{
    // per-block self-sniff (identical rule to the old k_sniff)
    __shared__ int cnt;
    if (threadIdx.x == 0) cnt = 0;
    __syncthreads();
    {
        const bf16* xb = (const bf16*)a.x0;
        const float v = fabsf(b2f(xb[2*threadIdx.x]));
        if (v >= 1e-6f && v <= 1e6f) atomicAdd(&cnt, 1);
    }
    __syncthreads();
    const bool isf = (cnt < 192);
    if (blockIdx.x == 0 && threadIdx.x == 0) *flag = isf ? 1 : 0;

    const int i1 = a.total;            // region WR frags (bf16, in rl_cw slot)
    const int i2 = i1 + SZ_RL;         // WB2
    const int i3 = i2 + SZ_WB2;        // WB3
    const int i4 = i3 + SZ_WB3;        // WC1
    const int i5 = i4 + SZ_WC1;
    for (int idx = blockIdx.x*256 + threadIdx.x; idx < i5; idx += gridDim.x*256){
        if (idx < i1){
            if (idx >= OFF_RLCW && idx < OFF_RLCB) continue;   // slot reused for WR
            int k = 0;
            #pragma unroll
            for (int j = 1; j < 23; j++) if (idx >= a.off[j]) k = j;
            P[idx] = getv(a.src[k], idx - a.off[k], isf);
        } else if (idx < i2){
            // WR[net][tap][half][lane][j]: A-frag (weights, M=co16) for region
            const int d = idx - i1;
            const int net = d / 9216, dn = d % 9216;
            const int tap = dn >> 10, rem = dn & 1023;
            const int half = rem >> 9, lane = (rem >> 3) & 63, j = rem & 7;
            const int co = half*16 + (lane & 15);
            const int ci = ((lane >> 4) << 3) + j;
            const long sidx = (long)((net*32 + co)*32 + ci)*9 + tap;
            ((unsigned short*)(P + OFF_RLCW))[d] = (unsigned short)f2bf_u(getv(a.cw, sidx, isf));
        } else if (idx < i3){
            // WB2[tap][lane][j]: B-frag layout for conv2 (K=32ci)
            const int d = idx - i2;
            const int j = d & 7, lane = (d >> 3) & 63, tap = d >> 9;
            const int n = lane & 15, k = ((lane >> 4) << 3) + j;
            const int ci = k, ky = tap >> 3, kx = tap & 7;
            const long sidx = (long)((n*32 + ci)*8 + ky)*8 + kx;
            ((unsigned short*)(P + OFF_WB2))[d] = (unsigned short)f2bf_u(getv(a.w2, sidx, isf));
        } else if (idx < i4){
            // WB3[pair][lane][j]: B-frag layout for conv3 (K=16ci x 2 taps)
            const int d = idx - i3;
            const int j = d & 7, lane = (d >> 3) & 63, pair = d >> 9;
            const int n = lane & 15, k = ((lane >> 4) << 3) + j;
            const int tsel = k >> 4, ci = k & 15;
            const int ky = pair >> 2, kx = ((pair & 3) << 1) + tsel;
            const long sidx = (long)((n*16 + ci)*8 + ky)*8 + kx;
            ((unsigned short*)(P + OFF_WB3))[d] = (unsigned short)f2bf_u(getv(a.w3, sidx, isf));
        } else {
            // WC1[ky][ch][lane][j]: A-frag (weights, M=co32) for conv1, K=16 = 4kx x 4ci
            const int d = idx - i4;
            const int ky = d / 1536, rem = d % 1536;
            const int ch = rem >> 9, rem2 = rem & 511;
            const int lane = rem2 >> 3, j = rem2 & 7;
            const int co = lane & 31, h5 = lane >> 5;
            const int kx = ch*4 + h5*2 + (j >> 2), ci = j & 3;
            float v = 0.f;
            if (ci < 3 && kx < 11)
                v = getv(a.src[0], (long)((co*3 + ci)*11 + ky)*11 + kx, isf);
            ((unsigned short*)(P + OFF_WC1))[d] = (unsigned short)f2bf_u(v);
        }
    }
}

// ---------------- conv1 via 32x32x16 MFMA: x[32,3,170,170] -> bf16 NHWC [32,160,160,32] ----------------
__global__ __launch_bounds__(256,3) void k_conv1M(const void* __restrict__ x,
        const int* __restrict__ flag, const float* __restrict__ P, unsigned short* __restrict__ out)
{
    __shared__ unsigned short xs[18*44*4];     // [row18][col44][ci4] bf16, 6336 B
    __shared__ unsigned short wsm[SZ_WC1];     // 33792 B
    const int t = threadIdx.x;
    const int y0 = blockIdx.x*8, x0 = blockIdx.y*32, b = blockIdx.z;
    { const uint4* src = (const uint4*)(P + OFF_WC1);
      uint4* dst = (uint4*)wsm;
      for (int e=t; e<2112; e+=256) dst[e] = src[e]; }
    const bool isf = (*flag) != 0;
    for (int e=t; e<792; e+=256){
        const int r = e/44, c = e%44;
        const long base = ((long)(b*3)*170 + (y0+r))*170 + min(x0+c, 169);
        float v0, v1, v2;
        if (isf){
            const float* xf = (const float*)x;
            v0 = xf[base]; v1 = xf[base+28900]; v2 = xf[base+57800];
        } else {
            const bf16* xf = (const bf16*)x;
            v0 = b2f(xf[base]); v1 = b2f(xf[base+28900]); v2 = b2f(xf[base+57800]);
        }
        uint2 u;
        u.x = f2bf_u(v0) | (f2bf_u(v1) << 16);
        u.y = f2bf_u(v2);
        *(uint2*)&xs[(r*44+c)*4] = u;
    }
    __syncthreads();
    const int wave = t>>6, lane = t&63;
    const int n = lane & 31, h5 = lane >> 5;
    const int r0 = wave*2;
    f32x16 acc0 = {0.f}, acc1 = {0.f};
    #pragma unroll
    for (int e=0;e<16;e++){ acc0[e]=0.f; acc1[e]=0.f; }
    #pragma unroll 1
    for (int ky=0; ky<11; ky++){
        #pragma unroll
        for (int ch=0; ch<3; ch++){
            const short8 aw = *(const short8*)&wsm[((ky*3+ch)*64 + lane)*8];
            const int kx0 = ch*4 + h5*2;
            const int a0 = ((r0+ky)*44 + n + kx0)*4;
            const int a1 = ((r0+1+ky)*44 + n + kx0)*4;
            union { uint2 u2[2]; short8 s; } ub0, ub1;
            ub0.u2[0] = *(const uint2*)&xs[a0];
            ub0.u2[1] = *(const uint2*)&xs[a0+4];
            ub1.u2[0] = *(const uint2*)&xs[a1];
            ub1.u2[1] = *(const uint2*)&xs[a1+4];
            acc0 = __builtin_amdgcn_mfma_f32_32x32x16_bf16(aw, ub0.s, acc0, 0,0,0);
            acc1 = __builtin_amdgcn_mfma_f32_32x32x16_bf16(aw, ub1.s, acc1, 0,0,0);
        }
    }
    // D: col = lane&31 = pixel-col, row(co) = (reg&3) + 8*(reg>>2) + 4*h5
    unsigned short* opb = out + ((long)b*25600 + (long)(y0+r0)*160 + x0 + n)*32;
    #pragma unroll
    for (int g=0; g<4; g++){
        const int co0 = 8*g + 4*h5;
        const f32x4 bv = *(const f32x4*)&P[OFF_C1B + co0];
        float s0[4], s1[4];
        #pragma unroll
        for (int r=0;r<4;r++){ s0[r] = acc0[4*g+r] + bv[r]; s1[r] = acc1[4*g+r] + bv[r]; }
        *(uint2*)(opb + co0) = pack4(s0);
        *(uint2*)(opb + 160*32 + co0) = pack4(s1);
    }
}

// ------- region layer via 16x16x32 MFMA; bf16 NHWC in, bf16 NHWC pooled out -------
__global__ __launch_bounds__(256,2) void k_regionM(const unsigned short* __restrict__ in,
        const float* __restrict__ P, unsigned short* __restrict__ pooled)
{
    __shared__ unsigned short s_in[484*32];    // [pix 22x22][ci32] bf16, 30976 B
    __shared__ unsigned short wsm[9216];       // [tap9][half2][lane64][j8], 18432 B
    __shared__ float sc[32], sh[32];
    const int t = threadIdx.x;
    const int b = blockIdx.x & 31, kk = blockIdx.x >> 5;
    const int gi = kk >> 3, gj = kk & 7;
    const int net = gj*(gi+1);                 // idx = ii*jj + jj
    const long pbase = ((long)b*25600 + (long)(gi*20)*160 + gj*20)*32;
    if (t < 32){
        const float inv = rsqrtf(P[OFF_RLV+net*32+t]+1e-5f)*P[OFF_RLG+net*32+t];
        sc[t] = inv; sh[t] = P[OFF_RLB+net*32+t] - P[OFF_RLM+net*32+t]*inv;
    }
    { const uint4* src = (const uint4*)((const unsigned short*)(P+OFF_RLCW) + (size_t)net*9216);
      uint4* dst = (uint4*)wsm;
      for (int e=t; e<1152; e+=256) dst[e] = src[e]; }
    __syncthreads();
    for (int e=t; e<1936; e+=256){
        const int o = e & 3, p = e >> 2;
        const int pr = p/22, pc = p%22;
        short8 pk = {0,0,0,0,0,0,0,0};
        if (pr>0 && pr<21 && pc>0 && pc<21){
            const long a = pbase + ((long)(pr-1)*160 + (pc-1))*32 + o*8;
            const uint4 u = *(const uint4*)&in[a];
            float v[8];
            unp8(u, v);
            #pragma unroll
            for (int j=0;j<8;j++){
                const int ci = o*8 + j;
                v[j] = fmaxf(fmaf(v[j], sc[ci], sh[ci]), 0.f);
            }
            pk = pack8(v);
        }
        *(short8*)&s_in[p*32 + o*8] = pk;
    }
    __syncthreads();
    const int wave = t>>6, lane = t&63;
    const int q = lane>>4, n = lane&15;
    const int dr = n>>2, dc = n&3;
    const int nt = (wave==0) ? 7 : 6;          // 25 tiles over 4 waves
    int trs[7], tcs[7];
    #pragma unroll
    for (int i=0;i<7;i++){ const int tt = 4*i + wave; trs[i] = tt/5; tcs[i] = tt - 5*(tt/5); }
    f32x4 acc[7][2];
    {   float bias_v[2][4];
        #pragma unroll
        for (int h=0;h<2;h++)
            #pragma unroll
            for (int r=0;r<4;r++) bias_v[h][r] = P[OFF_RLCB + net*32 + h*16 + q*4 + r];
        #pragma unroll
        for (int i=0;i<7;i++)
            #pragma unroll
            for (int h=0;h<2;h++)
                acc[i][h] = (f32x4){bias_v[h][0], bias_v[h][1], bias_v[h][2], bias_v[h][3]};
    }
    #pragma unroll 1
    for (int tap=0; tap<9; tap++){
        const short8 a0 = *(const short8*)&wsm[(tap*2+0)*512 + lane*8];
        const short8 a1 = *(const short8*)&wsm[(tap*2+1)*512 + lane*8];
        const int ky = tap/3, kx = tap - 3*(tap/3);
        #pragma unroll
        for (int i=0;i<7;i++){
            if (i < nt){
                const int srow = trs[i]*4 + dr + ky, scol = tcs[i]*4 + dc + kx;
                const short8 bx = *(const short8*)&s_in[(srow*22 + scol)*32 + q*8];
                acc[i][0] = __builtin_amdgcn_mfma_f32_16x16x32_bf16(a0, bx, acc[i][0], 0,0,0);
                acc[i][1] = __builtin_amdgcn_mfma_f32_16x16x32_bf16(a1, bx, acc[i][1], 0,0,0);
            }
        }
    }
    float bnsc[2][4], bnsh[2][4];
    #pragma unroll
    for (int h=0;h<2;h++)
        #pragma unroll
        for (int r=0;r<4;r++){
            const int co = h*16 + q*4 + r;
            const float inv = rsqrtf(P[OFF_BNV+co]+1e-5f)*P[OFF_BNG+co];
            bnsc[h][r] = inv; bnsh[h][r] = P[OFF_BNB+co] - P[OFF_BNM+co]*inv;
        }
    const bool wr = ((n & 5) == 0);            // dc even && dr even
    #pragma unroll
    for (int i=0;i<7;i++){
        if (i < nt){
            const int prow = trs[i]*4 + dr, pcol = tcs[i]*4 + dc;
            const long ra = pbase + ((long)prow*160 + pcol)*32;
            const long pa0 = ((long)b*6400 + (long)(gi*10 + trs[i]*2 + (dr>>1))*80
                              + gj*10 + tcs[i]*2 + (dc>>1))*32;
            #pragma unroll
            for (int h=0;h<2;h++){
                const uint2 ru = *(const uint2*)&in[ra + h*16 + q*4];
                float res[4];
                unp4(ru, res);
                float pv[4];
                #pragma unroll
                for (int r=0;r<4;r++){
                    float v = acc[i][h][r] + res[r];
                    v = fmaxf(v, 0.f);
                    v = fmaxf(v, __shfl_xor(v, 1, 64));
                    v = fmaxf(v, __shfl_xor(v, 4, 64));
                    pv[r] = fmaf(v, bnsc[h][r], bnsh[h][r]);
                }
                if (wr) *(uint2*)&pooled[pa0 + h*16 + q*4] = pack4(pv);
            }
        }
    }
}

// ------- conv2/conv3 via MFMA shift-GEMM; bf16 NHWC input (pure memcpy stage) -------
template<int CIN, int HIN, int WIN, int HOUT, int WOUT, bool NHWC_OUT>
__global__ __launch_bounds__(256) void k_convM(const unsigned short* __restrict__ in,
        const unsigned short* __restrict__ WB, const float* __restrict__ bias,
        void* __restrict__ outv)
{
    constexpr int PP = 23;
    constexpr bool C32 = (CIN == 32);
    __shared__ unsigned short xs[PP*PP*CIN];
    __shared__ unsigned short ws[C32 ? 16*64*8 : 32*64*8];
    const int t = threadIdx.x;
    const int col0 = blockIdx.x*16, row0 = blockIdx.y*16, b = blockIdx.z;
    for (int e = t; e < PP*PP*(CIN/8); e += 256){
        const int o = e % (CIN/8), pix = e / (CIN/8);
        int rr = row0 + pix/PP; if (rr > HIN-1) rr = HIN-1;
        int cc = col0 + pix%PP; if (cc > WIN-1) cc = WIN-1;
        const uint4 v = *(const uint4*)&in[((long)b*HIN*WIN + (long)rr*WIN + cc)*CIN + o*8];
        *(uint4*)&xs[pix*CIN + o*8] = v;
    }
    const int wave = t>>6, lane = t&63;
    const int quad = lane>>4, n16 = lane&15;
    const float bv = bias[n16];
    f32x4 acc[4];
    #pragma unroll
    for (int mt=0;mt<4;mt++) acc[mt] = (f32x4){bv,bv,bv,bv};
    if constexpr (C32){
        for (int ch=0; ch<4; ch++){
            __syncthreads();
            const unsigned* src = (const unsigned*)WB + ch*4096;
            for (int e=t; e<4096; e+=256) ((unsigned*)ws)[e] = src[e];
            __syncthreads();
            #pragma unroll 1
            for (int tap=0; tap<16; tap++){
                const int tg = ch*16+tap, ky = tg>>3, kx = tg&7;
                const short8 bw = *(const short8*)&ws[(tap*64+lane)*8];
                #pragma unroll
                for (int mt=0; mt<4; mt++){
                    const int pr = wave*4+mt+ky, pc = n16+kx;
                    const short8 av = *(const short8*)&xs[(pr*PP+pc)*32 + quad*8];
                    acc[mt] = __builtin_amdgcn_mfma_f32_16x16x32_bf16(av, bw, acc[mt], 0,0,0);
                }
            }
        }
    } else {
        for (int e=t; e<8192; e+=256) ((unsigned*)ws)[e] = ((const unsigned*)WB)[e];
        __syncthreads();
        #pragma unroll 1
        for (int pair=0; pair<32; pair++){
            const int ky = pair>>2, kx0 = (pair&3)*2;
            const short8 bw = *(const short8*)&ws[(pair*64+lane)*8];
            #pragma unroll
            for (int mt=0; mt<4; mt++){
                const int pr = wave*4+mt+ky, pc = n16 + kx0 + (quad>>1);
                const short8 av = *(const short8*)&xs[(pr*PP+pc)*16 + (quad&1)*8];
                acc[mt] = __builtin_amdgcn_mfma_f32_16x16x32_bf16(av, bw, acc[mt], 0,0,0);
            }
        }
    }
    #pragma unroll
    for (int mt=0; mt<4; mt++){
        const int orow = row0 + wave*4 + mt;
        if (orow >= HOUT) continue;
        const int ocol = col0 + quad*4;
        #pragma unroll
        for (int r=0;r<4;r++){
            if (ocol + r < WOUT){
                const float v = fmaxf(acc[mt][r], 0.f);
                if constexpr (NHWC_OUT)
                    ((unsigned short*)outv)[((long)b*HOUT*WOUT + (long)orow*WOUT + ocol + r)*16 + n16]
                        = (unsigned short)f2bf_u(v);
                else
                    ((float*)outv)[((long)(b*16 + n16)*HOUT + orow)*WOUT + ocol + r] = v;
            }
        }
    }
}

// ---------------- conv4 direct (+relu), 4 outputs/thread ----------------
template<int CIN, int COUT, int KS, int STRIDE, int HIN, int WIN, int HOUT, int WOUT,
         int NG, int OW>
__global__ __launch_bounds__(256,2) void k_convN(const float* __restrict__ in,
        const float* __restrict__ w, const float* __restrict__ bias, float* __restrict__ out)
{
    __shared__ float wl[CIN*KS*KS];
    const int co = blockIdx.y, b = blockIdx.z;
    for (int j=threadIdx.x; j<CIN*KS*KS; j+=blockDim.x) wl[j] = w[co*CIN*KS*KS + j];
    __syncthreads();
    const int i = blockIdx.x*blockDim.x + threadIdx.x;
    if (i >= HOUT*NG) return;
    const int y = i / NG, x0 = (i % NG) * OW;
    float acc[OW];
    const float bv = bias[co];
    #pragma unroll
    for (int j=0;j<OW;j++) acc[j]=bv;
    constexpr int SPAN = STRIDE*(OW-1) + KS;
    for (int ci=0; ci<CIN; ci++){
        #pragma unroll
        for (int ky=0; ky<KS; ky++){
            const float* ip = in + ((long)(b*CIN+ci)*HIN + (STRIDE*y+ky))*WIN + STRIDE*x0;
            float v[SPAN];
            #pragma unroll
            for (int j=0;j<SPAN;j++) v[j]=ip[j];
            const float* wr = &wl[(ci*KS+ky)*KS];
            #pragma unroll
            for (int kx=0;kx<KS;kx++){
                const float wv = wr[kx];
                #pragma unroll
                for (int j=0;j<OW;j++) acc[j] = fmaf(v[STRIDE*j+kx], wv, acc[j]);
            }
        }
    }
    float* op = out + ((long)(b*COUT+co)*HOUT + y)*WOUT + x0;
    #pragma unroll
    for (int j=0;j<OW;j++)
        if (x0 + j < WOUT) op[j] = fmaxf(acc[j], 0.f);
}

// ---------------- conv5 fused: direct conv -> bf16 Xp rows; + fc1 y-bias-init + Xp pad-zero ----------------
// grid dim3(1,16,32): blockIdx.y=co, blockIdx.z=b; 512 blocks x 256 threads = 131072 = 32*4096
__global__ __launch_bounds__(256,2) void k_conv5F(const float* __restrict__ in,
        const float* __restrict__ P, unsigned short* __restrict__ xp, float* __restrict__ y)
{
    __shared__ float wl[16*25];
    const int co = blockIdx.y, b = blockIdx.z;
    const int t = threadIdx.x;
    for (int j=t; j<400; j+=256) wl[j] = P[OFF_C5W + co*400 + j];
    // fused fc1 y = bias (exactly 1 element per thread across the grid)
    {   const int lin = (b*16 + co)*256 + t;
        y[lin] = P[OFF_F1B + (lin & 4095)];
    }
    // fused Xp K-pad zero [11664,12288) per batch row
    if (co == 0 && t < 208){
        unsigned short* pp = xp + (long)b*12288 + 11664 + t*3;
        pp[0] = 0; pp[1] = 0; pp[2] = 0;
    }
    __syncthreads();
    if (t >= 27*7) return;
    const int yy = t / 7, x0 = (t % 7) * 4;
    float acc[4];
    const float bv = P[OFF_C5B + co];
    #pragma unroll
    for (int j=0;j<4;j++) acc[j]=bv;
    for (int ci=0; ci<16; ci++){
        #pragma unroll
        for (int ky=0; ky<5; ky++){
            const float* ip = in + ((long)(b*16+ci)*31 + (yy+ky))*31 + x0;
            float v[8];
            #pragma unroll
            for (int j=0;j<8;j++) v[j]=ip[j];
            const float* wr = &wl[(ci*5+ky)*5];
            #pragma unroll
            for (int kx=0;kx<5;kx++){
                const float wv = wr[kx];
                #pragma unroll
                for (int j=0;j<4;j++) acc[j] = fmaf(v[j+kx], wv, acc[j]);
            }
        }
    }
    unsigned short* op = xp + (long)b*12288 + (co*27 + yy)*27 + x0;
    #pragma unroll
    for (int j=0;j<4;j++)
        if (x0 + j < 27) op[j] = (unsigned short)f2bf_u(fmaxf(acc[j], 0.f));
}

// ---------------- combined pack(relu)+bias-init for fc2/fc3 ----------------
// i < ny: y[i] = bias[i % N];  else: xpack item (rows x K, relu, Ksrc==Kdst)
__global__ __launch_bounds__(256) void k_pk(const float* __restrict__ in,
        unsigned short* __restrict__ out, float* __restrict__ y,
        const float* __restrict__ bias, int N, int ny, int rows, int K)
{
    const int i = blockIdx.x*256 + threadIdx.x;
    if (i < ny){ y[i] = bias[i % N]; return; }
    const int d = i - ny;
    const int per = K >> 3;
    if (d >= rows*per) return;
    const int row = d / per, k = (d - row*per)*8;
    float v[8];
    *(f32x4*)&v[0] = *(const f32x4*)&in[(long)row*K + k];
    *(f32x4*)&v[4] = *(const f32x4*)&in[(long)row*K + k + 4];
    #pragma unroll
    for (int j=0;j<8;j++) v[j] = fmaxf(v[j], 0.f);
    *(short8*)&out[(long)row*K + k] = pack8(v);
}

// ---------------- fc1/fc2: LDS-staged GEMM via global_load_lds ----------------
template<typename WT>
__device__ __forceinline__ void fcl_body(const unsigned short* __restrict__ x,
        const WT* __restrict__ w, float* __restrict__ y,
        int Kw, int Khat, int N, int Kc, int Nvalid, unsigned char* lbuf)
{
    constexpr bool WF = __is_same(WT, float);
    const int t = threadIdx.x;
    const int wave = t>>6, lane = t&63;
    const int quad = lane>>4, n16 = lane&15;
    const int og = wave>>1, bh = wave&1;
    const int bx = blockIdx.x;
    const int start = blockIdx.y*Kc;
    int steps = 0;
    {   const int rem = Kw - start;
        const int sa = Kc >> 7;
        if (rem > 0){ steps = (rem + 127) >> 7; if (steps > sa) steps = sa; }
    }
    f32x4 acc = {0.f,0.f,0.f,0.f};
    const unsigned short* xp = x + (long)(bh*16 + n16)*Khat;
    const int row = og*16 + n16;

    auto stage = [&](int s, int bsel){
        const int k0 = start + (s<<7);
        const bool swz = (k0 + 128 <= Kw);
        unsigned char* base = lbuf + bsel*16384;
        if constexpr (WF){
            const int r0 = wave*8;
            #pragma unroll
            for (int c=0;c<4;c++){
                const int rr = r0 + 2*c + (lane>>5);
                const int cs = swz ? ((lane&31) ^ (rr&7)) : (lane&31);
                long koff = (long)k0 + cs*4;
                const float* ga = w + (long)(bx*32 + rr)*Kw + koff;
                if (!swz && (koff + 4 > Kw)) ga = w + (long)(bx*32 + rr)*Kw;  // x=0 there
                GLD_LDS16(ga, base + (r0 + 2*c)*512);
            }
        } else {
            const int r0 = wave*8;
            #pragma unroll
            for (int c=0;c<2;c++){
                const int rr = r0 + 4*c + (lane>>4);
                const int cs = swz ? ((lane&15) ^ (rr&7)) : (lane&15);
                long koff = (long)k0 + cs*8;
                const WT* ga = w + (long)(bx*32 + rr)*Kw + koff;
                if (!swz && (koff + 8 > Kw)) ga = w + (long)(bx*32 + rr)*Kw;
                GLD_LDS16(ga, base + (r0 + 4*c)*256);
            }
        }
    };
    auto consume = [&](int s, int bsel){
        const int k0 = start + (s<<7);
        const bool swz = (k0 + 128 <= Kw);
        const unsigned char* base = lbuf + bsel*16384;
        #pragma unroll
        for (int kk=0; kk<4; kk++){
            const int ka = k0 + kk*32 + quad*8;
            const short8 x8 = *(const short8*)&xp[ka];
            short8 bw;
            if constexpr (WF){
                const int c0 = kk*8 + quad*2;
                const int p0 = swz ? (c0 ^ (row&7)) : c0;
                const int p1 = swz ? ((c0+1) ^ (row&7)) : (c0+1);
                float wv[8];
                *(f32x4*)&wv[0] = *(const f32x4*)&base[row*512 + p0*16];
                *(f32x4*)&wv[4] = *(const f32x4*)&base[row*512 + p1*16];
                bw = pack8(wv);
            } else {
                const int c0 = kk*4 + quad;
                const int p0 = swz ? (c0 ^ (row&7)) : c0;
                bw = *(const short8*)&base[row*256 + p0*16];
            }
            acc = __builtin_amdgcn_mfma_f32_16x16x32_bf16(x8, bw, acc, 0,0,0);
        }
    };

    if (steps > 0){
        stage(0, 0);
        __syncthreads();
        for (int s=0; s<steps; s++){
            if (s+1 < steps) stage(s+1, (s+1)&1);
            consume(s, s&1);
            __syncthreads();
        }
    }
    const int o = bx*32 + og*16 + n16;
    if (o < Nvalid){
        #pragma unroll
        for (int r=0;r<4;r++)
            atomicAdd(&y[(long)(bh*16 + quad*4 + r)*N + o], acc[r]);
    }
}

__global__ __launch_bounds__(256,4) void k_fcL(const unsigned short* __restrict__ x,
        const void* __restrict__ w, const int* __restrict__ flag,
        float* __restrict__ y, int Kw, int Khat, int N, int Kc, int Nvalid)
{
    __shared__ unsigned char lbuf[2*16384];
    if (*flag) fcl_body<float>(x, (const float*)w, y, Kw, Khat, N, Kc, Nvalid, lbuf);
    else       fcl_body<bf16 >(x, (const bf16 *)w, y, Kw, Khat, N, Kc, Nvalid, lbuf);
}

// ---------------- fc3 (tiny): register-pipelined MFMA ----------------
template<typename WT>
__device__ __forceinline__ void fcm_loop(const unsigned short* __restrict__ xp,
        const WT* __restrict__ wp, int start, int end, int quad, f32x4& acc)
{
    const int nfull = (end - start) >> 5;
    const int end32 = start + (nfull << 5);
    const int qo = quad*8;

    short8 xA, xB, xC;
    short8 bwA, bwB, bwC;
    f32x4 wA0, wA1, wB0, wB1, wC0, wC1;

    auto loadA = [&](int k0){
        const int ka = k0 + qo;
        xA = *(const short8*)&xp[ka];
        if constexpr (__is_same(WT, bf16)) bwA = *(const short8*)&wp[ka];
        else { wA0 = *(const f32x4*)&wp[ka]; wA1 = *(const f32x4*)&wp[ka+4]; }
    };
    auto loadB = [&](int k0){
        const int ka = k0 + qo;
        xB = *(const short8*)&xp[ka];
        if constexpr (__is_same(WT, bf16)) bwB = *(const short8*)&wp[ka];
        else { wB0 = *(const f32x4*)&wp[ka]; wB1 = *(const f32x4*)&wp[ka+4]; }
    };
    auto loadC = [&](int k0){
        const int ka = k0 + qo;
        xC = *(const short8*)&xp[ka];
        if constexpr (__is_same(WT, bf16)) bwC = *(const short8*)&wp[ka];
        else { wC0 = *(const f32x4*)&wp[ka]; wC1 = *(const f32x4*)&wp[ka+4]; }
    };
    auto compA = [&](){
        short8 bw;
        if constexpr (__is_same(WT, bf16)) bw = bwA;
        else { float wv[8]; *(f32x4*)&wv[0]=wA0; *(f32x4*)&wv[4]=wA1; bw = pack8(wv); }
        acc = __builtin_amdgcn_mfma_f32_16x16x32_bf16(xA, bw, acc, 0,0,0);
    };
    auto compB = [&](){
        short8 bw;
        if constexpr (__is_same(WT, bf16)) bw = bwB;
        else { float wv[8]; *(f32x4*)&wv[0]=wB0; *(f32x4*)&wv[4]=wB1; bw = pack8(wv); }
        acc = __builtin_amdgcn_mfma_f32_16x16x32_bf16(xB, bw, acc, 0,0,0);
    };
    auto compC = [&](){
        short8 bw;
        if constexpr (__is_same(WT, bf16)) bw = bwC;
        else { float wv[8]; *(f32x4*)&wv[0]=wC0; *(f32x4*)&wv[4]=wC1; bw = pack8(wv); }
        acc = __builtin_amdgcn_mfma_f32_16x16x32_bf16(xC, bw, acc, 0,0,0);
    };

    if (nfull >= 3){
        loadA(start); loadB(start+32); loadC(start+64);
        int j = 0;
        for (; j + 6 <= nfull; j += 3){
            compA(); loadA(start + ((j+3)<<5));
            compB(); loadB(start + ((j+4)<<5));
            compC(); loadC(start + ((j+5)<<5));
        }
        const int rem = nfull - j;
        if (rem == 3){ compA(); compB(); compC(); }
        else if (rem == 4){
            compA(); loadA(start + ((j+3)<<5));
            compB(); compC(); compA();
        } else {
            compA(); loadA(start + ((j+3)<<5));
            compB(); loadB(start + ((j+4)<<5));
            compC(); compA(); compB();
        }
    } else if (nfull == 2){
        loadA(start); loadB(start+32); compA(); compB();
    } else if (nfull == 1){
        loadA(start); compA();
    }
    if (end32 < end){
        const int ka = end32 + qo;
        float xv[8], wv[8];
        #pragma unroll
        for (int j=0;j<8;j++){
            const bool v = (ka + j) < end;
            xv[j] = v ? b2f(((const bf16*)xp)[ka+j]) : 0.f;
            wv[j] = v ? (float)ld(wp, ka+j) : 0.f;
        }
        acc = __builtin_amdgcn_mfma_f32_16x16x32_bf16(pack8(xv), pack8(wv), acc, 0,0,0);
    }
}

__global__ __launch_bounds__(256,4) void k_fcM(const unsigned short* __restrict__ x,
        const void* __restrict__ w, const int* __restrict__ flag,
        float* __restrict__ y, int K, int N, int Kc, int Nvalid)
{
    const int t = threadIdx.x;
    const int wave = t>>6, lane = t&63;
    const int quad = lane>>4, n16 = lane&15;
    const int og = wave>>1, bh = wave&1;
    const int o = blockIdx.x*32 + og*16 + n16;
    const int orow = (o < Nvalid) ? o : (Nvalid-1);
    const int xrow = bh*16 + n16;
    const int start = blockIdx.y*Kc;
    const int end = min(K, start + Kc);
    f32x4 acc = {0.f,0.f,0.f,0.f};
    const unsigned short* xp = x + (long)xrow*K;
    if (*flag) fcm_loop<float>(xp, (const float*)w + (long)orow*K, start, end, quad, acc);
    else       fcm_loop<bf16 >(xp, (const bf16 *)w + (long)orow*K, start, end, quad, acc);
    if (o < Nvalid){
        #pragma unroll
        for (int r=0;r<4;r++)
            atomicAdd(&y[(long)(bh*16 + quad*4 + r)*N + o], acc[r]);
    }
}

// ---------------- paired log_softmax over axis 1 of [32,2,12] ----------------
__global__ void k_lsm(const float* __restrict__ in, const int* __restrict__ flag,
                      void* __restrict__ out)
{
    const int i = threadIdx.x;
    if (i >= 384) return;
    const int b = i/12, au = i%12;
    const float a0 = in[b*24+au], a1 = in[b*24+12+au];
    const float m = fmaxf(a0,a1);
    const float lse = m + logf(expf(a0-m)+expf(a1-m));
    const float o0 = a0-lse, o1 = a1-lse;
    if (*flag){
        ((float*)out)[b*24+au]    = o0;
        ((float*)out)[b*24+12+au] = o1;
    } else {
        ((bf16*)out)[b*24+au]    = __float2bfloat16(o0);
        ((bf16*)out)[b*24+12+au] = __float2bfloat16(o1);
    }
}

extern "C" void kernel_launch(void* const* d_in, const int* in_sizes, int n_in,
                              void* d_out, int out_size, void* d_ws, size_t ws_size,
                              hipStream_t stream) {
    (void)in_sizes; (void)n_in; (void)out_size; (void)ws_size;
    const void* x = d_in[0];

    float* A = (float*)d_ws;               // 26,214,400 floats
    float* B = A + 26214400;               //  6,553,600 floats
    float* P = B + 6553600;                //  P_END floats
    int* flag = (int*)(P + P_END);
    unsigned short* Xp = (unsigned short*)(P + P_END + 16);  // 393,216 bf16
    unsigned short* Abf = (unsigned short*)A;
    unsigned short* Bbf = (unsigned short*)B;
    float* Bhi = B + 5000000;              // conv4 out [32,16,31,31] = 492,032 floats

    CvtArgs a;
    const int src_idx[23] = {1,2,3,4,5,6,7,8,9,10,11,12,13,14,15,16,17,18,19,20,22,24,26};
    const int offs[23] = {OFF_C1W,OFF_C1B,OFF_RLG,OFF_RLB,OFF_RLM,OFF_RLV,OFF_RLCW,OFF_RLCB,
                          OFF_BNG,OFF_BNB,OFF_BNM,OFF_BNV,OFF_C2W,OFF_C2B,OFF_C3W,OFF_C3B,
                          OFF_C4W,OFF_C4B,OFF_C5W,OFF_C5B,OFF_F1B,OFF_F2B,OFF_F3B};
    for (int j=0;j<23;j++){ a.src[j] = d_in[src_idx[j]]; a.off[j] = offs[j]; }
    a.cw = d_in[7]; a.w2 = d_in[13]; a.w3 = d_in[15];
    a.x0 = x;
    a.total = P_TOTAL;

    // 1: params convert (self-sniffs dtype; block 0 publishes flag)
    k_cvt<<<(P_TOTAL+SZ_RL+SZ_WB2+SZ_WB3+SZ_WC1+255)/256,256,0,stream>>>(a, flag, P);
    // 2: conv1 -> Abf bf16 NHWC [32,160,160,32]
    k_conv1M<<<dim3(20,5,32),256,0,stream>>>(x, flag, P, Abf);
    // 3: region -> Bbf bf16 NHWC pooled [32,80,80,32]
    k_regionM<<<2048,256,0,stream>>>(Abf, P, Bbf);
    // 4: conv2 -> Abf bf16 NHWC [32,73,73,16]
    k_convM<32,80,80,73,73,true><<<dim3(5,5,32),256,0,stream>>>(Bbf, (const unsigned short*)(P+OFF_WB2), P+OFF_C2B, (void*)Abf);
    // 5: conv3 -> B f32 NCHW [32,16,66,66]
    k_convM<16,73,73,66,66,false><<<dim3(5,5,32),256,0,stream>>>(Abf, (const unsigned short*)(P+OFF_WB3), P+OFF_C3B, (void*)B);
    // 6: conv4 stride 2 -> Bhi f32 NCHW [32,16,31,31]
    k_convN<16,16,6,2,66,66,31,31,8,4><<<dim3(1,16,32),256,0,stream>>>(B, P+OFF_C4W, P+OFF_C4B, Bhi);
    // 7: conv5 -> bf16 Xp rows [32][12288]; fused fc1 y=A bias-init + Xp pad-zero
    k_conv5F<<<dim3(1,16,32),256,0,stream>>>(Bhi, P, Xp, A);
    // 8: fc1 K=11664 (pad 12288) -> 4096, y=A; 8 K-splits, single-round co-resident
    k_fcL<<<dim3(128,8),256,0,stream>>>(Xp, d_in[21], flag, A, 11664, 12288, 4096, 1536, 4096);
    // 9: pack fc1-out (relu) + fc2 y=B bias-init
    k_pk<<<(65536+16384+255)/256,256,0,stream>>>(A, Xp, B, P+OFF_F2B, 2048, 65536, 32, 4096);
    // 10: fc2 K=4096 -> 2048, y=B; 8 K-splits
    k_fcL<<<dim3(64,8),256,0,stream>>>(Xp, d_in[23], flag, B, 4096, 4096, 2048, 512, 2048);
    // 11: pack fc2-out (relu) + fc3 y=A bias-init
    k_pk<<<(768+8192+255)/256,256,0,stream>>>(B, Xp, A, P+OFF_F3B, 24, 768, 32, 2048);
    // 12: fc3 K=2048 -> 24, y=A
    k_fcM<<<dim3(1,64),256,0,stream>>>(Xp, d_in[25], flag, A, 2048, 24, 32, 24);
    // 13: log_softmax
    k_lsm<<<1,384,0,stream>>>(A, flag, d_out);
}

// Round 8
// 557.435 us; speedup vs baseline: 1.3588x; 1.0221x over previous
//
#include <hip/hip_runtime.h>
#include <hip/hip_bf16.h>

typedef __hip_bfloat16 bf16;
typedef __attribute__((ext_vector_type(8))) short short8;
typedef __attribute__((ext_vector_type(4))) float f32x4;
typedef __attribute__((ext_vector_type(16))) float f32x16;

__device__ __forceinline__ float b2f(const bf16 v){ return __bfloat162float(v); }
__device__ __forceinline__ float ld(const float* p, long i){ return p[i]; }
__device__ __forceinline__ float ld(const bf16*  p, long i){ return b2f(p[i]); }

__device__ __forceinline__ unsigned f2bf_u(float f){
    union { float f; unsigned u; } a; a.f = f;
    unsigned r = a.u + 0x7FFFu + ((a.u >> 16) & 1u);
    return r >> 16;
}

__device__ __forceinline__ short8 pack8(const float* v){
    union { __hip_bfloat162 h[4]; short8 s; } r;
    #pragma unroll
    for (int i=0;i<4;i++)
        r.h[i] = __float22bfloat162_rn(float2{v[2*i], v[2*i+1]});
    return r.s;
}

__device__ __forceinline__ uint2 pack4(const float* v){
    union { __hip_bfloat162 h[2]; uint2 u; } r;
    r.h[0] = __float22bfloat162_rn(float2{v[0], v[1]});
    r.h[1] = __float22bfloat162_rn(float2{v[2], v[3]});
    return r.u;
}

__device__ __forceinline__ void unp8(uint4 u, float* v){
    union { unsigned x; float f; } a;
    a.x = u.x<<16; v[0]=a.f; a.x = u.x&0xffff0000u; v[1]=a.f;
    a.x = u.y<<16; v[2]=a.f; a.x = u.y&0xffff0000u; v[3]=a.f;
    a.x = u.z<<16; v[4]=a.f; a.x = u.z&0xffff0000u; v[5]=a.f;
    a.x = u.w<<16; v[6]=a.f; a.x = u.w&0xffff0000u; v[7]=a.f;
}

__device__ __forceinline__ void unp4(uint2 u, float* v){
    union { unsigned x; float f; } a;
    a.x = u.x<<16; v[0]=a.f; a.x = u.x&0xffff0000u; v[1]=a.f;
    a.x = u.y<<16; v[2]=a.f; a.x = u.y&0xffff0000u; v[3]=a.f;
}

#define GLD_LDS16(g, l) __builtin_amdgcn_global_load_lds( \
    (const __attribute__((address_space(1))) void*)(g), \
    (__attribute__((address_space(3))) void*)(l), 16, 0, 0)

// ---- converted-params block offsets (floats) within P ----
#define OFF_C1W   0        /* 11616 */
#define OFF_C1B   11616    /* 32   */
#define OFF_RLG   11648    /* 2048 */
#define OFF_RLB   13696
#define OFF_RLM   15744
#define OFF_RLV   17792
#define OFF_RLCW  19840    /* 589824 slots: bf16 WR [net][tap9][half2][lane64][j8] */
#define OFF_RLCB  609664   /* 2048 */
#define OFF_BNG   611712
#define OFF_BNB   611744
#define OFF_BNM   611776
#define OFF_BNV   611808
#define OFF_C2W   611840   /* 32768 */
#define OFF_C2B   644608
#define OFF_C3W   644624   /* 16384 */
#define OFF_C3B   661008
#define OFF_C4W   661024   /* 9216 */
#define OFF_C4B   670240
#define OFF_C5W   670256   /* 6400 */
#define OFF_C5B   676656
#define OFF_F1B   676672   /* 4096 */
#define OFF_F2B   680768   /* 2048 */
#define OFF_F3B   682816   /* 24   */
#define P_TOTAL   682840
#define OFF_WB2   P_TOTAL             /* 32768 bf16 = 16384 f32 slots */
#define OFF_WB3   (P_TOTAL + 16384)   /* 16384 bf16 = 8192 f32 slots  */
#define OFF_WC1   (P_TOTAL + 16384 + 8192)  /* 16896 bf16 = 8448 f32 slots */
#define P_END     (OFF_WC1 + 8448)

#define SZ_RL  589824
#define SZ_WB2 32768
#define SZ_WB3 16384
#define SZ_WC1 16896
#define SZ_HOLE (OFF_RLCB - OFF_RLCW)   /* 589824 */

// ---------- convert params; self-sniff dtype; compacted index space ----------
struct CvtArgs { const void* src[23]; int off[23]; const void* cw; const void* w2; const void* w3;
                 const void* x0; int total; };

__device__ __forceinline__ float getv(const void* p, long i, bool isf){
    return isf ? ((const float*)p)[i] : b2f(((const bf16*)p)[i]);
}

__global__ __launch_bounds__(256) void k_cvt(CvtArgs a, int* __restrict__ flag,
                                             float* __restrict__ P)
{
    // per-block self-sniff (identical rule to the old k_sniff)
    __shared__ int cnt;
    if (threadIdx.x == 0) cnt = 0;
    __syncthreads();
    {
        const bf16* xb = (const bf16*)a.x0;
        const float v = fabsf(b2f(xb[2*threadIdx.x]));
        if (v >= 1e-6f && v <= 1e6f) atomicAdd(&cnt, 1);
    }
    __syncthreads();
    const bool isf = (cnt < 192);
    if (blockIdx.x == 0 && threadIdx.x == 0) *flag = isf ? 1 : 0;

    // compacted space: params (hole removed), WR, WB2, WB3, WC1
    const int c1 = P_TOTAL - SZ_HOLE;   // 93016 param items
    const int c2 = c1 + SZ_RL;
    const int c3 = c2 + SZ_WB2;
    const int c4 = c3 + SZ_WB3;
    const int c5 = c4 + SZ_WC1;
    for (int c = blockIdx.x*256 + threadIdx.x; c < c5; c += gridDim.x*256){
        if (c < c1){
            const int idx = (c < OFF_RLCW) ? c : (c + SZ_HOLE);
            int k = 0;
            #pragma unroll
            for (int j = 1; j < 23; j++) if (idx >= a.off[j]) k = j;
            P[idx] = getv(a.src[k], idx - a.off[k], isf);
        } else if (c < c2){
            // WR[net][tap][half][lane][j]: A-frag (weights, M=co16) for region
            const int d = c - c1;
            const int net = d / 9216, dn = d % 9216;
            const int tap = dn >> 10, rem = dn & 1023;
            const int half = rem >> 9, lane = (rem >> 3) & 63, j = rem & 7;
            const int co = half*16 + (lane & 15);
            const int ci = ((lane >> 4) << 3) + j;
            const long sidx = (long)((net*32 + co)*32 + ci)*9 + tap;
            ((unsigned short*)(P + OFF_RLCW))[d] = (unsigned short)f2bf_u(getv(a.cw, sidx, isf));
        } else if (c < c3){
            // WB2[tap][lane][j]: B-frag layout for conv2 (K=32ci)
            const int d = c - c2;
            const int j = d & 7, lane = (d >> 3) & 63, tap = d >> 9;
            const int n = lane & 15, k = ((lane >> 4) << 3) + j;
            const int ci = k, ky = tap >> 3, kx = tap & 7;
            const long sidx = (long)((n*32 + ci)*8 + ky)*8 + kx;
            ((unsigned short*)(P + OFF_WB2))[d] = (unsigned short)f2bf_u(getv(a.w2, sidx, isf));
        } else if (c < c4){
            // WB3[pair][lane][j]: B-frag layout for conv3 (K=16ci x 2 taps)
            const int d = c - c3;
            const int j = d & 7, lane = (d >> 3) & 63, pair = d >> 9;
            const int n = lane & 15, k = ((lane >> 4) << 3) + j;
            const int tsel = k >> 4, ci = k & 15;
            const int ky = pair >> 2, kx = ((pair & 3) << 1) + tsel;
            const long sidx = (long)((n*16 + ci)*8 + ky)*8 + kx;
            ((unsigned short*)(P + OFF_WB3))[d] = (unsigned short)f2bf_u(getv(a.w3, sidx, isf));
        } else {
            // WC1[ky][ch][lane][j]: A-frag (weights, M=co32) for conv1, K=16 = 4kx x 4ci
            const int d = c - c4;
            const int ky = d / 1536, rem = d % 1536;
            const int ch = rem >> 9, rem2 = rem & 511;
            const int lane = rem2 >> 3, j = rem2 & 7;
            const int co = lane & 31, h5 = lane >> 5;
            const int kx = ch*4 + h5*2 + (j >> 2), ci = j & 3;
            float v = 0.f;
            if (ci < 3 && kx < 11)
                v = getv(a.src[0], (long)((co*3 + ci)*11 + ky)*11 + kx, isf);
            ((unsigned short*)(P + OFF_WC1))[d] = (unsigned short)f2bf_u(v);
        }
    }
}

// ---------------- conv1 via 32x32x16 MFMA: x[32,3,170,170] -> bf16 NHWC [32,160,160,32] ----------------
// 16 output rows per block; wave = 4 row-strips (4x A-frag reuse vs 2x before)
__global__ __launch_bounds__(256,2) void k_conv1M(const void* __restrict__ x,
        const int* __restrict__ flag, const float* __restrict__ P, unsigned short* __restrict__ out)
{
    __shared__ unsigned short xs[26*44*4];     // [row26][col44][ci4] bf16, 18304 B
    __shared__ unsigned short wsm[SZ_WC1];     // 33792 B
    const int t = threadIdx.x;
    const int y0 = blockIdx.x*16, x0 = blockIdx.y*32, b = blockIdx.z;
    { const uint4* src = (const uint4*)(P + OFF_WC1);
      uint4* dst = (uint4*)wsm;
      for (int e=t; e<2112; e+=256) dst[e] = src[e]; }
    const bool isf = (*flag) != 0;
    for (int e=t; e<1144; e+=256){
        const int r = e/44, c = e%44;
        const long base = ((long)(b*3)*170 + (y0+r))*170 + min(x0+c, 169);
        float v0, v1, v2;
        if (isf){
            const float* xf = (const float*)x;
            v0 = xf[base]; v1 = xf[base+28900]; v2 = xf[base+57800];
        } else {
            const bf16* xf = (const bf16*)x;
            v0 = b2f(xf[base]); v1 = b2f(xf[base+28900]); v2 = b2f(xf[base+57800]);
        }
        uint2 u;
        u.x = f2bf_u(v0) | (f2bf_u(v1) << 16);
        u.y = f2bf_u(v2);
        *(uint2*)&xs[(r*44+c)*4] = u;
    }
    __syncthreads();
    const int wave = t>>6, lane = t&63;
    const int n = lane & 31, h5 = lane >> 5;
    const int r0 = wave*4;
    f32x16 acc0 = {0.f}, acc1 = {0.f}, acc2 = {0.f}, acc3 = {0.f};
    #pragma unroll
    for (int e=0;e<16;e++){ acc0[e]=0.f; acc1[e]=0.f; acc2[e]=0.f; acc3[e]=0.f; }
    #pragma unroll 1
    for (int ky=0; ky<11; ky++){
        #pragma unroll
        for (int ch=0; ch<3; ch++){
            const short8 aw = *(const short8*)&wsm[((ky*3+ch)*64 + lane)*8];
            const int kx0 = ch*4 + h5*2;
            const int ab = ((r0+ky)*44 + n + kx0)*4;
            union { uint2 u2[2]; short8 s; } ub0, ub1, ub2, ub3;
            ub0.u2[0] = *(const uint2*)&xs[ab];
            ub0.u2[1] = *(const uint2*)&xs[ab+4];
            ub1.u2[0] = *(const uint2*)&xs[ab+176];
            ub1.u2[1] = *(const uint2*)&xs[ab+180];
            ub2.u2[0] = *(const uint2*)&xs[ab+352];
            ub2.u2[1] = *(const uint2*)&xs[ab+356];
            ub3.u2[0] = *(const uint2*)&xs[ab+528];
            ub3.u2[1] = *(const uint2*)&xs[ab+532];
            acc0 = __builtin_amdgcn_mfma_f32_32x32x16_bf16(aw, ub0.s, acc0, 0,0,0);
            acc1 = __builtin_amdgcn_mfma_f32_32x32x16_bf16(aw, ub1.s, acc1, 0,0,0);
            acc2 = __builtin_amdgcn_mfma_f32_32x32x16_bf16(aw, ub2.s, acc2, 0,0,0);
            acc3 = __builtin_amdgcn_mfma_f32_32x32x16_bf16(aw, ub3.s, acc3, 0,0,0);
        }
    }
    // D: col = lane&31 = pixel-col, row(co) = (reg&3) + 8*(reg>>2) + 4*h5
    #pragma unroll
    for (int s=0; s<4; s++){
        unsigned short* opb = out + ((long)b*25600 + (long)(y0+r0+s)*160 + x0 + n)*32;
        const f32x16* ap = (s==0) ? &acc0 : (s==1) ? &acc1 : (s==2) ? &acc2 : &acc3;
        #pragma unroll
        for (int g=0; g<4; g++){
            const int co0 = 8*g + 4*h5;
            const f32x4 bv = *(const f32x4*)&P[OFF_C1B + co0];
            float sv[4];
            #pragma unroll
            for (int r=0;r<4;r++) sv[r] = (*ap)[4*g+r] + bv[r];
            *(uint2*)(opb + co0) = pack4(sv);
        }
    }
}

// ------- region layer via 16x16x32 MFMA; bf16 NHWC in, bf16 NHWC pooled out -------
__global__ __launch_bounds__(256,2) void k_regionM(const unsigned short* __restrict__ in,
        const float* __restrict__ P, unsigned short* __restrict__ pooled)
{
    __shared__ unsigned short s_in[484*32];    // [pix 22x22][ci32] bf16, 30976 B
    __shared__ unsigned short wsm[9216];       // [tap9][half2][lane64][j8], 18432 B
    __shared__ float sc[32], sh[32];
    const int t = threadIdx.x;
    const int b = blockIdx.x & 31, kk = blockIdx.x >> 5;
    const int gi = kk >> 3, gj = kk & 7;
    const int net = gj*(gi+1);                 // idx = ii*jj + jj
    const long pbase = ((long)b*25600 + (long)(gi*20)*160 + gj*20)*32;
    if (t < 32){
        const float inv = rsqrtf(P[OFF_RLV+net*32+t]+1e-5f)*P[OFF_RLG+net*32+t];
        sc[t] = inv; sh[t] = P[OFF_RLB+net*32+t] - P[OFF_RLM+net*32+t]*inv;
    }
    { const uint4* src = (const uint4*)((const unsigned short*)(P+OFF_RLCW) + (size_t)net*9216);
      uint4* dst = (uint4*)wsm;
      for (int e=t; e<1152; e+=256) dst[e] = src[e]; }
    __syncthreads();
    for (int e=t; e<1936; e+=256){
        const int o = e & 3, p = e >> 2;
        const int pr = p/22, pc = p%22;
        short8 pk = {0,0,0,0,0,0,0,0};
        if (pr>0 && pr<21 && pc>0 && pc<21){
            const long a = pbase + ((long)(pr-1)*160 + (pc-1))*32 + o*8;
            const uint4 u = *(const uint4*)&in[a];
            float v[8];
            unp8(u, v);
            #pragma unroll
            for (int j=0;j<8;j++){
                const int ci = o*8 + j;
                v[j] = fmaxf(fmaf(v[j], sc[ci], sh[ci]), 0.f);
            }
            pk = pack8(v);
        }
        *(short8*)&s_in[p*32 + o*8] = pk;
    }
    __syncthreads();
    const int wave = t>>6, lane = t&63;
    const int q = lane>>4, n = lane&15;
    const int dr = n>>2, dc = n&3;
    const int nt = (wave==0) ? 7 : 6;          // 25 tiles over 4 waves
    int trs[7], tcs[7];
    #pragma unroll
    for (int i=0;i<7;i++){ const int tt = 4*i + wave; trs[i] = tt/5; tcs[i] = tt - 5*(tt/5); }
    f32x4 acc[7][2];
    {   float bias_v[2][4];
        #pragma unroll
        for (int h=0;h<2;h++)
            #pragma unroll
            for (int r=0;r<4;r++) bias_v[h][r] = P[OFF_RLCB + net*32 + h*16 + q*4 + r];
        #pragma unroll
        for (int i=0;i<7;i++)
            #pragma unroll
            for (int h=0;h<2;h++)
                acc[i][h] = (f32x4){bias_v[h][0], bias_v[h][1], bias_v[h][2], bias_v[h][3]};
    }
    #pragma unroll 1
    for (int tap=0; tap<9; tap++){
        const short8 a0 = *(const short8*)&wsm[(tap*2+0)*512 + lane*8];
        const short8 a1 = *(const short8*)&wsm[(tap*2+1)*512 + lane*8];
        const int ky = tap/3, kx = tap - 3*(tap/3);
        #pragma unroll
        for (int i=0;i<7;i++){
            if (i < nt){
                const int srow = trs[i]*4 + dr + ky, scol = tcs[i]*4 + dc + kx;
                const short8 bx = *(const short8*)&s_in[(srow*22 + scol)*32 + q*8];
                acc[i][0] = __builtin_amdgcn_mfma_f32_16x16x32_bf16(a0, bx, acc[i][0], 0,0,0);
                acc[i][1] = __builtin_amdgcn_mfma_f32_16x16x32_bf16(a1, bx, acc[i][1], 0,0,0);
            }
        }
    }
    float bnsc[2][4], bnsh[2][4];
    #pragma unroll
    for (int h=0;h<2;h++)
        #pragma unroll
        for (int r=0;r<4;r++){
            const int co = h*16 + q*4 + r;
            const float inv = rsqrtf(P[OFF_BNV+co]+1e-5f)*P[OFF_BNG+co];
            bnsc[h][r] = inv; bnsh[h][r] = P[OFF_BNB+co] - P[OFF_BNM+co]*inv;
        }
    const bool wr = ((n & 5) == 0);            // dc even && dr even
    #pragma unroll
    for (int i=0;i<7;i++){
        if (i < nt){
            const int prow = trs[i]*4 + dr, pcol = tcs[i]*4 + dc;
            const long ra = pbase + ((long)prow*160 + pcol)*32;
            const long pa0 = ((long)b*6400 + (long)(gi*10 + trs[i]*2 + (dr>>1))*80
                              + gj*10 + tcs[i]*2 + (dc>>1))*32;
            #pragma unroll
            for (int h=0;h<2;h++){
                const uint2 ru = *(const uint2*)&in[ra + h*16 + q*4];
                float res[4];
                unp4(ru, res);
                float pv[4];
                #pragma unroll
                for (int r=0;r<4;r++){
                    float v = acc[i][h][r] + res[r];
                    v = fmaxf(v, 0.f);
                    v = fmaxf(v, __shfl_xor(v, 1, 64));
                    v = fmaxf(v, __shfl_xor(v, 4, 64));
                    pv[r] = fmaf(v, bnsc[h][r], bnsh[h][r]);
                }
                if (wr) *(uint2*)&pooled[pa0 + h*16 + q*4] = pack4(pv);
            }
        }
    }
}

// ------- conv2/conv3 via MFMA shift-GEMM; bf16 NHWC input (pure memcpy stage) -------
template<int CIN, int HIN, int WIN, int HOUT, int WOUT, bool NHWC_OUT>
__global__ __launch_bounds__(256) void k_convM(const unsigned short* __restrict__ in,
        const unsigned short* __restrict__ WB, const float* __restrict__ bias,
        void* __restrict__ outv)
{
    constexpr int PP = 23;
    constexpr bool C32 = (CIN == 32);
    __shared__ unsigned short xs[PP*PP*CIN];
    __shared__ unsigned short ws[C32 ? 16*64*8 : 32*64*8];
    const int t = threadIdx.x;
    const int col0 = blockIdx.x*16, row0 = blockIdx.y*16, b = blockIdx.z;
    for (int e = t; e < PP*PP*(CIN/8); e += 256){
        const int o = e % (CIN/8), pix = e / (CIN/8);
        int rr = row0 + pix/PP; if (rr > HIN-1) rr = HIN-1;
        int cc = col0 + pix%PP; if (cc > WIN-1) cc = WIN-1;
        const uint4 v = *(const uint4*)&in[((long)b*HIN*WIN + (long)rr*WIN + cc)*CIN + o*8];
        *(uint4*)&xs[pix*CIN + o*8] = v;
    }
    const int wave = t>>6, lane = t&63;
    const int quad = lane>>4, n16 = lane&15;
    const float bv = bias[n16];
    f32x4 acc[4];
    #pragma unroll
    for (int mt=0;mt<4;mt++) acc[mt] = (f32x4){bv,bv,bv,bv};
    if constexpr (C32){
        for (int ch=0; ch<4; ch++){
            __syncthreads();
            const unsigned* src = (const unsigned*)WB + ch*4096;
            for (int e=t; e<4096; e+=256) ((unsigned*)ws)[e] = src[e];
            __syncthreads();
            #pragma unroll 1
            for (int tap=0; tap<16; tap++){
                const int tg = ch*16+tap, ky = tg>>3, kx = tg&7;
                const short8 bw = *(const short8*)&ws[(tap*64+lane)*8];
                #pragma unroll
                for (int mt=0; mt<4; mt++){
                    const int pr = wave*4+mt+ky, pc = n16+kx;
                    const short8 av = *(const short8*)&xs[(pr*PP+pc)*32 + quad*8];
                    acc[mt] = __builtin_amdgcn_mfma_f32_16x16x32_bf16(av, bw, acc[mt], 0,0,0);
                }
            }
        }
    } else {
        for (int e=t; e<8192; e+=256) ((unsigned*)ws)[e] = ((const unsigned*)WB)[e];
        __syncthreads();
        #pragma unroll 1
        for (int pair=0; pair<32; pair++){
            const int ky = pair>>2, kx0 = (pair&3)*2;
            const short8 bw = *(const short8*)&ws[(pair*64+lane)*8];
            #pragma unroll
            for (int mt=0; mt<4; mt++){
                const int pr = wave*4+mt+ky, pc = n16 + kx0 + (quad>>1);
                const short8 av = *(const short8*)&xs[(pr*PP+pc)*16 + (quad&1)*8];
                acc[mt] = __builtin_amdgcn_mfma_f32_16x16x32_bf16(av, bw, acc[mt], 0,0,0);
            }
        }
    }
    #pragma unroll
    for (int mt=0; mt<4; mt++){
        const int orow = row0 + wave*4 + mt;
        if (orow >= HOUT) continue;
        const int ocol = col0 + quad*4;
        #pragma unroll
        for (int r=0;r<4;r++){
            if (ocol + r < WOUT){
                const float v = fmaxf(acc[mt][r], 0.f);
                if constexpr (NHWC_OUT)
                    ((unsigned short*)outv)[((long)b*HOUT*WOUT + (long)orow*WOUT + ocol + r)*16 + n16]
                        = (unsigned short)f2bf_u(v);
                else
                    ((float*)outv)[((long)(b*16 + n16)*HOUT + orow)*WOUT + ocol + r] = v;
            }
        }
    }
}

// ---------------- conv4 direct (+relu): 2 co per block, 8x less input re-read ----------------
// grid dim3(2,8,32): x=row half, y=co pair, z=b; 512 blocks x 256 threads
__global__ __launch_bounds__(256,2) void k_conv4(const float* __restrict__ in,
        const float* __restrict__ P, float* __restrict__ out)
{
    __shared__ float wl[2*16*36];   // 4608 B
    const int cp = blockIdx.y, bx = blockIdx.x, b = blockIdx.z;
    const int t = threadIdx.x;
    for (int j=t; j<1152; j+=256) wl[j] = P[OFF_C4W + cp*1152 + j];
    __syncthreads();
    const int cl = t>>7;                 // 0..1 local co
    const int rem = t&127;
    const int r = bx*16 + (rem>>3);      // output row
    const int grp = rem&7;
    const int x0 = grp*4;                // output col base (OW=4)
    if (r >= 31) return;
    const int co = cp*2 + cl;
    float acc[4];
    const float bv = P[OFF_C4B + co];
    #pragma unroll
    for (int j=0;j<4;j++) acc[j]=bv;
    const float* wc = &wl[cl*576];
    for (int ci=0; ci<16; ci++){
        #pragma unroll
        for (int ky=0; ky<6; ky++){
            const float* ip = in + ((long)(b*16+ci)*66 + (2*r+ky))*66 + 2*x0;
            float v[12];
            #pragma unroll
            for (int j=0;j<12;j++) v[j]=ip[j];
            const float* wr = &wc[(ci*6+ky)*6];
            #pragma unroll
            for (int kx=0;kx<6;kx++){
                const float wv = wr[kx];
                #pragma unroll
                for (int j=0;j<4;j++) acc[j] = fmaf(v[2*j+kx], wv, acc[j]);
            }
        }
    }
    float* op = out + ((long)(b*16+co)*31 + r)*31 + x0;
    #pragma unroll
    for (int j=0;j<4;j++)
        if (x0 + j < 31) op[j] = fmaxf(acc[j], 0.f);
}

// ---------------- conv5 fused: direct conv -> bf16 Xp rows; + fc1 y-bias-init + Xp pad-zero ----------------
// grid dim3(1,16,32): blockIdx.y=co, blockIdx.z=b; 512 blocks x 256 threads = 131072 = 32*4096
__global__ __launch_bounds__(256,2) void k_conv5F(const float* __restrict__ in,
        const float* __restrict__ P, unsigned short* __restrict__ xp, float* __restrict__ y)
{
    __shared__ float wl[16*25];
    const int co = blockIdx.y, b = blockIdx.z;
    const int t = threadIdx.x;
    for (int j=t; j<400; j+=256) wl[j] = P[OFF_C5W + co*400 + j];
    // fused fc1 y = bias (exactly 1 element per thread across the grid)
    {   const int lin = (b*16 + co)*256 + t;
        y[lin] = P[OFF_F1B + (lin & 4095)];
    }
    // fused Xp K-pad zero [11664,12288) per batch row
    if (co == 0 && t < 208){
        unsigned short* pp = xp + (long)b*12288 + 11664 + t*3;
        pp[0] = 0; pp[1] = 0; pp[2] = 0;
    }
    __syncthreads();
    if (t >= 27*7) return;
    const int yy = t / 7, x0 = (t % 7) * 4;
    float acc[4];
    const float bv = P[OFF_C5B + co];
    #pragma unroll
    for (int j=0;j<4;j++) acc[j]=bv;
    for (int ci=0; ci<16; ci++){
        #pragma unroll
        for (int ky=0; ky<5; ky++){
            const float* ip = in + ((long)(b*16+ci)*31 + (yy+ky))*31 + x0;
            float v[8];
            #pragma unroll
            for (int j=0;j<8;j++) v[j]=ip[j];
            const float* wr = &wl[(ci*5+ky)*5];
            #pragma unroll
            for (int kx=0;kx<5;kx++){
                const float wv = wr[kx];
                #pragma unroll
                for (int j=0;j<4;j++) acc[j] = fmaf(v[j+kx], wv, acc[j]);
            }
        }
    }
    unsigned short* op = xp + (long)b*12288 + (co*27 + yy)*27 + x0;
    #pragma unroll
    for (int j=0;j<4;j++)
        if (x0 + j < 27) op[j] = (unsigned short)f2bf_u(fmaxf(acc[j], 0.f));
}

// ---------------- combined pack(relu)+bias-init for fc2/fc3 ----------------
__global__ __launch_bounds__(256) void k_pk(const float* __restrict__ in,
        unsigned short* __restrict__ out, float* __restrict__ y,
        const float* __restrict__ bias, int N, int ny, int rows, int K)
{
    const int i = blockIdx.x*256 + threadIdx.x;
    if (i < ny){ y[i] = bias[i % N]; return; }
    const int d = i - ny;
    const int per = K >> 3;
    if (d >= rows*per) return;
    const int row = d / per, k = (d - row*per)*8;
    float v[8];
    *(f32x4*)&v[0] = *(const f32x4*)&in[(long)row*K + k];
    *(f32x4*)&v[4] = *(const f32x4*)&in[(long)row*K + k + 4];
    #pragma unroll
    for (int j=0;j<8;j++) v[j] = fmaxf(v[j], 0.f);
    *(short8*)&out[(long)row*K + k] = pack8(v);
}

// ---------------- fc1/fc2: LDS-staged GEMM via global_load_lds ----------------
template<typename WT>
__device__ __forceinline__ void fcl_body(const unsigned short* __restrict__ x,
        const WT* __restrict__ w, float* __restrict__ y,
        int Kw, int Khat, int N, int Kc, int Nvalid, unsigned char* lbuf)
{
    constexpr bool WF = __is_same(WT, float);
    const int t = threadIdx.x;
    const int wave = t>>6, lane = t&63;
    const int quad = lane>>4, n16 = lane&15;
    const int og = wave>>1, bh = wave&1;
    const int bx = blockIdx.x;
    const int start = blockIdx.y*Kc;
    int steps = 0;
    {   const int rem = Kw - start;
        const int sa = Kc >> 7;
        if (rem > 0){ steps = (rem + 127) >> 7; if (steps > sa) steps = sa; }
    }
    f32x4 acc = {0.f,0.f,0.f,0.f};
    const unsigned short* xp = x + (long)(bh*16 + n16)*Khat;
    const int row = og*16 + n16;

    auto stage = [&](int s, int bsel){
        const int k0 = start + (s<<7);
        const bool swz = (k0 + 128 <= Kw);
        unsigned char* base = lbuf + bsel*16384;
        if constexpr (WF){
            const int r0 = wave*8;
            #pragma unroll
            for (int c=0;c<4;c++){
                const int rr = r0 + 2*c + (lane>>5);
                const int cs = swz ? ((lane&31) ^ (rr&7)) : (lane&31);
                long koff = (long)k0 + cs*4;
                const float* ga = w + (long)(bx*32 + rr)*Kw + koff;
                if (!swz && (koff + 4 > Kw)) ga = w + (long)(bx*32 + rr)*Kw;  // x=0 there
                GLD_LDS16(ga, base + (r0 + 2*c)*512);
            }
        } else {
            const int r0 = wave*8;
            #pragma unroll
            for (int c=0;c<2;c++){
                const int rr = r0 + 4*c + (lane>>4);
                const int cs = swz ? ((lane&15) ^ (rr&7)) : (lane&15);
                long koff = (long)k0 + cs*8;
                const WT* ga = w + (long)(bx*32 + rr)*Kw + koff;
                if (!swz && (koff + 8 > Kw)) ga = w + (long)(bx*32 + rr)*Kw;
                GLD_LDS16(ga, base + (r0 + 4*c)*256);
            }
        }
    };
    auto consume = [&](int s, int bsel){
        const int k0 = start + (s<<7);
        const bool swz = (k0 + 128 <= Kw);
        const unsigned char* base = lbuf + bsel*16384;
        #pragma unroll
        for (int kk=0; kk<4; kk++){
            const int ka = k0 + kk*32 + quad*8;
            const short8 x8 = *(const short8*)&xp[ka];
            short8 bw;
            if constexpr (WF){
                const int c0 = kk*8 + quad*2;
                const int p0 = swz ? (c0 ^ (row&7)) : c0;
                const int p1 = swz ? ((c0+1) ^ (row&7)) : (c0+1);
                float wv[8];
                *(f32x4*)&wv[0] = *(const f32x4*)&base[row*512 + p0*16];
                *(f32x4*)&wv[4] = *(const f32x4*)&base[row*512 + p1*16];
                bw = pack8(wv);
            } else {
                const int c0 = kk*4 + quad;
                const int p0 = swz ? (c0 ^ (row&7)) : c0;
                bw = *(const short8*)&base[row*256 + p0*16];
            }
            acc = __builtin_amdgcn_mfma_f32_16x16x32_bf16(x8, bw, acc, 0,0,0);
        }
    };

    if (steps > 0){
        stage(0, 0);
        __syncthreads();
        for (int s=0; s<steps; s++){
            if (s+1 < steps) stage(s+1, (s+1)&1);
            consume(s, s&1);
            __syncthreads();
        }
    }
    const int o = bx*32 + og*16 + n16;
    if (o < Nvalid){
        #pragma unroll
        for (int r=0;r<4;r++)
            atomicAdd(&y[(long)(bh*16 + quad*4 + r)*N + o], acc[r]);
    }
}

__global__ __launch_bounds__(256,4) void k_fcL(const unsigned short* __restrict__ x,
        const void* __restrict__ w, const int* __restrict__ flag,
        float* __restrict__ y, int Kw, int Khat, int N, int Kc, int Nvalid)
{
    __shared__ unsigned char lbuf[2*16384];
    if (*flag) fcl_body<float>(x, (const float*)w, y, Kw, Khat, N, Kc, Nvalid, lbuf);
    else       fcl_body<bf16 >(x, (const bf16 *)w, y, Kw, Khat, N, Kc, Nvalid, lbuf);
}

// ---------------- fc3 (tiny): register-pipelined MFMA ----------------
template<typename WT>
__device__ __forceinline__ void fcm_loop(const unsigned short* __restrict__ xp,
        const WT* __restrict__ wp, int start, int end, int quad, f32x4& acc)
{
    const int nfull = (end - start) >> 5;
    const int end32 = start + (nfull << 5);
    const int qo = quad*8;

    short8 xA, xB, xC;
    short8 bwA, bwB, bwC;
    f32x4 wA0, wA1, wB0, wB1, wC0, wC1;

    auto loadA = [&](int k0){
        const int ka = k0 + qo;
        xA = *(const short8*)&xp[ka];
        if constexpr (__is_same(WT, bf16)) bwA = *(const short8*)&wp[ka];
        else { wA0 = *(const f32x4*)&wp[ka]; wA1 = *(const f32x4*)&wp[ka+4]; }
    };
    auto loadB = [&](int k0){
        const int ka = k0 + qo;
        xB = *(const short8*)&xp[ka];
        if constexpr (__is_same(WT, bf16)) bwB = *(const short8*)&wp[ka];
        else { wB0 = *(const f32x4*)&wp[ka]; wB1 = *(const f32x4*)&wp[ka+4]; }
    };
    auto loadC = [&](int k0){
        const int ka = k0 + qo;
        xC = *(const short8*)&xp[ka];
        if constexpr (__is_same(WT, bf16)) bwC = *(const short8*)&wp[ka];
        else { wC0 = *(const f32x4*)&wp[ka]; wC1 = *(const f32x4*)&wp[ka+4]; }
    };
    auto compA = [&](){
        short8 bw;
        if constexpr (__is_same(WT, bf16)) bw = bwA;
        else { float wv[8]; *(f32x4*)&wv[0]=wA0; *(f32x4*)&wv[4]=wA1; bw = pack8(wv); }
        acc = __builtin_amdgcn_mfma_f32_16x16x32_bf16(xA, bw, acc, 0,0,0);
    };
    auto compB = [&](){
        short8 bw;
        if constexpr (__is_same(WT, bf16)) bw = bwB;
        else { float wv[8]; *(f32x4*)&wv[0]=wB0; *(f32x4*)&wv[4]=wB1; bw = pack8(wv); }
        acc = __builtin_amdgcn_mfma_f32_16x16x32_bf16(xB, bw, acc, 0,0,0);
    };
    auto compC = [&](){
        short8 bw;
        if constexpr (__is_same(WT, bf16)) bw = bwC;
        else { float wv[8]; *(f32x4*)&wv[0]=wC0; *(f32x4*)&wv[4]=wC1; bw = pack8(wv); }
        acc = __builtin_amdgcn_mfma_f32_16x16x32_bf16(xC, bw, acc, 0,0,0);
    };

    if (nfull >= 3){
        loadA(start); loadB(start+32); loadC(start+64);
        int j = 0;
        for (; j + 6 <= nfull; j += 3){
            compA(); loadA(start + ((j+3)<<5));
            compB(); loadB(start + ((j+4)<<5));
            compC(); loadC(start + ((j+5)<<5));
        }
        const int rem = nfull - j;
        if (rem == 3){ compA(); compB(); compC(); }
        else if (rem == 4){
            compA(); loadA(start + ((j+3)<<5));
            compB(); compC(); compA();
        } else {
            compA(); loadA(start + ((j+3)<<5));
            compB(); loadB(start + ((j+4)<<5));
            compC(); compA(); compB();
        }
    } else if (nfull == 2){
        loadA(start); loadB(start+32); compA(); compB();
    } else if (nfull == 1){
        loadA(start); compA();
    }
    if (end32 < end){
        const int ka = end32 + qo;
        float xv[8], wv[8];
        #pragma unroll
        for (int j=0;j<8;j++){
            const bool v = (ka + j) < end;
            xv[j] = v ? b2f(((const bf16*)xp)[ka+j]) : 0.f;
            wv[j] = v ? (float)ld(wp, ka+j) : 0.f;
        }
        acc = __builtin_amdgcn_mfma_f32_16x16x32_bf16(pack8(xv), pack8(wv), acc, 0,0,0);
    }
}

__global__ __launch_bounds__(256,4) void k_fcM(const unsigned short* __restrict__ x,
        const void* __restrict__ w, const int* __restrict__ flag,
        float* __restrict__ y, int K, int N, int Kc, int Nvalid)
{
    const int t = threadIdx.x;
    const int wave = t>>6, lane = t&63;
    const int quad = lane>>4, n16 = lane&15;
    const int og = wave>>1, bh = wave&1;
    const int o = blockIdx.x*32 + og*16 + n16;
    const int orow = (o < Nvalid) ? o : (Nvalid-1);
    const int xrow = bh*16 + n16;
    const int start = blockIdx.y*Kc;
    const int end = min(K, start + Kc);
    f32x4 acc = {0.f,0.f,0.f,0.f};
    const unsigned short* xp = x + (long)xrow*K;
    if (*flag) fcm_loop<float>(xp, (const float*)w + (long)orow*K, start, end, quad, acc);
    else       fcm_loop<bf16 >(xp, (const bf16 *)w + (long)orow*K, start, end, quad, acc);
    if (o < Nvalid){
        #pragma unroll
        for (int r=0;r<4;r++)
            atomicAdd(&y[(long)(bh*16 + quad*4 + r)*N + o], acc[r]);
    }
}

// ---------------- paired log_softmax over axis 1 of [32,2,12] ----------------
__global__ void k_lsm(const float* __restrict__ in, const int* __restrict__ flag,
                      void* __restrict__ out)
{
    const int i = threadIdx.x;
    if (i >= 384) return;
    const int b = i/12, au = i%12;
    const float a0 = in[b*24+au], a1 = in[b*24+12+au];
    const float m = fmaxf(a0,a1);
    const float lse = m + logf(expf(a0-m)+expf(a1-m));
    const float o0 = a0-lse, o1 = a1-lse;
    if (*flag){
        ((float*)out)[b*24+au]    = o0;
        ((float*)out)[b*24+12+au] = o1;
    } else {
        ((bf16*)out)[b*24+au]    = __float2bfloat16(o0);
        ((bf16*)out)[b*24+12+au] = __float2bfloat16(o1);
    }
}

extern "C" void kernel_launch(void* const* d_in, const int* in_sizes, int n_in,
                              void* d_out, int out_size, void* d_ws, size_t ws_size,
                              hipStream_t stream) {
    (void)in_sizes; (void)n_in; (void)out_size; (void)ws_size;
    const void* x = d_in[0];

    float* A = (float*)d_ws;               // 26,214,400 floats
    float* B = A + 26214400;               //  6,553,600 floats
    float* P = B + 6553600;                //  P_END floats
    int* flag = (int*)(P + P_END);
    unsigned short* Xp = (unsigned short*)(P + P_END + 16);  // 393,216 bf16
    unsigned short* Abf = (unsigned short*)A;
    unsigned short* Bbf = (unsigned short*)B;
    float* Bhi = B + 5000000;              // conv4 out [32,16,31,31] = 492,032 floats

    CvtArgs a;
    const int src_idx[23] = {1,2,3,4,5,6,7,8,9,10,11,12,13,14,15,16,17,18,19,20,22,24,26};
    const int offs[23] = {OFF_C1W,OFF_C1B,OFF_RLG,OFF_RLB,OFF_RLM,OFF_RLV,OFF_RLCW,OFF_RLCB,
                          OFF_BNG,OFF_BNB,OFF_BNM,OFF_BNV,OFF_C2W,OFF_C2B,OFF_C3W,OFF_C3B,
                          OFF_C4W,OFF_C4B,OFF_C5W,OFF_C5B,OFF_F1B,OFF_F2B,OFF_F3B};
    for (int j=0;j<23;j++){ a.src[j] = d_in[src_idx[j]]; a.off[j] = offs[j]; }
    a.cw = d_in[7]; a.w2 = d_in[13]; a.w3 = d_in[15];
    a.x0 = x;
    a.total = P_TOTAL;

    // 1: params convert (self-sniffs dtype; compacted index space)
    k_cvt<<<((P_TOTAL-SZ_HOLE)+SZ_RL+SZ_WB2+SZ_WB3+SZ_WC1+255)/256,256,0,stream>>>(a, flag, P);
    // 2: conv1 -> Abf bf16 NHWC [32,160,160,32]  (16 rows/block)
    k_conv1M<<<dim3(10,5,32),256,0,stream>>>(x, flag, P, Abf);
    // 3: region -> Bbf bf16 NHWC pooled [32,80,80,32]
    k_regionM<<<2048,256,0,stream>>>(Abf, P, Bbf);
    // 4: conv2 -> Abf bf16 NHWC [32,73,73,16]
    k_convM<32,80,80,73,73,true><<<dim3(5,5,32),256,0,stream>>>(Bbf, (const unsigned short*)(P+OFF_WB2), P+OFF_C2B, (void*)Abf);
    // 5: conv3 -> B f32 NCHW [32,16,66,66]
    k_convM<16,73,73,66,66,false><<<dim3(5,5,32),256,0,stream>>>(Abf, (const unsigned short*)(P+OFF_WB3), P+OFF_C3B, (void*)B);
    // 6: conv4 stride 2 -> Bhi f32 NCHW [32,16,31,31]  (2 co/block)
    k_conv4<<<dim3(2,8,32),256,0,stream>>>(B, P, Bhi);
    // 7: conv5 -> bf16 Xp rows [32][12288]; fused fc1 y=A bias-init + Xp pad-zero
    k_conv5F<<<dim3(1,16,32),256,0,stream>>>(Bhi, P, Xp, A);
    // 8: fc1 K=11664 (pad 12288) -> 4096, y=A; 8 K-splits
    k_fcL<<<dim3(128,8),256,0,stream>>>(Xp, d_in[21], flag, A, 11664, 12288, 4096, 1536, 4096);
    // 9: pack fc1-out (relu) + fc2 y=B bias-init
    k_pk<<<(65536+16384+255)/256,256,0,stream>>>(A, Xp, B, P+OFF_F2B, 2048, 65536, 32, 4096);
    // 10: fc2 K=4096 -> 2048, y=B; 8 K-splits
    k_fcL<<<dim3(64,8),256,0,stream>>>(Xp, d_in[23], flag, B, 4096, 4096, 2048, 512, 2048);
    // 11: pack fc2-out (relu) + fc3 y=A bias-init
    k_pk<<<(768+8192+255)/256,256,0,stream>>>(B, Xp, A, P+OFF_F3B, 24, 768, 32, 2048);
    // 12: fc3 K=2048 -> 24, y=A
    k_fcM<<<dim3(1,64),256,0,stream>>>(Xp, d_in[25], flag, A, 2048, 24, 32, 24);
    // 13: log_softmax
    k_lsm<<<1,384,0,stream>>>(A, flag, d_out);
}